// Round 4
// baseline (607.166 us; speedup 1.0000x reference)
//
#include <hip/hip_runtime.h>
#include <hip/hip_fp16.h>

typedef _Float16 half8 __attribute__((ext_vector_type(8)));
typedef float f32x4 __attribute__((ext_vector_type(4)));

#define B_   4
#define L_   4096
#define D_   128
#define M_   (B_*L_)     // 16384
#define D2_  256
#define H_   512
#define OUT_ 55

__device__ __forceinline__ f32x4 mfma16(half8 a, half8 b, f32x4 c) {
    return __builtin_amdgcn_mfma_f32_16x16x32_f16(a, b, c, 0, 0, 0);
}

// ---- weight swizzle offsets (in halfs) within wsw region ----
#define WQ_OFF   0
#define WV1_OFF  16384
#define WK_OFF   32768
#define WV2_OFF  49152
#define WP1_OFF  65536
#define WP2_OFF  81920
#define WF1_OFF  98304     // 256x512 = 131072
#define WF2_OFF  229376    // 512x256 = 131072
#define WO_OFF   360448    // 256x64 (padded) = 16384

// Pre-swizzle weights (fp32 row-major [K][N]) into B-fragment layout fp16:
// idx = ((s*nc + c)*64 + lane)*8 + j ; s=k>>5, q=(k>>3)&3, j=k&7, c=n>>4, ln=n&15, lane=q*16+ln
__global__ void prep_kernel(const float* Wq, const float* Wv1, const float* Wk,
                            const float* Wv2, const float* Wp1, const float* Wp2,
                            const float* Wf1, const float* Wf2, const float* Wo,
                            _Float16* wsw) {
    int id = blockIdx.y;
    int t  = blockIdx.x * 256 + threadIdx.x;
    const float* src = nullptr; int K = 0, N = 0, Npad = 0, off = 0;
    switch (id) {
        case 0: src = Wq;  K = 128; N = 128; Npad = 128; off = WQ_OFF;  break;
        case 1: src = Wv1; K = 128; N = 128; Npad = 128; off = WV1_OFF; break;
        case 2: src = Wk;  K = 128; N = 128; Npad = 128; off = WK_OFF;  break;
        case 3: src = Wv2; K = 128; N = 128; Npad = 128; off = WV2_OFF; break;
        case 4: src = Wp1; K = 128; N = 128; Npad = 128; off = WP1_OFF; break;
        case 5: src = Wp2; K = 128; N = 128; Npad = 128; off = WP2_OFF; break;
        case 6: src = Wf1; K = 256; N = 512; Npad = 512; off = WF1_OFF; break;
        case 7: src = Wf2; K = 512; N = 256; Npad = 256; off = WF2_OFF; break;
        case 8: src = Wo;  K = 256; N = 55;  Npad = 64;  off = WO_OFF;  break;
        default: return;
    }
    int total = K * Npad;
    if (t >= total) return;
    int k = t / Npad, n = t % Npad;
    float v = (n < N) ? src[k * N + n] : 0.f;
    int s = k >> 5, q = (k >> 3) & 3, j = k & 7, c = n >> 4, ln = n & 15;
    int nc = Npad >> 4;
    wsw[off + ((size_t)((s * nc + c) * 64 + q * 16 + ln)) * 8 + j] = (_Float16)v;
}

// FR layout for X[M][C] halfs:
// idx = ((lt*(C/32) + s)*64 + q*16 + ln_r)*8 + j ; lt=row>>4, ln_r=row&15,
// s=col>>5, q=(col>>3)&3, j=col&7.  A/B-frag loads become lane-contiguous 1KB.

// LayerNorm over D=128, one wave per token, fp32 in -> fp16 FR-swizzled out
__global__ __launch_bounds__(256) void ln_kernel(const float* x1, const float* x2,
        const float* g1, const float* b1, const float* g2, const float* b2,
        _Float16* x1n, _Float16* x2n) {
    int wave = threadIdx.x >> 6, lane = threadIdx.x & 63;
    int token = blockIdx.x * 4 + wave;
    const float* x = blockIdx.y ? x2 : x1;
    const float* g = blockIdx.y ? g2 : g1;
    const float* bb = blockIdx.y ? b2 : b1;
    _Float16* o = blockIdx.y ? x2n : x1n;
    const float* xr = x + (size_t)token * D_;
    float a0 = xr[lane], a1 = xr[lane + 64];
    float s = a0 + a1, s2 = a0 * a0 + a1 * a1;
    #pragma unroll
    for (int off = 1; off < 64; off <<= 1) {
        s += __shfl_xor(s, off);
        s2 += __shfl_xor(s2, off);
    }
    float mean = s * (1.f / 128.f);
    float var = s2 * (1.f / 128.f) - mean * mean;
    float inv = rsqrtf(var + 1e-5f);
    int lt = token >> 4, ln_r = token & 15;
    #pragma unroll
    for (int h = 0; h < 2; h++) {
        int col = lane + h * 64;
        float v = (h ? a1 : a0);
        float out = (v - mean) * inv * g[col] + bb[col];
        int ss = col >> 5, q = (col >> 3) & 3, j = col & 7;
        o[((size_t)((lt * 4 + ss) * 64 + q * 16 + ln_r)) * 8 + j] = (_Float16)out;
    }
}

// Projections: q1 = x1n@Wq ; v1 = x1n@Wv1 ; k2 = x2n@Wk ; v2 = x2n@Wv2 (+biases)
// q1/k2 stored FR-swizzled (global M); v1/v2 stored PV-B-frag layout per batch.
__global__ __launch_bounds__(256) void proj_kernel(const _Float16* x1n, const _Float16* x2n,
        const _Float16* wsw, const float* bq, const float* bv1, const float* bk,
        const float* bv2, _Float16* q1, _Float16* k2, _Float16* v1sw, _Float16* v2sw) {
    int g = blockIdx.y;   // 0:Wq 1:Wv1 2:Wk 3:Wv2
    const _Float16* A = (g < 2) ? x1n : x2n;
    const _Float16* Bw = wsw + g * 16384;
    const float* bias = (g == 0) ? bq : (g == 1) ? bv1 : (g == 2) ? bk : bv2;
    int wave = threadIdx.x >> 6, lane = threadIdx.x & 63;
    int quad = lane >> 4, ln = lane & 15;
    int mbase = blockIdx.x * 64 + wave * 16;
    int lt = mbase >> 4;

    half8 a[4];
    #pragma unroll
    for (int s = 0; s < 4; s++)
        a[s] = *(const half8*)(A + ((size_t)((lt * 4 + s) * 64 + lane)) * 8);

    f32x4 acc[8];
    #pragma unroll
    for (int c = 0; c < 8; c++) {
        acc[c] = f32x4{0.f, 0.f, 0.f, 0.f};
        #pragma unroll
        for (int s = 0; s < 4; s++) {
            half8 bf = *(const half8*)(Bw + ((size_t)((s * 8 + c) * 64 + lane)) * 8);
            acc[c] = mfma16(a[s], bf, acc[c]);
        }
    }
    bool isV = (g == 1) || (g == 3);
    _Float16* out = (g == 0) ? q1 : (g == 2) ? k2 : (g == 1) ? v1sw : v2sw;
    #pragma unroll
    for (int c = 0; c < 8; c++) {
        int n = c * 16 + ln;
        float bv = bias[n];
        #pragma unroll
        for (int r = 0; r < 4; r++) {
            int m = mbase + quad * 4 + r;
            float val = acc[c][r] + bv;
            if (!isV) {
                int s_o = c >> 1, q_o = ((c & 1) << 1) | (ln >> 3), j = ln & 7;
                out[((size_t)((lt * 4 + s_o) * 64 + q_o * 16 + (quad * 4 + r))) * 8 + j]
                    = (_Float16)val;
            } else {
                int b = m >> 12, l = m & (L_ - 1);
                int tt = l >> 5, q2 = (l >> 3) & 3, j = l & 7;
                out[(size_t)b * (L_ * D_) + (((size_t)((tt * 8 + c) * 64 + q2 * 16 + ln)) * 8 + j)]
                    = (_Float16)val;
            }
        }
    }
}

// Fused flash attention + output projections + residual + concat + LNf.
// Block = 4 waves (256 thr), ALL on the same 16 Q-rows; wave w = K-split (1024 rows).
// Partials merged in LDS (unstabilized softmax -> plain sums). 1024 blocks = 4 blk/CU.
// NOTE: no min-occupancy in launch_bounds — forcing 4 waves/EU starved the register
// allocator to 64 arch VGPRs and spilled the accumulators (FETCH 51->250 MB, r2/r3).
__global__ __launch_bounds__(256) void flash_kernel(
        const _Float16* __restrict__ q1sw, const _Float16* __restrict__ k2sw,
        const _Float16* __restrict__ v1sw, const _Float16* __restrict__ v2sw,
        const _Float16* __restrict__ wsw,
        const float* __restrict__ bp1, const float* __restrict__ bp2,
        const float* __restrict__ x1, const float* __restrict__ x2,
        const float* __restrict__ lnf_g, const float* __restrict__ lnf_b,
        float* __restrict__ res, _Float16* __restrict__ xn) {
    __shared__ _Float16 part[3][16 * 264];     // 25.3 KB: partial O from ks=1..3
    __shared__ float lpart[3][16];
    __shared__ _Float16 att[16 * 264];         // 8.4 KB: final normalized att (both streams)
    __shared__ _Float16 pbuf[4][16 * 40];      // 5 KB
    __shared__ float sst[16][4][2];            // LN stats exchange

    int bid = blockIdx.x;
    int xcd = bid & 7;                 // XCD-affine: 2 XCDs per batch (K/V L2-resident)
    int b = xcd >> 1;
    int qt = ((bid >> 3) << 1) | (xcd & 1);    // 0..255 (16-row Q tile)
    int w = threadIdx.x >> 6, lane = threadIdx.x & 63;
    int quad = lane >> 4, ln = lane & 15;
    int qrow0 = (b << 12) + (qt << 4);

    // Q fragments (A-operand), FR-swizzled coalesced; same for all 4 waves
    half8 qf[4];
    int lt_q = qrow0 >> 4;
    #pragma unroll
    for (int s = 0; s < 4; s++)
        qf[s] = *(const half8*)(k2sw + ((size_t)((lt_q * 4 + s) * 64 + lane)) * 8);

    const _Float16* V1 = v1sw + (size_t)b * (L_ * D_);
    const _Float16* V2 = v2sw + (size_t)b * (L_ * D_);

    f32x4 o1[8], o2[8];
    #pragma unroll
    for (int c = 0; c < 8; c++) { o1[c] = f32x4{0,0,0,0}; o2[c] = f32x4{0,0,0,0}; }
    float lsum[4] = {0.f, 0.f, 0.f, 0.f};
    const float scale = 0.08838834764831845f;   // 1/sqrt(128)

    _Float16* pb = pbuf[w];
    for (int it = 0; it < 32; it++) {
        int t32 = w * 32 + it;                  // 32-row K tile within batch
        int lt_k = (b << 8) + (t32 << 1);
        f32x4 s0 = f32x4{0,0,0,0}, s1 = f32x4{0,0,0,0};
        #pragma unroll
        for (int s = 0; s < 4; s++) {
            half8 k0 = *(const half8*)(q1sw + ((size_t)((lt_k * 4 + s) * 64 + lane)) * 8);
            s0 = mfma16(qf[s], k0, s0);
        }
        #pragma unroll
        for (int s = 0; s < 4; s++) {
            half8 k1 = *(const half8*)(q1sw + ((size_t)(((lt_k + 1) * 4 + s) * 64 + lane)) * 8);
            s1 = mfma16(qf[s], k1, s1);
        }
        #pragma unroll
        for (int r = 0; r < 4; r++) {
            float p0 = __expf(s0[r] * scale);
            float p1 = __expf(s1[r] * scale);
            lsum[r] += p0 + p1;
            pb[(quad * 4 + r) * 40 + ln]      = (_Float16)p0;
            pb[(quad * 4 + r) * 40 + 16 + ln] = (_Float16)p1;
        }
        half8 pf = *(const half8*)(pb + ln * 40 + quad * 8);
        #pragma unroll
        for (int c = 0; c < 8; c++) {
            half8 v1f = *(const half8*)(V1 + ((size_t)((t32 * 8 + c) * 64 + lane)) * 8);
            half8 v2f = *(const half8*)(V2 + ((size_t)((t32 * 8 + c) * 64 + lane)) * 8);
            o1[c] = mfma16(pf, v1f, o1[c]);
            o2[c] = mfma16(pf, v2f, o2[c]);
        }
    }
    // row-sum reduce over the 16 lanes holding each row's columns
    #pragma unroll
    for (int off = 1; off < 16; off <<= 1)
        #pragma unroll
        for (int r = 0; r < 4; r++) lsum[r] += __shfl_xor(lsum[r], off);

    if (w > 0) {
        _Float16* op = part[w - 1];
        #pragma unroll
        for (int c = 0; c < 8; c++)
            #pragma unroll
            for (int r = 0; r < 4; r++) {
                op[(quad * 4 + r) * 264 + c * 16 + ln]       = (_Float16)o1[c][r];
                op[(quad * 4 + r) * 264 + 128 + c * 16 + ln] = (_Float16)o2[c][r];
            }
        if (ln == 0)
            #pragma unroll
            for (int r = 0; r < 4; r++) lpart[w - 1][quad * 4 + r] = lsum[r];
    }
    __syncthreads();
    if (w == 0) {
        float inv[4];
        #pragma unroll
        for (int r = 0; r < 4; r++) {
            float lt2 = lsum[r];
            #pragma unroll
            for (int kk = 0; kk < 3; kk++) lt2 += lpart[kk][quad * 4 + r];
            inv[r] = 1.f / lt2;
        }
        #pragma unroll
        for (int c = 0; c < 8; c++)
            #pragma unroll
            for (int r = 0; r < 4; r++) {
                int ro = (quad * 4 + r) * 264;
                float va = o1[c][r], vb = o2[c][r];
                #pragma unroll
                for (int kk = 0; kk < 3; kk++) {
                    va += (float)part[kk][ro + c * 16 + ln];
                    vb += (float)part[kk][ro + 128 + c * 16 + ln];
                }
                att[ro + c * 16 + ln]       = (_Float16)(va * inv[r]);
                att[ro + 128 + c * 16 + ln] = (_Float16)(vb * inv[r]);
            }
    }
    __syncthreads();

    // Epilogue: wave (stream, nhalf): out_s[16 x 64] = att_s @ Wp_s + b + res
    int stream = w & 1, nhalf = w >> 1;
    const _Float16* attA = att + stream * 128;
    half8 af[4];
    #pragma unroll
    for (int s = 0; s < 4; s++)
        af[s] = *(const half8*)(attA + ln * 264 + s * 32 + quad * 8);
    const _Float16* Wp = wsw + (stream ? WP2_OFF : WP1_OFF);
    f32x4 acc[4];
    #pragma unroll
    for (int c = 0; c < 4; c++) {
        acc[c] = f32x4{0,0,0,0};
        int cg = nhalf * 4 + c;
        #pragma unroll
        for (int s = 0; s < 4; s++)
            acc[c] = mfma16(af[s], *(const half8*)(Wp + ((size_t)((s * 8 + cg) * 64 + lane)) * 8), acc[c]);
    }
    const float* bp = stream ? bp2 : bp1;
    const float* xres = stream ? x2 : x1;
    float y[4][4];
    float psum[4] = {0,0,0,0}, psq[4] = {0,0,0,0};
    #pragma unroll
    for (int c = 0; c < 4; c++) {
        int n = nhalf * 64 + c * 16 + ln;
        float bv = bp[n];
        #pragma unroll
        for (int r = 0; r < 4; r++) {
            int m = qrow0 + quad * 4 + r;
            float v = acc[c][r] + bv + xres[(size_t)m * D_ + n];
            y[c][r] = v; psum[r] += v; psq[r] += v * v;
        }
    }
    #pragma unroll
    for (int off = 1; off < 16; off <<= 1)
        #pragma unroll
        for (int r = 0; r < 4; r++) { psum[r] += __shfl_xor(psum[r], off); psq[r] += __shfl_xor(psq[r], off); }
    if (ln == 0)
        #pragma unroll
        for (int r = 0; r < 4; r++) {
            sst[quad * 4 + r][w][0] = psum[r];
            sst[quad * 4 + r][w][1] = psq[r];
        }
    __syncthreads();
    #pragma unroll
    for (int r = 0; r < 4; r++) {
        float su = 0.f, sq = 0.f;
        #pragma unroll
        for (int k = 0; k < 4; k++) { su += sst[quad * 4 + r][k][0]; sq += sst[quad * 4 + r][k][1]; }
        float mean = su * (1.f / 256.f);
        float var = sq * (1.f / 256.f) - mean * mean;
        float invs = rsqrtf(var + 1e-5f);
        int m = qrow0 + quad * 4 + r;
        int lt_m = m >> 4;
        #pragma unroll
        for (int c = 0; c < 4; c++) {
            int colg = stream * 128 + nhalf * 64 + c * 16 + ln;
            float yv = y[c][r];
            res[(size_t)m * D2_ + colg] = yv;
            float yn = (yv - mean) * invs * lnf_g[colg] + lnf_b[colg];
            int s_x = colg >> 5, q_x = (colg >> 3) & 3, j = colg & 7;
            xn[((size_t)((lt_m * 8 + s_x) * 64 + q_x * 16 + (m & 15))) * 8 + j] = (_Float16)yn;
        }
    }
}

// h = gelu(xn @ Wf1 + bf1)  [M x 512], FR-swizzled in/out
__global__ __launch_bounds__(256) void ffn1_kernel(const _Float16* xn, const _Float16* wsw,
        const float* bf1, _Float16* h) {
    int wave = threadIdx.x >> 6, lane = threadIdx.x & 63;
    int quad = lane >> 4, ln = lane & 15;
    int mbase = blockIdx.x * 64 + wave * 16;
    int lt = mbase >> 4;
    int nt = blockIdx.y;   // 0..3
    const _Float16* W = wsw + WF1_OFF;   // K=256, N=512, nc=32

    half8 a[8];
    #pragma unroll
    for (int s = 0; s < 8; s++)
        a[s] = *(const half8*)(xn + ((size_t)((lt * 8 + s) * 64 + lane)) * 8);

    f32x4 acc[8];
    #pragma unroll
    for (int c = 0; c < 8; c++) {
        acc[c] = f32x4{0,0,0,0};
        int cg = nt * 8 + c;
        #pragma unroll
        for (int s = 0; s < 8; s++)
            acc[c] = mfma16(a[s], *(const half8*)(W + ((size_t)((s * 32 + cg) * 64 + lane)) * 8), acc[c]);
    }
    #pragma unroll
    for (int c = 0; c < 8; c++) {
        int n = nt * 128 + c * 16 + ln;
        float bv = bf1[n];
        int s_h = n >> 5, q_h = (n >> 3) & 3, j = n & 7;
        #pragma unroll
        for (int r = 0; r < 4; r++) {
            float v = acc[c][r] + bv;
            float ge = 0.5f * v * (1.f + erff(v * 0.70710678118654752f));
            h[((size_t)((lt * 16 + s_h) * 64 + q_h * 16 + (quad * 4 + r))) * 8 + j] = (_Float16)ge;
        }
    }
}

// x = LN3(h @ Wf2 + bf2 + res) -> xn2 (FR-swizzled fp16). Block: 2 rowtiles x 2 N-halves.
__global__ __launch_bounds__(256) void ffn2_kernel(const _Float16* h, const _Float16* wsw,
        const float* bf2, const float* res, const float* g3, const float* b3, _Float16* xn2) {
    __shared__ float sst[2][16][2][2];
    int w = threadIdx.x >> 6, lane = threadIdx.x & 63;
    int quad = lane >> 4, ln = lane & 15;
    int rt = w & 1, nh = w >> 1;
    int mb = blockIdx.x * 32 + rt * 16;
    int lt = mb >> 4;
    const _Float16* W = wsw + WF2_OFF;   // K=512, N=256, nc=16

    f32x4 acc[8];
    #pragma unroll
    for (int c = 0; c < 8; c++) acc[c] = f32x4{0,0,0,0};
    for (int s = 0; s < 16; s++) {
        half8 a = *(const half8*)(h + ((size_t)((lt * 16 + s) * 64 + lane)) * 8);
        #pragma unroll
        for (int c = 0; c < 8; c++)
            acc[c] = mfma16(a, *(const half8*)(W + ((size_t)((s * 16 + nh * 8 + c) * 64 + lane)) * 8), acc[c]);
    }
    float y[8][4];
    float psum[4] = {0,0,0,0}, psq[4] = {0,0,0,0};
    #pragma unroll
    for (int c = 0; c < 8; c++) {
        int n = nh * 128 + c * 16 + ln;
        float bv = bf2[n];
        #pragma unroll
        for (int r = 0; r < 4; r++) {
            int m = mb + quad * 4 + r;
            float v = acc[c][r] + bv + res[(size_t)m * D2_ + n];
            y[c][r] = v; psum[r] += v; psq[r] += v * v;
        }
    }
    #pragma unroll
    for (int off = 1; off < 16; off <<= 1)
        #pragma unroll
        for (int r = 0; r < 4; r++) { psum[r] += __shfl_xor(psum[r], off); psq[r] += __shfl_xor(psq[r], off); }
    if (ln == 0)
        #pragma unroll
        for (int r = 0; r < 4; r++) { sst[rt][quad * 4 + r][nh][0] = psum[r]; sst[rt][quad * 4 + r][nh][1] = psq[r]; }
    __syncthreads();
    #pragma unroll
    for (int r = 0; r < 4; r++) {
        float su = sst[rt][quad * 4 + r][0][0] + sst[rt][quad * 4 + r][1][0];
        float sq = sst[rt][quad * 4 + r][0][1] + sst[rt][quad * 4 + r][1][1];
        float mean = su * (1.f / 256.f);
        float var = sq * (1.f / 256.f) - mean * mean;
        float invs = rsqrtf(var + 1e-5f);
        #pragma unroll
        for (int c = 0; c < 8; c++) {
            int n = nh * 128 + c * 16 + ln;
            float yn = (y[c][r] - mean) * invs * g3[n] + b3[n];
            int s_x = n >> 5, q_x = (n >> 3) & 3, j = n & 7;
            xn2[((size_t)((lt * 8 + s_x) * 64 + q_x * 16 + (quad * 4 + r))) * 8 + j] = (_Float16)yn;
        }
    }
}

// out = xn2 @ Wo + bo [M x 55] fp32. Block: 2 rowtiles x 2 K-halves, LDS combine.
__global__ __launch_bounds__(256) void out_kernel(const _Float16* xn2, const _Float16* wsw,
        const float* bo, float* out) {
    __shared__ f32x4 pc[2][4][64];
    int w = threadIdx.x >> 6, lane = threadIdx.x & 63;
    int quad = lane >> 4, ln = lane & 15;
    int rt = w & 1, kh = w >> 1;
    int mb = blockIdx.x * 32 + rt * 16;
    int lt = mb >> 4;
    const _Float16* W = wsw + WO_OFF;   // K=256, N=64(padded), nc=4

    f32x4 acc[4];
    #pragma unroll
    for (int c = 0; c < 4; c++) acc[c] = f32x4{0,0,0,0};
    #pragma unroll
    for (int ss = 0; ss < 4; ss++) {
        int s = kh * 4 + ss;
        half8 a = *(const half8*)(xn2 + ((size_t)((lt * 8 + s) * 64 + lane)) * 8);
        #pragma unroll
        for (int c = 0; c < 4; c++)
            acc[c] = mfma16(a, *(const half8*)(W + ((size_t)((s * 4 + c) * 64 + lane)) * 8), acc[c]);
    }
    if (kh == 1)
        #pragma unroll
        for (int c = 0; c < 4; c++) pc[rt][c][lane] = acc[c];
    __syncthreads();
    if (kh == 0) {
        #pragma unroll
        for (int c = 0; c < 4; c++) {
            f32x4 p = pc[rt][c][lane];
            int n = c * 16 + ln;
            if (n < OUT_) {
                float bv = bo[n];
                #pragma unroll
                for (int r = 0; r < 4; r++)
                    out[(size_t)(mb + quad * 4 + r) * OUT_ + n] = acc[c][r] + p[r] + bv;
            }
        }
    }
}

extern "C" void kernel_launch(void* const* d_in, const int* in_sizes, int n_in,
                              void* d_out, int out_size, void* d_ws, size_t ws_size,
                              hipStream_t stream) {
    const float* x1    = (const float*)d_in[0];
    const float* x2    = (const float*)d_in[1];
    const float* ln1_g = (const float*)d_in[2];
    const float* ln1_b = (const float*)d_in[3];
    const float* ln2_g = (const float*)d_in[4];
    const float* ln2_b = (const float*)d_in[5];
    const float* Wq    = (const float*)d_in[6];
    const float* bq    = (const float*)d_in[7];
    const float* Wv1   = (const float*)d_in[8];
    const float* bv1   = (const float*)d_in[9];
    const float* Wk    = (const float*)d_in[10];
    const float* bk    = (const float*)d_in[11];
    const float* Wv2   = (const float*)d_in[12];
    const float* bv2   = (const float*)d_in[13];
    const float* Wp1   = (const float*)d_in[14];
    const float* bp1   = (const float*)d_in[15];
    const float* Wp2   = (const float*)d_in[16];
    const float* bp2   = (const float*)d_in[17];
    const float* lnf_g = (const float*)d_in[18];
    const float* lnf_b = (const float*)d_in[19];
    const float* Wf1   = (const float*)d_in[20];
    const float* bf1   = (const float*)d_in[21];
    const float* Wf2   = (const float*)d_in[22];
    const float* bf2   = (const float*)d_in[23];
    const float* ln3_g = (const float*)d_in[24];
    const float* ln3_b = (const float*)d_in[25];
    const float* Wo    = (const float*)d_in[26];
    const float* bo    = (const float*)d_in[27];
    float* out = (float*)d_out;

    char* ws = (char*)d_ws;
    const size_t MB = 1 << 20;
    _Float16* x1n  = (_Float16*)(ws + 0 * MB);    // 4 MB
    _Float16* x2n  = (_Float16*)(ws + 4 * MB);    // 4 MB
    _Float16* q1sw = (_Float16*)(ws + 8 * MB);    // 4 MB
    _Float16* k2sw = (_Float16*)(ws + 12 * MB);   // 4 MB
    _Float16* v1sw = (_Float16*)(ws + 16 * MB);   // 4 MB
    _Float16* v2sw = (_Float16*)(ws + 20 * MB);   // 4 MB
    float*    res  = (float*)   (ws + 24 * MB);   // 16 MB
    _Float16* xn   = (_Float16*)(ws + 40 * MB);   // 8 MB
    _Float16* h    = (_Float16*)(ws + 48 * MB);   // 16 MB
    _Float16* xn2  = (_Float16*)(ws + 64 * MB);   // 8 MB
    _Float16* wsw  = (_Float16*)(ws + 72 * MB);   // ~0.74 MB

    prep_kernel<<<dim3(512, 9), 256, 0, stream>>>(Wq, Wv1, Wk, Wv2, Wp1, Wp2, Wf1, Wf2, Wo, wsw);
    ln_kernel<<<dim3(M_ / 4, 2), 256, 0, stream>>>(x1, x2, ln1_g, ln1_b, ln2_g, ln2_b, x1n, x2n);
    proj_kernel<<<dim3(M_ / 64, 4), 256, 0, stream>>>(x1n, x2n, wsw, bq, bv1, bk, bv2,
                                                      q1sw, k2sw, v1sw, v2sw);
    flash_kernel<<<dim3(1024), 256, 0, stream>>>(q1sw, k2sw, v1sw, v2sw, wsw, bp1, bp2,
                                                 x1, x2, lnf_g, lnf_b, res, xn);
    ffn1_kernel<<<dim3(M_ / 64, 4), 256, 0, stream>>>(xn, wsw, bf1, h);
    ffn2_kernel<<<dim3(M_ / 32), 256, 0, stream>>>(h, wsw, bf2, res, ln3_g, ln3_b, xn2);
    out_kernel<<<dim3(M_ / 32), 256, 0, stream>>>(xn2, wsw, bo, out);
}

// Round 5
// 361.657 us; speedup vs baseline: 1.6788x; 1.6788x over previous
//
#include <hip/hip_runtime.h>
#include <hip/hip_fp16.h>

typedef _Float16 half8 __attribute__((ext_vector_type(8)));
typedef float f32x4 __attribute__((ext_vector_type(4)));

#define B_   4
#define L_   4096
#define D_   128
#define M_   (B_*L_)     // 16384
#define D2_  256
#define H_   512
#define OUT_ 55

__device__ __forceinline__ f32x4 mfma16(half8 a, half8 b, f32x4 c) {
    return __builtin_amdgcn_mfma_f32_16x16x32_f16(a, b, c, 0, 0, 0);
}

// ---- weight swizzle offsets (in halfs) within wsw region ----
#define WQ_OFF   0
#define WV1_OFF  16384
#define WK_OFF   32768
#define WV2_OFF  49152
#define WP1_OFF  65536
#define WP2_OFF  81920
#define WF1_OFF  98304     // 256x512 = 131072
#define WF2_OFF  229376    // 512x256 = 131072
#define WO_OFF   360448    // 256x64 (padded) = 16384

// Pre-swizzle weights (fp32 row-major [K][N]) into B-fragment layout fp16:
// idx = ((s*nc + c)*64 + lane)*8 + j ; s=k>>5, q=(k>>3)&3, j=k&7, c=n>>4, ln=n&15, lane=q*16+ln
__global__ void prep_kernel(const float* Wq, const float* Wv1, const float* Wk,
                            const float* Wv2, const float* Wp1, const float* Wp2,
                            const float* Wf1, const float* Wf2, const float* Wo,
                            _Float16* wsw) {
    int id = blockIdx.y;
    int t  = blockIdx.x * 256 + threadIdx.x;
    const float* src = nullptr; int K = 0, N = 0, Npad = 0, off = 0;
    switch (id) {
        case 0: src = Wq;  K = 128; N = 128; Npad = 128; off = WQ_OFF;  break;
        case 1: src = Wv1; K = 128; N = 128; Npad = 128; off = WV1_OFF; break;
        case 2: src = Wk;  K = 128; N = 128; Npad = 128; off = WK_OFF;  break;
        case 3: src = Wv2; K = 128; N = 128; Npad = 128; off = WV2_OFF; break;
        case 4: src = Wp1; K = 128; N = 128; Npad = 128; off = WP1_OFF; break;
        case 5: src = Wp2; K = 128; N = 128; Npad = 128; off = WP2_OFF; break;
        case 6: src = Wf1; K = 256; N = 512; Npad = 512; off = WF1_OFF; break;
        case 7: src = Wf2; K = 512; N = 256; Npad = 256; off = WF2_OFF; break;
        case 8: src = Wo;  K = 256; N = 55;  Npad = 64;  off = WO_OFF;  break;
        default: return;
    }
    int total = K * Npad;
    if (t >= total) return;
    int k = t / Npad, n = t % Npad;
    float v = (n < N) ? src[k * N + n] : 0.f;
    int s = k >> 5, q = (k >> 3) & 3, j = k & 7, c = n >> 4, ln = n & 15;
    int nc = Npad >> 4;
    wsw[off + ((size_t)((s * nc + c) * 64 + q * 16 + ln)) * 8 + j] = (_Float16)v;
}

// FR layout for X[M][C] halfs:
// idx = ((lt*(C/32) + s)*64 + q*16 + ln_r)*8 + j ; lt=row>>4, ln_r=row&15,
// s=col>>5, q=(col>>3)&3, j=col&7.  Serves BOTH A-frags (rows) and transposed
// B-frags (cols of X^T) as lane-contiguous 1KB loads.

// LayerNorm over D=128, one wave per token, fp32 in -> fp16 FR-swizzled out
__global__ __launch_bounds__(256) void ln_kernel(const float* x1, const float* x2,
        const float* g1, const float* b1, const float* g2, const float* b2,
        _Float16* x1n, _Float16* x2n) {
    int wave = threadIdx.x >> 6, lane = threadIdx.x & 63;
    int token = blockIdx.x * 4 + wave;
    const float* x = blockIdx.y ? x2 : x1;
    const float* g = blockIdx.y ? g2 : g1;
    const float* bb = blockIdx.y ? b2 : b1;
    _Float16* o = blockIdx.y ? x2n : x1n;
    const float* xr = x + (size_t)token * D_;
    float a0 = xr[lane], a1 = xr[lane + 64];
    float s = a0 + a1, s2 = a0 * a0 + a1 * a1;
    #pragma unroll
    for (int off = 1; off < 64; off <<= 1) {
        s += __shfl_xor(s, off);
        s2 += __shfl_xor(s2, off);
    }
    float mean = s * (1.f / 128.f);
    float var = s2 * (1.f / 128.f) - mean * mean;
    float inv = rsqrtf(var + 1e-5f);
    int lt = token >> 4, ln_r = token & 15;
    #pragma unroll
    for (int h = 0; h < 2; h++) {
        int col = lane + h * 64;
        float v = (h ? a1 : a0);
        float out = (v - mean) * inv * g[col] + bb[col];
        int ss = col >> 5, q = (col >> 3) & 3, j = col & 7;
        o[((size_t)((lt * 4 + ss) * 64 + q * 16 + ln_r)) * 8 + j] = (_Float16)out;
    }
}

// Projections. q1/k2 FR-swizzled (global M); v1/v2 merged into vsw: per-batch
// B-frag layout [k=4096][n=256] (V1 cols 0-127, V2 cols 128-255):
// idx = ((s*16 + c)*64 + q*16 + ln)*8 + j ; s=k>>5, c=n>>4.
__global__ __launch_bounds__(256) void proj_kernel(const _Float16* x1n, const _Float16* x2n,
        const _Float16* wsw, const float* bq, const float* bv1, const float* bk,
        const float* bv2, _Float16* q1, _Float16* k2, _Float16* vsw) {
    int g = blockIdx.y;   // 0:Wq 1:Wv1 2:Wk 3:Wv2
    const _Float16* A = (g < 2) ? x1n : x2n;
    const _Float16* Bw = wsw + g * 16384;
    const float* bias = (g == 0) ? bq : (g == 1) ? bv1 : (g == 2) ? bk : bv2;
    int wave = threadIdx.x >> 6, lane = threadIdx.x & 63;
    int quad = lane >> 4, ln = lane & 15;
    int mbase = blockIdx.x * 64 + wave * 16;
    int lt = mbase >> 4;

    half8 a[4];
    #pragma unroll
    for (int s = 0; s < 4; s++)
        a[s] = *(const half8*)(A + ((size_t)((lt * 4 + s) * 64 + lane)) * 8);

    f32x4 acc[8];
    #pragma unroll
    for (int c = 0; c < 8; c++) {
        acc[c] = f32x4{0.f, 0.f, 0.f, 0.f};
        #pragma unroll
        for (int s = 0; s < 4; s++) {
            half8 bf = *(const half8*)(Bw + ((size_t)((s * 8 + c) * 64 + lane)) * 8);
            acc[c] = mfma16(a[s], bf, acc[c]);
        }
    }
    bool isV = (g == 1) || (g == 3);
    int cbase = (g == 3) ? 8 : 0;
    _Float16* out = (g == 0) ? q1 : (g == 2) ? k2 : vsw;
    #pragma unroll
    for (int c = 0; c < 8; c++) {
        int n = c * 16 + ln;
        float bv = bias[n];
        #pragma unroll
        for (int r = 0; r < 4; r++) {
            int m = mbase + quad * 4 + r;
            float val = acc[c][r] + bv;
            if (!isV) {
                int s_o = c >> 1, q_o = ((c & 1) << 1) | (ln >> 3), j = ln & 7;
                out[((size_t)((lt * 4 + s_o) * 64 + q_o * 16 + (quad * 4 + r))) * 8 + j]
                    = (_Float16)val;
            } else {
                int b = m >> 12, l = m & (L_ - 1);
                int s_v = l >> 5, q2 = (l >> 3) & 3, j = l & 7;
                out[(size_t)b * (L_ * D2_) +
                    (((size_t)((s_v * 16 + cbase + c) * 64 + q2 * 16 + ln)) * 8 + j)]
                    = (_Float16)val;
            }
        }
    }
}

__global__ __launch_bounds__(256) void zero_kernel(float* rowsum) {
    int i = (blockIdx.x * 256 + threadIdx.x) * 4;
    *(f32x4*)(rowsum + i) = f32x4{0.f, 0.f, 0.f, 0.f};
}

// Pass 1: P = exp(scale * k2 . q1^T), written in FR-A layout (per batch, C=4096)
// + per-row sums via atomics. Block = 128x128 tile, 4 waves of 64x64 (4x4 frags).
// B-frags direct from L2 (FR layout = 1KB coalesced loads, 0.5 KB/MFMA).
__global__ __launch_bounds__(256) void score_kernel(
        const _Float16* __restrict__ q1sw, const _Float16* __restrict__ k2sw,
        _Float16* __restrict__ pmat, float* __restrict__ rowsum) {
    __shared__ _Float16 T[4][64 * 72];
    int w = threadIdx.x >> 6, lane = threadIdx.x & 63;
    int quad = lane >> 4, ln = lane & 15;
    int b = blockIdx.z;
    int rowL0 = blockIdx.y * 128 + (w & 1) * 64;   // att-row base (k2 rows)
    int colL0 = blockIdx.x * 128 + (w >> 1) * 64;  // col base (q1 rows)
    int ltr = ((b << 12) + rowL0) >> 4;
    int ltc = ((b << 12) + colL0) >> 4;

    f32x4 acc[4][4];
    #pragma unroll
    for (int i = 0; i < 4; i++)
        #pragma unroll
        for (int j = 0; j < 4; j++) acc[i][j] = f32x4{0.f, 0.f, 0.f, 0.f};

    #pragma unroll
    for (int s = 0; s < 4; s++) {
        half8 a[4], bq[4];
        #pragma unroll
        for (int i = 0; i < 4; i++)
            a[i] = *(const half8*)(k2sw + ((size_t)(((ltr + i) * 4 + s) * 64 + lane)) * 8);
        #pragma unroll
        for (int j = 0; j < 4; j++)
            bq[j] = *(const half8*)(q1sw + ((size_t)(((ltc + j) * 4 + s) * 64 + lane)) * 8);
        #pragma unroll
        for (int i = 0; i < 4; i++)
            #pragma unroll
            for (int j = 0; j < 4; j++)
                acc[i][j] = mfma16(a[i], bq[j], acc[i][j]);
    }

    const float scale = 0.08838834764831845f;   // 1/sqrt(128)
    _Float16* Tw = T[w];
    #pragma unroll
    for (int i = 0; i < 4; i++) {
        float rsum[4] = {0.f, 0.f, 0.f, 0.f};
        #pragma unroll
        for (int j = 0; j < 4; j++)
            #pragma unroll
            for (int r = 0; r < 4; r++) {
                float p = __expf(acc[i][j][r] * scale);
                rsum[r] += p;
                Tw[(i * 16 + quad * 4 + r) * 72 + j * 16 + ln] = (_Float16)p;
            }
        #pragma unroll
        for (int off = 1; off < 16; off <<= 1)
            #pragma unroll
            for (int r = 0; r < 4; r++) rsum[r] += __shfl_xor(rsum[r], off);
        if (ln == 0)
            #pragma unroll
            for (int r = 0; r < 4; r++)
                atomicAdd(&rowsum[(b << 12) + rowL0 + i * 16 + quad * 4 + r], rsum[r]);
    }
    // LDS transpose -> coalesced FR stores (same-wave LDS write->read, in-order)
    _Float16* Pb = pmat + (size_t)b * ((size_t)L_ * L_);
    #pragma unroll
    for (int li = 0; li < 4; li++)
        #pragma unroll
        for (int si = 0; si < 2; si++) {
            half8 v = *(const half8*)(Tw + (li * 16 + ln) * 72 + si * 32 + quad * 8);
            int ltL = (rowL0 >> 4) + li;
            int sL = (colL0 >> 5) + si;
            *(half8*)(Pb + ((size_t)((ltL * 128 + sL) * 64 + lane)) * 8) = v;
        }
}

// Pass 2: O = P . V (dual streams via blockIdx.y), LDS-staged double-buffered
// GEMM (BK=32). Block 64 rows x 128 cols, 4 waves of 32x64 (acc 32 regs).
// Epilogue: normalize by rowsum, FR-layout att1/att2 via LDS transpose.
__global__ __launch_bounds__(256) void pv_kernel(
        const _Float16* __restrict__ pmat, const _Float16* __restrict__ vsw,
        const float* __restrict__ rowsum,
        _Float16* __restrict__ att1, _Float16* __restrict__ att2) {
    __shared__ _Float16 Ab[2][2048];   // 64 rows x 32 k per buf
    __shared__ _Float16 Bb[2][4096];   // 32 k x 128 n per buf
    __shared__ _Float16 T[4][32 * 72];
    int w = threadIdx.x >> 6, lane = threadIdx.x & 63;
    int quad = lane >> 4, ln = lane & 15;
    int rowG0 = blockIdx.x * 64;
    int b = rowG0 >> 12;
    int rowL0 = rowG0 & (L_ - 1);
    int nh = blockIdx.y;               // 0 -> att1, 1 -> att2
    const _Float16* Pb = pmat + (size_t)b * ((size_t)L_ * L_);
    const _Float16* Vb = vsw + (size_t)b * (L_ * D2_);

    int rh = w & 1, ch = w >> 1;
    f32x4 acc[2][4];
    #pragma unroll
    for (int i = 0; i < 2; i++)
        #pragma unroll
        for (int j = 0; j < 4; j++) acc[i][j] = f32x4{0.f, 0.f, 0.f, 0.f};

    // stage tile kt into buf (each wave: 1 A-chunk + 2 B-chunks)
    #define STAGE(buf, kt) do {                                                     \
        half8 av = *(const half8*)(Pb + ((size_t)((((rowL0 >> 4) + w) * 128 + (kt)) * 64 + lane)) * 8); \
        *(half8*)&Ab[buf][(size_t)(w * 64 + lane) * 8] = av;                        \
        _Pragma("unroll")                                                           \
        for (int t = 0; t < 2; t++) {                                               \
            int c = w * 2 + t;                                                      \
            half8 bv = *(const half8*)(Vb + ((size_t)(((kt) * 16 + nh * 8 + c) * 64 + lane)) * 8); \
            *(half8*)&Bb[buf][(size_t)(c * 64 + lane) * 8] = bv;                    \
        }                                                                           \
    } while (0)

    STAGE(0, 0);
    __syncthreads();
    for (int kt = 0; kt < 128; kt++) {
        int buf = kt & 1;
        if (kt + 1 < 128) STAGE(buf ^ 1, kt + 1);
        half8 a0 = *(const half8*)&Ab[buf][(size_t)((rh * 2 + 0) * 64 + lane) * 8];
        half8 a1 = *(const half8*)&Ab[buf][(size_t)((rh * 2 + 1) * 64 + lane) * 8];
        #pragma unroll
        for (int j = 0; j < 4; j++) {
            half8 bv = *(const half8*)&Bb[buf][(size_t)((ch * 4 + j) * 64 + lane) * 8];
            acc[0][j] = mfma16(a0, bv, acc[0][j]);
            acc[1][j] = mfma16(a1, bv, acc[1][j]);
        }
        __syncthreads();
    }
    #undef STAGE

    // normalize + transpose + FR store
    _Float16* Tw = T[w];
    #pragma unroll
    for (int i = 0; i < 2; i++) {
        float inv[4];
        #pragma unroll
        for (int r = 0; r < 4; r++)
            inv[r] = 1.f / rowsum[rowG0 + rh * 32 + i * 16 + quad * 4 + r];
        #pragma unroll
        for (int j = 0; j < 4; j++)
            #pragma unroll
            for (int r = 0; r < 4; r++)
                Tw[(i * 16 + quad * 4 + r) * 72 + j * 16 + ln]
                    = (_Float16)(acc[i][j][r] * inv[r]);
    }
    _Float16* att = nh ? att2 : att1;
    #pragma unroll
    for (int li = 0; li < 2; li++)
        #pragma unroll
        for (int si = 0; si < 2; si++) {
            half8 v = *(const half8*)(Tw + (li * 16 + ln) * 72 + si * 32 + quad * 8);
            int ltm = ((rowG0 + rh * 32) >> 4) + li;
            int sp = ch * 2 + si;
            *(half8*)(att + ((size_t)((ltm * 4 + sp) * 64 + lane)) * 8) = v;
        }
}

// out_s = att_s @ Wp_s + bias + residual ; concat -> res (fp32) ; LNf -> xn (FR fp16)
__global__ __launch_bounds__(256) void attn_out_kernel(const _Float16* att1, const _Float16* att2,
        const _Float16* wsw, const float* bp1, const float* bp2,
        const float* x1, const float* x2, const float* lnf_g, const float* lnf_b,
        float* res, _Float16* xn) {
    int wave = threadIdx.x >> 6, lane = threadIdx.x & 63;
    int quad = lane >> 4, ln = lane & 15;
    int mbase = blockIdx.x * 64 + wave * 16;
    int lt = mbase >> 4;
    const _Float16* Wp1 = wsw + WP1_OFF;
    const _Float16* Wp2 = wsw + WP2_OFF;

    half8 a1[4], a2[4];
    #pragma unroll
    for (int s = 0; s < 4; s++) {
        a1[s] = *(const half8*)(att1 + ((size_t)((lt * 4 + s) * 64 + lane)) * 8);
        a2[s] = *(const half8*)(att2 + ((size_t)((lt * 4 + s) * 64 + lane)) * 8);
    }
    f32x4 y1[8], y2[8];
    #pragma unroll
    for (int c = 0; c < 8; c++) {
        y1[c] = f32x4{0,0,0,0}; y2[c] = f32x4{0,0,0,0};
        #pragma unroll
        for (int s = 0; s < 4; s++) {
            y1[c] = mfma16(a1[s], *(const half8*)(Wp1 + ((size_t)((s * 8 + c) * 64 + lane)) * 8), y1[c]);
            y2[c] = mfma16(a2[s], *(const half8*)(Wp2 + ((size_t)((s * 8 + c) * 64 + lane)) * 8), y2[c]);
        }
    }
    #pragma unroll
    for (int c = 0; c < 8; c++) {
        int n = c * 16 + ln;
        float b1v = bp1[n], b2v = bp2[n];
        #pragma unroll
        for (int r = 0; r < 4; r++) {
            int m = mbase + quad * 4 + r;
            y1[c][r] += b1v + x1[(size_t)m * D_ + n];
            y2[c][r] += b2v + x2[(size_t)m * D_ + n];
        }
    }
    float sum[4] = {0,0,0,0}, sq[4] = {0,0,0,0};
    #pragma unroll
    for (int c = 0; c < 8; c++)
        #pragma unroll
        for (int r = 0; r < 4; r++) {
            sum[r] += y1[c][r] + y2[c][r];
            sq[r]  += y1[c][r] * y1[c][r] + y2[c][r] * y2[c][r];
        }
    #pragma unroll
    for (int off = 1; off < 16; off <<= 1)
        #pragma unroll
        for (int r = 0; r < 4; r++) { sum[r] += __shfl_xor(sum[r], off); sq[r] += __shfl_xor(sq[r], off); }
    #pragma unroll
    for (int r = 0; r < 4; r++) {
        float mean = sum[r] * (1.f / 256.f);
        float var = sq[r] * (1.f / 256.f) - mean * mean;
        float inv = rsqrtf(var + 1e-5f);
        int m = mbase + quad * 4 + r;
        int lt_m = m >> 4;
        #pragma unroll
        for (int c = 0; c < 8; c++) {
            int n = c * 16 + ln;
            res[(size_t)m * D2_ + n]       = y1[c][r];
            res[(size_t)m * D2_ + 128 + n] = y2[c][r];
            float yn1 = (y1[c][r] - mean) * inv * lnf_g[n] + lnf_b[n];
            float yn2 = (y2[c][r] - mean) * inv * lnf_g[128 + n] + lnf_b[128 + n];
            int s_x = n >> 5, q_x = (n >> 3) & 3, j = n & 7;
            xn[((size_t)((lt_m * 8 + s_x) * 64 + q_x * 16 + (m & 15))) * 8 + j] = (_Float16)yn1;
            int n2 = 128 + n;
            int s_y = n2 >> 5, q_y = (n2 >> 3) & 3, j2 = n2 & 7;
            xn[((size_t)((lt_m * 8 + s_y) * 64 + q_y * 16 + (m & 15))) * 8 + j2] = (_Float16)yn2;
        }
    }
}

// h = gelu(xn @ Wf1 + bf1)  [M x 512], FR-swizzled in/out
__global__ __launch_bounds__(256) void ffn1_kernel(const _Float16* xn, const _Float16* wsw,
        const float* bf1, _Float16* h) {
    int wave = threadIdx.x >> 6, lane = threadIdx.x & 63;
    int quad = lane >> 4, ln = lane & 15;
    int mbase = blockIdx.x * 64 + wave * 16;
    int lt = mbase >> 4;
    int nt = blockIdx.y;   // 0..3
    const _Float16* W = wsw + WF1_OFF;   // K=256, N=512, nc=32

    half8 a[8];
    #pragma unroll
    for (int s = 0; s < 8; s++)
        a[s] = *(const half8*)(xn + ((size_t)((lt * 8 + s) * 64 + lane)) * 8);

    f32x4 acc[8];
    #pragma unroll
    for (int c = 0; c < 8; c++) {
        acc[c] = f32x4{0,0,0,0};
        int cg = nt * 8 + c;
        #pragma unroll
        for (int s = 0; s < 8; s++)
            acc[c] = mfma16(a[s], *(const half8*)(W + ((size_t)((s * 32 + cg) * 64 + lane)) * 8), acc[c]);
    }
    #pragma unroll
    for (int c = 0; c < 8; c++) {
        int n = nt * 128 + c * 16 + ln;
        float bv = bf1[n];
        int s_h = n >> 5, q_h = (n >> 3) & 3, j = n & 7;
        #pragma unroll
        for (int r = 0; r < 4; r++) {
            float v = acc[c][r] + bv;
            float ge = 0.5f * v * (1.f + erff(v * 0.70710678118654752f));
            h[((size_t)((lt * 16 + s_h) * 64 + q_h * 16 + (quad * 4 + r))) * 8 + j] = (_Float16)ge;
        }
    }
}

// x = LN3(h @ Wf2 + bf2 + res) -> xn2 (FR-swizzled fp16). Block: 2 rowtiles x 2 N-halves.
__global__ __launch_bounds__(256) void ffn2_kernel(const _Float16* h, const _Float16* wsw,
        const float* bf2, const float* res, const float* g3, const float* b3, _Float16* xn2) {
    __shared__ float sst[2][16][2][2];
    int w = threadIdx.x >> 6, lane = threadIdx.x & 63;
    int quad = lane >> 4, ln = lane & 15;
    int rt = w & 1, nh = w >> 1;
    int mb = blockIdx.x * 32 + rt * 16;
    int lt = mb >> 4;
    const _Float16* W = wsw + WF2_OFF;   // K=512, N=256, nc=16

    f32x4 acc[8];
    #pragma unroll
    for (int c = 0; c < 8; c++) acc[c] = f32x4{0,0,0,0};
    for (int s = 0; s < 16; s++) {
        half8 a = *(const half8*)(h + ((size_t)((lt * 16 + s) * 64 + lane)) * 8);
        #pragma unroll
        for (int c = 0; c < 8; c++)
            acc[c] = mfma16(a, *(const half8*)(W + ((size_t)((s * 16 + nh * 8 + c) * 64 + lane)) * 8), acc[c]);
    }
    float y[8][4];
    float psum[4] = {0,0,0,0}, psq[4] = {0,0,0,0};
    #pragma unroll
    for (int c = 0; c < 8; c++) {
        int n = nh * 128 + c * 16 + ln;
        float bv = bf2[n];
        #pragma unroll
        for (int r = 0; r < 4; r++) {
            int m = mb + quad * 4 + r;
            float v = acc[c][r] + bv + res[(size_t)m * D2_ + n];
            y[c][r] = v; psum[r] += v; psq[r] += v * v;
        }
    }
    #pragma unroll
    for (int off = 1; off < 16; off <<= 1)
        #pragma unroll
        for (int r = 0; r < 4; r++) { psum[r] += __shfl_xor(psum[r], off); psq[r] += __shfl_xor(psq[r], off); }
    if (ln == 0)
        #pragma unroll
        for (int r = 0; r < 4; r++) { sst[rt][quad * 4 + r][nh][0] = psum[r]; sst[rt][quad * 4 + r][nh][1] = psq[r]; }
    __syncthreads();
    #pragma unroll
    for (int r = 0; r < 4; r++) {
        float su = sst[rt][quad * 4 + r][0][0] + sst[rt][quad * 4 + r][1][0];
        float sq = sst[rt][quad * 4 + r][0][1] + sst[rt][quad * 4 + r][1][1];
        float mean = su * (1.f / 256.f);
        float var = sq * (1.f / 256.f) - mean * mean;
        float invs = rsqrtf(var + 1e-5f);
        #pragma unroll
        for (int c = 0; c < 8; c++) {
            int n = nh * 128 + c * 16 + ln;
            float yn = (y[c][r] - mean) * invs * g3[n] + b3[n];
            int s_x = n >> 5, q_x = (n >> 3) & 3, j = n & 7;
            xn2[((size_t)((lt * 8 + s_x) * 64 + q_x * 16 + (quad * 4 + r))) * 8 + j] = (_Float16)yn;
        }
    }
}

// out = xn2 @ Wo + bo [M x 55] fp32. Block: 2 rowtiles x 2 K-halves, LDS combine.
__global__ __launch_bounds__(256) void out_kernel(const _Float16* xn2, const _Float16* wsw,
        const float* bo, float* out) {
    __shared__ f32x4 pc[2][4][64];
    int w = threadIdx.x >> 6, lane = threadIdx.x & 63;
    int quad = lane >> 4, ln = lane & 15;
    int rt = w & 1, kh = w >> 1;
    int mb = blockIdx.x * 32 + rt * 16;
    int lt = mb >> 4;
    const _Float16* W = wsw + WO_OFF;   // K=256, N=64(padded), nc=4

    f32x4 acc[4];
    #pragma unroll
    for (int c = 0; c < 4; c++) acc[c] = f32x4{0,0,0,0};
    #pragma unroll
    for (int ss = 0; ss < 4; ss++) {
        int s = kh * 4 + ss;
        half8 a = *(const half8*)(xn2 + ((size_t)((lt * 8 + s) * 64 + lane)) * 8);
        #pragma unroll
        for (int c = 0; c < 4; c++)
            acc[c] = mfma16(a, *(const half8*)(W + ((size_t)((s * 4 + c) * 64 + lane)) * 8), acc[c]);
    }
    if (kh == 1)
        #pragma unroll
        for (int c = 0; c < 4; c++) pc[rt][c][lane] = acc[c];
    __syncthreads();
    if (kh == 0) {
        #pragma unroll
        for (int c = 0; c < 4; c++) {
            f32x4 p = pc[rt][c][lane];
            int n = c * 16 + ln;
            if (n < OUT_) {
                float bv = bo[n];
                #pragma unroll
                for (int r = 0; r < 4; r++)
                    out[(size_t)(mb + quad * 4 + r) * OUT_ + n] = acc[c][r] + p[r] + bv;
            }
        }
    }
}

extern "C" void kernel_launch(void* const* d_in, const int* in_sizes, int n_in,
                              void* d_out, int out_size, void* d_ws, size_t ws_size,
                              hipStream_t stream) {
    const float* x1    = (const float*)d_in[0];
    const float* x2    = (const float*)d_in[1];
    const float* ln1_g = (const float*)d_in[2];
    const float* ln1_b = (const float*)d_in[3];
    const float* ln2_g = (const float*)d_in[4];
    const float* ln2_b = (const float*)d_in[5];
    const float* Wq    = (const float*)d_in[6];
    const float* bq    = (const float*)d_in[7];
    const float* Wv1   = (const float*)d_in[8];
    const float* bv1   = (const float*)d_in[9];
    const float* Wk    = (const float*)d_in[10];
    const float* bk    = (const float*)d_in[11];
    const float* Wv2   = (const float*)d_in[12];
    const float* bv2   = (const float*)d_in[13];
    const float* Wp1   = (const float*)d_in[14];
    const float* bp1   = (const float*)d_in[15];
    const float* Wp2   = (const float*)d_in[16];
    const float* bp2   = (const float*)d_in[17];
    const float* lnf_g = (const float*)d_in[18];
    const float* lnf_b = (const float*)d_in[19];
    const float* Wf1   = (const float*)d_in[20];
    const float* bf1   = (const float*)d_in[21];
    const float* Wf2   = (const float*)d_in[22];
    const float* bf2   = (const float*)d_in[23];
    const float* ln3_g = (const float*)d_in[24];
    const float* ln3_b = (const float*)d_in[25];
    const float* Wo    = (const float*)d_in[26];
    const float* bo    = (const float*)d_in[27];
    float* out = (float*)d_out;

    char* ws = (char*)d_ws;
    const size_t MB = 1 << 20;
    _Float16* q1sw = (_Float16*)(ws + 0 * MB);    // 4 MB
    _Float16* k2sw = (_Float16*)(ws + 4 * MB);    // 4 MB
    _Float16* vsw  = (_Float16*)(ws + 8 * MB);    // 8 MB (V1|V2 B-layout per batch)
    _Float16* att1 = (_Float16*)(ws + 16 * MB);   // 4 MB
    _Float16* att2 = (_Float16*)(ws + 20 * MB);   // 4 MB
    _Float16* x1n  = (_Float16*)(ws + 24 * MB);   // 4 MB
    _Float16* x2n  = (_Float16*)(ws + 28 * MB);   // 4 MB
    _Float16* wsw  = (_Float16*)(ws + 32 * MB);   // ~0.74 MB
    float*    rowsum = (float*) (ws + 33 * MB);   // 64 KB
    float*    res  = (float*)   (ws + 34 * MB);   // 16 MB
    _Float16* xn   = (_Float16*)(ws + 50 * MB);   // 8 MB
    _Float16* h    = (_Float16*)(ws + 58 * MB);   // 16 MB
    _Float16* xn2  = (_Float16*)(ws + 74 * MB);   // 8 MB
    _Float16* pmat = (_Float16*)(ws + 82 * MB);   // 128 MB (P, FR-A layout per batch)

    prep_kernel<<<dim3(512, 9), 256, 0, stream>>>(Wq, Wv1, Wk, Wv2, Wp1, Wp2, Wf1, Wf2, Wo, wsw);
    ln_kernel<<<dim3(M_ / 4, 2), 256, 0, stream>>>(x1, x2, ln1_g, ln1_b, ln2_g, ln2_b, x1n, x2n);
    proj_kernel<<<dim3(M_ / 64, 4), 256, 0, stream>>>(x1n, x2n, wsw, bq, bv1, bk, bv2,
                                                      q1sw, k2sw, vsw);
    zero_kernel<<<dim3(16), 256, 0, stream>>>(rowsum);
    score_kernel<<<dim3(32, 32, 4), 256, 0, stream>>>(q1sw, k2sw, pmat, rowsum);
    pv_kernel<<<dim3(M_ / 64, 2), 256, 0, stream>>>(pmat, vsw, rowsum, att1, att2);
    attn_out_kernel<<<dim3(M_ / 64), 256, 0, stream>>>(att1, att2, wsw, bp1, bp2,
                                                       x1, x2, lnf_g, lnf_b, res, xn);
    ffn1_kernel<<<dim3(M_ / 64, 4), 256, 0, stream>>>(xn, wsw, bf1, h);
    ffn2_kernel<<<dim3(M_ / 32), 256, 0, stream>>>(h, wsw, bf2, res, ln3_g, ln3_b, xn2);
    out_kernel<<<dim3(M_ / 32), 256, 0, stream>>>(xn2, wsw, bo, out);
}

// Round 6
// 318.476 us; speedup vs baseline: 1.9065x; 1.1356x over previous
//
#include <hip/hip_runtime.h>
#include <hip/hip_fp16.h>

typedef _Float16 half8 __attribute__((ext_vector_type(8)));
typedef float f32x4 __attribute__((ext_vector_type(4)));
typedef long lng2 __attribute__((ext_vector_type(2)));

#define B_   4
#define L_   4096
#define D_   128
#define M_   (B_*L_)     // 16384
#define D2_  256
#define H_   512
#define OUT_ 55

__device__ __forceinline__ f32x4 mfma16(half8 a, half8 b, f32x4 c) {
    return __builtin_amdgcn_mfma_f32_16x16x32_f16(a, b, c, 0, 0, 0);
}
__device__ __forceinline__ f32x4 mfma8(long a, long b, f32x4 c) {
    return __builtin_amdgcn_mfma_f32_16x16x32_fp8_fp8(a, b, c, 0, 0, 0);
}
// pack 4 floats -> 4 fp8 e4m3 bytes (OCP on gfx950)
__device__ __forceinline__ int pk4(float a, float b, float c, float d) {
    int t = __builtin_amdgcn_cvt_pk_fp8_f32(a, b, 0, false);
    return __builtin_amdgcn_cvt_pk_fp8_f32(c, d, t, true);
}

// ---- weight swizzle offsets (in halfs) within wsw region ----
#define WQ_OFF   0
#define WV1_OFF  16384
#define WK_OFF   32768
#define WV2_OFF  49152
#define WP1_OFF  65536
#define WP2_OFF  81920
#define WF1_OFF  98304     // 256x512 = 131072
#define WF2_OFF  229376    // 512x256 = 131072
#define WO_OFF   360448    // 256x64 (padded) = 16384

// Pre-swizzle weights (fp32 row-major [K][N]) into B-fragment layout fp16:
// idx = ((s*nc + c)*64 + lane)*8 + j ; s=k>>5, q=(k>>3)&3, j=k&7, c=n>>4, ln=n&15, lane=q*16+ln
__global__ void prep_kernel(const float* Wq, const float* Wv1, const float* Wk,
                            const float* Wv2, const float* Wp1, const float* Wp2,
                            const float* Wf1, const float* Wf2, const float* Wo,
                            _Float16* wsw) {
    int id = blockIdx.y;
    int t  = blockIdx.x * 256 + threadIdx.x;
    const float* src = nullptr; int K = 0, N = 0, Npad = 0, off = 0;
    switch (id) {
        case 0: src = Wq;  K = 128; N = 128; Npad = 128; off = WQ_OFF;  break;
        case 1: src = Wv1; K = 128; N = 128; Npad = 128; off = WV1_OFF; break;
        case 2: src = Wk;  K = 128; N = 128; Npad = 128; off = WK_OFF;  break;
        case 3: src = Wv2; K = 128; N = 128; Npad = 128; off = WV2_OFF; break;
        case 4: src = Wp1; K = 128; N = 128; Npad = 128; off = WP1_OFF; break;
        case 5: src = Wp2; K = 128; N = 128; Npad = 128; off = WP2_OFF; break;
        case 6: src = Wf1; K = 256; N = 512; Npad = 512; off = WF1_OFF; break;
        case 7: src = Wf2; K = 512; N = 256; Npad = 256; off = WF2_OFF; break;
        case 8: src = Wo;  K = 256; N = 55;  Npad = 64;  off = WO_OFF;  break;
        default: return;
    }
    int total = K * Npad;
    if (t >= total) return;
    int k = t / Npad, n = t % Npad;
    float v = (n < N) ? src[k * N + n] : 0.f;
    int s = k >> 5, q = (k >> 3) & 3, j = k & 7, c = n >> 4, ln = n & 15;
    int nc = Npad >> 4;
    wsw[off + ((size_t)((s * nc + c) * 64 + q * 16 + ln)) * 8 + j] = (_Float16)v;
}

// FR layout for X[M][C] halfs:
// idx = ((lt*(C/32) + s)*64 + q*16 + ln_r)*8 + j ; lt=row>>4, ln_r=row&15,
// s=col>>5, q=(col>>3)&3, j=col&7.

// fp8 P layout (per batch, bytes): ((lt*64 + sp)*64 + lane)*16 + sl*8 + j
//   row = lt*16 + (lane&15), k = sp*64 + sl*32 + (lane>>4)*8 + j
// fp8 Vcat layout (per batch, bytes): ((sp*16 + c)*64 + lane)*16 + sl*8 + j
//   k = sp*64 + sl*32 + (lane>>4)*8 + j, n = c*16 + (lane&15)   (n 0..255 = V1|V2)

// LayerNorm over D=128, one wave per token, fp32 in -> fp16 FR-swizzled out
__global__ __launch_bounds__(256) void ln_kernel(const float* x1, const float* x2,
        const float* g1, const float* b1, const float* g2, const float* b2,
        _Float16* x1n, _Float16* x2n) {
    int wave = threadIdx.x >> 6, lane = threadIdx.x & 63;
    int token = blockIdx.x * 4 + wave;
    const float* x = blockIdx.y ? x2 : x1;
    const float* g = blockIdx.y ? g2 : g1;
    const float* bb = blockIdx.y ? b2 : b1;
    _Float16* o = blockIdx.y ? x2n : x1n;
    const float* xr = x + (size_t)token * D_;
    float a0 = xr[lane], a1 = xr[lane + 64];
    float s = a0 + a1, s2 = a0 * a0 + a1 * a1;
    #pragma unroll
    for (int off = 1; off < 64; off <<= 1) {
        s += __shfl_xor(s, off);
        s2 += __shfl_xor(s2, off);
    }
    float mean = s * (1.f / 128.f);
    float var = s2 * (1.f / 128.f) - mean * mean;
    float inv = rsqrtf(var + 1e-5f);
    int lt = token >> 4, ln_r = token & 15;
    #pragma unroll
    for (int h = 0; h < 2; h++) {
        int col = lane + h * 64;
        float v = (h ? a1 : a0);
        float out = (v - mean) * inv * g[col] + bb[col];
        int ss = col >> 5, q = (col >> 3) & 3, j = col & 7;
        o[((size_t)((lt * 4 + ss) * 64 + q * 16 + ln_r)) * 8 + j] = (_Float16)out;
    }
}

// Projections. q1/k2 fp16 FR-swizzled (global M); v1/v2 -> vsw8 fp8 B-frag layout.
__global__ __launch_bounds__(256) void proj_kernel(const _Float16* x1n, const _Float16* x2n,
        const _Float16* wsw, const float* bq, const float* bv1, const float* bk,
        const float* bv2, _Float16* q1, _Float16* k2, unsigned char* vsw8) {
    int g = blockIdx.y;   // 0:Wq 1:Wv1 2:Wk 3:Wv2
    const _Float16* A = (g < 2) ? x1n : x2n;
    const _Float16* Bw = wsw + g * 16384;
    const float* bias = (g == 0) ? bq : (g == 1) ? bv1 : (g == 2) ? bk : bv2;
    int wave = threadIdx.x >> 6, lane = threadIdx.x & 63;
    int quad = lane >> 4, ln = lane & 15;
    int mbase = blockIdx.x * 64 + wave * 16;
    int lt = mbase >> 4;

    half8 a[4];
    #pragma unroll
    for (int s = 0; s < 4; s++)
        a[s] = *(const half8*)(A + ((size_t)((lt * 4 + s) * 64 + lane)) * 8);

    f32x4 acc[8];
    #pragma unroll
    for (int c = 0; c < 8; c++) {
        acc[c] = f32x4{0.f, 0.f, 0.f, 0.f};
        #pragma unroll
        for (int s = 0; s < 4; s++) {
            half8 bf = *(const half8*)(Bw + ((size_t)((s * 8 + c) * 64 + lane)) * 8);
            acc[c] = mfma16(a[s], bf, acc[c]);
        }
    }
    bool isV = (g == 1) || (g == 3);
    if (!isV) {
        _Float16* out = (g == 0) ? q1 : k2;
        #pragma unroll
        for (int c = 0; c < 8; c++) {
            int n = c * 16 + ln;
            float bv = bias[n];
            #pragma unroll
            for (int r = 0; r < 4; r++) {
                int s_o = c >> 1, q_o = ((c & 1) << 1) | (ln >> 3), j = ln & 7;
                out[((size_t)((lt * 4 + s_o) * 64 + q_o * 16 + (quad * 4 + r))) * 8 + j]
                    = (_Float16)(acc[c][r] + bv);
            }
        }
    } else {
        int cbase = (g == 3) ? 8 : 0;
        int b = mbase >> 12;
        int l0 = (mbase & (L_ - 1)) + quad * 4;
        int sp = l0 >> 6, sl = (l0 >> 5) & 1, q2 = (l0 >> 3) & 3, jb = l0 & 7;
        unsigned char* Vb = vsw8 + (size_t)b * (1u << 20);
        #pragma unroll
        for (int c = 0; c < 8; c++) {
            int n = c * 16 + ln;
            float bv = bias[n];
            int pk = pk4(acc[c][0] + bv, acc[c][1] + bv, acc[c][2] + bv, acc[c][3] + bv);
            *(int*)(Vb + (((size_t)(sp * 16 + cbase + c) * 64 + q2 * 16 + ln) * 16 + sl * 8 + jb)) = pk;
        }
    }
}

__global__ __launch_bounds__(256) void zero_kernel(float* rowsum) {
    int i = (blockIdx.x * 256 + threadIdx.x) * 4;
    *(f32x4*)(rowsum + i) = f32x4{0.f, 0.f, 0.f, 0.f};
}

// Pass 1: P = exp(scale * k2 . q1^T) -> fp8 interleaved A-frag layout + rowsums.
// Block = 128x128 tile, 4 waves of 64x64 (4x4 frags), B-frags direct from L2.
__global__ __launch_bounds__(256) void score_kernel(
        const _Float16* __restrict__ q1sw, const _Float16* __restrict__ k2sw,
        unsigned char* __restrict__ pmat8, float* __restrict__ rowsum) {
    __shared__ _Float16 T[4][64 * 72];
    int w = threadIdx.x >> 6, lane = threadIdx.x & 63;
    int quad = lane >> 4, ln = lane & 15;
    int b = blockIdx.z;
    int rowL0 = blockIdx.y * 128 + (w & 1) * 64;   // att-row base (k2 rows), local
    int colL0 = blockIdx.x * 128 + (w >> 1) * 64;  // col base (q1 rows), local
    int ltr = ((b << 12) + rowL0) >> 4;
    int ltc = ((b << 12) + colL0) >> 4;

    f32x4 acc[4][4];
    #pragma unroll
    for (int i = 0; i < 4; i++)
        #pragma unroll
        for (int j = 0; j < 4; j++) acc[i][j] = f32x4{0.f, 0.f, 0.f, 0.f};

    #pragma unroll
    for (int s = 0; s < 4; s++) {
        half8 a[4], bq[4];
        #pragma unroll
        for (int i = 0; i < 4; i++)
            a[i] = *(const half8*)(k2sw + ((size_t)(((ltr + i) * 4 + s) * 64 + lane)) * 8);
        #pragma unroll
        for (int j = 0; j < 4; j++)
            bq[j] = *(const half8*)(q1sw + ((size_t)(((ltc + j) * 4 + s) * 64 + lane)) * 8);
        #pragma unroll
        for (int i = 0; i < 4; i++)
            #pragma unroll
            for (int j = 0; j < 4; j++)
                acc[i][j] = mfma16(a[i], bq[j], acc[i][j]);
    }

    const float scale = 0.08838834764831845f;   // 1/sqrt(128)
    _Float16* Tw = T[w];
    #pragma unroll
    for (int i = 0; i < 4; i++) {
        float rsum[4] = {0.f, 0.f, 0.f, 0.f};
        #pragma unroll
        for (int j = 0; j < 4; j++)
            #pragma unroll
            for (int r = 0; r < 4; r++) {
                float p = __expf(acc[i][j][r] * scale);
                rsum[r] += p;
                Tw[(i * 16 + quad * 4 + r) * 72 + j * 16 + ln] = (_Float16)p;
            }
        #pragma unroll
        for (int off = 1; off < 16; off <<= 1)
            #pragma unroll
            for (int r = 0; r < 4; r++) rsum[r] += __shfl_xor(rsum[r], off);
        if (ln == 0)
            #pragma unroll
            for (int r = 0; r < 4; r++)
                atomicAdd(&rowsum[(b << 12) + rowL0 + i * 16 + quad * 4 + r], rsum[r]);
    }
    // transpose via LDS (same-wave, in-order) -> fp8 pack -> 16B/lane stores
    unsigned char* Pb = pmat8 + (size_t)b * (16u << 20);
    int spw = colL0 >> 6;
    #pragma unroll
    for (int li = 0; li < 4; li++) {
        half8 v0 = *(const half8*)((const char*)Tw + ((li * 16 + ln) * 72 + quad * 8) * 2);
        half8 v1 = *(const half8*)((const char*)Tw + ((li * 16 + ln) * 72 + 32 + quad * 8) * 2);
        int4 d;
        d.x = pk4((float)v0[0], (float)v0[1], (float)v0[2], (float)v0[3]);
        d.y = pk4((float)v0[4], (float)v0[5], (float)v0[6], (float)v0[7]);
        d.z = pk4((float)v1[0], (float)v1[1], (float)v1[2], (float)v1[3]);
        d.w = pk4((float)v1[4], (float)v1[5], (float)v1[6], (float)v1[7]);
        *(int4*)(Pb + (((size_t)(((rowL0 >> 4) + li) * 64 + spw)) * 64 + lane) * 16) = d;
    }
}

// Pass 2: O = P . Vcat, fp8 MFMA, NO LDS staging, NO barriers in K-loop.
// 256 blocks x 4 waves; all waves share the block's 64 rows; wave w owns cols w*64.
// A/B frags direct from global (native frag layouts, 1KB coalesced), register
// double-buffer prefetch of sp+1 during the 32-MFMA burst.
__global__ __launch_bounds__(256) void pv_kernel(
        const unsigned char* __restrict__ pmat8, const unsigned char* __restrict__ vsw8,
        const float* __restrict__ rowsum,
        _Float16* __restrict__ att1, _Float16* __restrict__ att2) {
    __shared__ _Float16 T[4][64 * 72];
    int w = threadIdx.x >> 6, lane = threadIdx.x & 63;
    int quad = lane >> 4, ln = lane & 15;
    int rowG0 = blockIdx.x * 64;
    int b = rowG0 >> 12;
    int lt0 = (rowG0 & (L_ - 1)) >> 4;
    const unsigned char* Pb = pmat8 + (size_t)b * (16u << 20);
    const unsigned char* Vb = vsw8 + (size_t)b * (1u << 20);
    int c0 = w * 4;

    f32x4 acc[4][4];
    #pragma unroll
    for (int i = 0; i < 4; i++)
        #pragma unroll
        for (int c = 0; c < 4; c++) acc[i][c] = f32x4{0.f, 0.f, 0.f, 0.f};

    lng2 Af[4], Bf[4], An[4], Bn[4];
    #pragma unroll
    for (int i = 0; i < 4; i++)
        Af[i] = *(const lng2*)(Pb + (((size_t)(lt0 + i) * 64 + 0) * 64 + lane) * 16);
    #pragma unroll
    for (int c = 0; c < 4; c++)
        Bf[c] = *(const lng2*)(Vb + (((size_t)(0 * 16 + c0 + c) * 64 + lane) * 16));

    for (int sp = 0; sp < 64; sp++) {
        int spn = (sp < 63) ? sp + 1 : 63;
        #pragma unroll
        for (int i = 0; i < 4; i++)
            An[i] = *(const lng2*)(Pb + (((size_t)(lt0 + i) * 64 + spn) * 64 + lane) * 16);
        #pragma unroll
        for (int c = 0; c < 4; c++)
            Bn[c] = *(const lng2*)(Vb + (((size_t)(spn * 16 + c0 + c) * 64 + lane) * 16));
        #pragma unroll
        for (int i = 0; i < 4; i++)
            #pragma unroll
            for (int c = 0; c < 4; c++) {
                acc[i][c] = mfma8(Af[i].x, Bf[c].x, acc[i][c]);
                acc[i][c] = mfma8(Af[i].y, Bf[c].y, acc[i][c]);
            }
        #pragma unroll
        for (int i = 0; i < 4; i++) Af[i] = An[i];
        #pragma unroll
        for (int c = 0; c < 4; c++) Bf[c] = Bn[c];
    }

    // normalize + transpose (per-wave LDS) + FR fp16 att stores
    _Float16* Tw = T[w];
    #pragma unroll
    for (int i = 0; i < 4; i++) {
        float inv[4];
        #pragma unroll
        for (int r = 0; r < 4; r++)
            inv[r] = 1.f / rowsum[rowG0 + i * 16 + quad * 4 + r];
        #pragma unroll
        for (int c = 0; c < 4; c++)
            #pragma unroll
            for (int r = 0; r < 4; r++)
                Tw[(i * 16 + quad * 4 + r) * 72 + c * 16 + ln]
                    = (_Float16)(acc[i][c][r] * inv[r]);
    }
    _Float16* att = (w >= 2) ? att2 : att1;
    int sbase = (w & 1) * 2;
    #pragma unroll
    for (int li = 0; li < 4; li++)
        #pragma unroll
        for (int sl2 = 0; sl2 < 2; sl2++) {
            half8 v = *(const half8*)((const char*)Tw
                        + ((li * 16 + ln) * 72 + sl2 * 32 + quad * 8) * 2);
            int ltG = (rowG0 >> 4) + li;
            *(half8*)(att + ((size_t)((ltG * 4 + sbase + sl2) * 64 + lane)) * 8) = v;
        }
}

// out_s = att_s @ Wp_s + bias + residual ; concat -> res (fp32) ; LNf -> xn (FR fp16)
__global__ __launch_bounds__(256) void attn_out_kernel(const _Float16* att1, const _Float16* att2,
        const _Float16* wsw, const float* bp1, const float* bp2,
        const float* x1, const float* x2, const float* lnf_g, const float* lnf_b,
        float* res, _Float16* xn) {
    int wave = threadIdx.x >> 6, lane = threadIdx.x & 63;
    int quad = lane >> 4, ln = lane & 15;
    int mbase = blockIdx.x * 64 + wave * 16;
    int lt = mbase >> 4;
    const _Float16* Wp1 = wsw + WP1_OFF;
    const _Float16* Wp2 = wsw + WP2_OFF;

    half8 a1[4], a2[4];
    #pragma unroll
    for (int s = 0; s < 4; s++) {
        a1[s] = *(const half8*)(att1 + ((size_t)((lt * 4 + s) * 64 + lane)) * 8);
        a2[s] = *(const half8*)(att2 + ((size_t)((lt * 4 + s) * 64 + lane)) * 8);
    }
    f32x4 y1[8], y2[8];
    #pragma unroll
    for (int c = 0; c < 8; c++) {
        y1[c] = f32x4{0,0,0,0}; y2[c] = f32x4{0,0,0,0};
        #pragma unroll
        for (int s = 0; s < 4; s++) {
            y1[c] = mfma16(a1[s], *(const half8*)(Wp1 + ((size_t)((s * 8 + c) * 64 + lane)) * 8), y1[c]);
            y2[c] = mfma16(a2[s], *(const half8*)(Wp2 + ((size_t)((s * 8 + c) * 64 + lane)) * 8), y2[c]);
        }
    }
    #pragma unroll
    for (int c = 0; c < 8; c++) {
        int n = c * 16 + ln;
        float b1v = bp1[n], b2v = bp2[n];
        #pragma unroll
        for (int r = 0; r < 4; r++) {
            int m = mbase + quad * 4 + r;
            y1[c][r] += b1v + x1[(size_t)m * D_ + n];
            y2[c][r] += b2v + x2[(size_t)m * D_ + n];
        }
    }
    float sum[4] = {0,0,0,0}, sq[4] = {0,0,0,0};
    #pragma unroll
    for (int c = 0; c < 8; c++)
        #pragma unroll
        for (int r = 0; r < 4; r++) {
            sum[r] += y1[c][r] + y2[c][r];
            sq[r]  += y1[c][r] * y1[c][r] + y2[c][r] * y2[c][r];
        }
    #pragma unroll
    for (int off = 1; off < 16; off <<= 1)
        #pragma unroll
        for (int r = 0; r < 4; r++) { sum[r] += __shfl_xor(sum[r], off); sq[r] += __shfl_xor(sq[r], off); }
    #pragma unroll
    for (int r = 0; r < 4; r++) {
        float mean = sum[r] * (1.f / 256.f);
        float var = sq[r] * (1.f / 256.f) - mean * mean;
        float inv = rsqrtf(var + 1e-5f);
        int m = mbase + quad * 4 + r;
        int lt_m = m >> 4;
        #pragma unroll
        for (int c = 0; c < 8; c++) {
            int n = c * 16 + ln;
            res[(size_t)m * D2_ + n]       = y1[c][r];
            res[(size_t)m * D2_ + 128 + n] = y2[c][r];
            float yn1 = (y1[c][r] - mean) * inv * lnf_g[n] + lnf_b[n];
            float yn2 = (y2[c][r] - mean) * inv * lnf_g[128 + n] + lnf_b[128 + n];
            int s_x = n >> 5, q_x = (n >> 3) & 3, j = n & 7;
            xn[((size_t)((lt_m * 8 + s_x) * 64 + q_x * 16 + (m & 15))) * 8 + j] = (_Float16)yn1;
            int n2 = 128 + n;
            int s_y = n2 >> 5, q_y = (n2 >> 3) & 3, j2 = n2 & 7;
            xn[((size_t)((lt_m * 8 + s_y) * 64 + q_y * 16 + (m & 15))) * 8 + j2] = (_Float16)yn2;
        }
    }
}

// h = gelu(xn @ Wf1 + bf1)  [M x 512], FR-swizzled in/out
__global__ __launch_bounds__(256) void ffn1_kernel(const _Float16* xn, const _Float16* wsw,
        const float* bf1, _Float16* h) {
    int wave = threadIdx.x >> 6, lane = threadIdx.x & 63;
    int quad = lane >> 4, ln = lane & 15;
    int mbase = blockIdx.x * 64 + wave * 16;
    int lt = mbase >> 4;
    int nt = blockIdx.y;   // 0..3
    const _Float16* W = wsw + WF1_OFF;   // K=256, N=512, nc=32

    half8 a[8];
    #pragma unroll
    for (int s = 0; s < 8; s++)
        a[s] = *(const half8*)(xn + ((size_t)((lt * 8 + s) * 64 + lane)) * 8);

    f32x4 acc[8];
    #pragma unroll
    for (int c = 0; c < 8; c++) {
        acc[c] = f32x4{0,0,0,0};
        int cg = nt * 8 + c;
        #pragma unroll
        for (int s = 0; s < 8; s++)
            acc[c] = mfma16(a[s], *(const half8*)(W + ((size_t)((s * 32 + cg) * 64 + lane)) * 8), acc[c]);
    }
    #pragma unroll
    for (int c = 0; c < 8; c++) {
        int n = nt * 128 + c * 16 + ln;
        float bv = bf1[n];
        int s_h = n >> 5, q_h = (n >> 3) & 3, j = n & 7;
        #pragma unroll
        for (int r = 0; r < 4; r++) {
            float v = acc[c][r] + bv;
            float ge = 0.5f * v * (1.f + erff(v * 0.70710678118654752f));
            h[((size_t)((lt * 16 + s_h) * 64 + q_h * 16 + (quad * 4 + r))) * 8 + j] = (_Float16)ge;
        }
    }
}

// x = LN3(h @ Wf2 + bf2 + res) -> xn2 (FR-swizzled fp16). Block: 2 rowtiles x 2 N-halves.
__global__ __launch_bounds__(256) void ffn2_kernel(const _Float16* h, const _Float16* wsw,
        const float* bf2, const float* res, const float* g3, const float* b3, _Float16* xn2) {
    __shared__ float sst[2][16][2][2];
    int w = threadIdx.x >> 6, lane = threadIdx.x & 63;
    int quad = lane >> 4, ln = lane & 15;
    int rt = w & 1, nh = w >> 1;
    int mb = blockIdx.x * 32 + rt * 16;
    int lt = mb >> 4;
    const _Float16* W = wsw + WF2_OFF;   // K=512, N=256, nc=16

    f32x4 acc[8];
    #pragma unroll
    for (int c = 0; c < 8; c++) acc[c] = f32x4{0,0,0,0};
    for (int s = 0; s < 16; s++) {
        half8 a = *(const half8*)(h + ((size_t)((lt * 16 + s) * 64 + lane)) * 8);
        #pragma unroll
        for (int c = 0; c < 8; c++)
            acc[c] = mfma16(a, *(const half8*)(W + ((size_t)((s * 16 + nh * 8 + c) * 64 + lane)) * 8), acc[c]);
    }
    float y[8][4];
    float psum[4] = {0,0,0,0}, psq[4] = {0,0,0,0};
    #pragma unroll
    for (int c = 0; c < 8; c++) {
        int n = nh * 128 + c * 16 + ln;
        float bv = bf2[n];
        #pragma unroll
        for (int r = 0; r < 4; r++) {
            int m = mb + quad * 4 + r;
            float v = acc[c][r] + bv + res[(size_t)m * D2_ + n];
            y[c][r] = v; psum[r] += v; psq[r] += v * v;
        }
    }
    #pragma unroll
    for (int off = 1; off < 16; off <<= 1)
        #pragma unroll
        for (int r = 0; r < 4; r++) { psum[r] += __shfl_xor(psum[r], off); psq[r] += __shfl_xor(psq[r], off); }
    if (ln == 0)
        #pragma unroll
        for (int r = 0; r < 4; r++) { sst[rt][quad * 4 + r][nh][0] = psum[r]; sst[rt][quad * 4 + r][nh][1] = psq[r]; }
    __syncthreads();
    #pragma unroll
    for (int r = 0; r < 4; r++) {
        float su = sst[rt][quad * 4 + r][0][0] + sst[rt][quad * 4 + r][1][0];
        float sq = sst[rt][quad * 4 + r][0][1] + sst[rt][quad * 4 + r][1][1];
        float mean = su * (1.f / 256.f);
        float var = sq * (1.f / 256.f) - mean * mean;
        float invs = rsqrtf(var + 1e-5f);
        #pragma unroll
        for (int c = 0; c < 8; c++) {
            int n = nh * 128 + c * 16 + ln;
            float yn = (y[c][r] - mean) * invs * g3[n] + b3[n];
            int s_x = n >> 5, q_x = (n >> 3) & 3, j = n & 7;
            xn2[((size_t)((lt * 8 + s_x) * 64 + q_x * 16 + (quad * 4 + r))) * 8 + j] = (_Float16)yn;
        }
    }
}

// out = xn2 @ Wo + bo [M x 55] fp32. Block: 2 rowtiles x 2 K-halves, LDS combine.
__global__ __launch_bounds__(256) void out_kernel(const _Float16* xn2, const _Float16* wsw,
        const float* bo, float* out) {
    __shared__ f32x4 pc[2][4][64];
    int w = threadIdx.x >> 6, lane = threadIdx.x & 63;
    int quad = lane >> 4, ln = lane & 15;
    int rt = w & 1, kh = w >> 1;
    int mb = blockIdx.x * 32 + rt * 16;
    int lt = mb >> 4;
    const _Float16* W = wsw + WO_OFF;   // K=256, N=64(padded), nc=4

    f32x4 acc[4];
    #pragma unroll
    for (int c = 0; c < 4; c++) acc[c] = f32x4{0,0,0,0};
    #pragma unroll
    for (int ss = 0; ss < 4; ss++) {
        int s = kh * 4 + ss;
        half8 a = *(const half8*)(xn2 + ((size_t)((lt * 8 + s) * 64 + lane)) * 8);
        #pragma unroll
        for (int c = 0; c < 4; c++)
            acc[c] = mfma16(a, *(const half8*)(W + ((size_t)((s * 4 + c) * 64 + lane)) * 8), acc[c]);
    }
    if (kh == 1)
        #pragma unroll
        for (int c = 0; c < 4; c++) pc[rt][c][lane] = acc[c];
    __syncthreads();
    if (kh == 0) {
        #pragma unroll
        for (int c = 0; c < 4; c++) {
            f32x4 p = pc[rt][c][lane];
            int n = c * 16 + ln;
            if (n < OUT_) {
                float bv = bo[n];
                #pragma unroll
                for (int r = 0; r < 4; r++)
                    out[(size_t)(mb + quad * 4 + r) * OUT_ + n] = acc[c][r] + p[r] + bv;
            }
        }
    }
}

extern "C" void kernel_launch(void* const* d_in, const int* in_sizes, int n_in,
                              void* d_out, int out_size, void* d_ws, size_t ws_size,
                              hipStream_t stream) {
    const float* x1    = (const float*)d_in[0];
    const float* x2    = (const float*)d_in[1];
    const float* ln1_g = (const float*)d_in[2];
    const float* ln1_b = (const float*)d_in[3];
    const float* ln2_g = (const float*)d_in[4];
    const float* ln2_b = (const float*)d_in[5];
    const float* Wq    = (const float*)d_in[6];
    const float* bq    = (const float*)d_in[7];
    const float* Wv1   = (const float*)d_in[8];
    const float* bv1   = (const float*)d_in[9];
    const float* Wk    = (const float*)d_in[10];
    const float* bk    = (const float*)d_in[11];
    const float* Wv2   = (const float*)d_in[12];
    const float* bv2   = (const float*)d_in[13];
    const float* Wp1   = (const float*)d_in[14];
    const float* bp1   = (const float*)d_in[15];
    const float* Wp2   = (const float*)d_in[16];
    const float* bp2   = (const float*)d_in[17];
    const float* lnf_g = (const float*)d_in[18];
    const float* lnf_b = (const float*)d_in[19];
    const float* Wf1   = (const float*)d_in[20];
    const float* bf1   = (const float*)d_in[21];
    const float* Wf2   = (const float*)d_in[22];
    const float* bf2   = (const float*)d_in[23];
    const float* ln3_g = (const float*)d_in[24];
    const float* ln3_b = (const float*)d_in[25];
    const float* Wo    = (const float*)d_in[26];
    const float* bo    = (const float*)d_in[27];
    float* out = (float*)d_out;

    char* ws = (char*)d_ws;
    const size_t MB = 1 << 20;
    _Float16* q1sw   = (_Float16*)(ws + 0 * MB);    // 4 MB
    _Float16* k2sw   = (_Float16*)(ws + 4 * MB);    // 4 MB
    unsigned char* vsw8 = (unsigned char*)(ws + 8 * MB);   // 4 MB (fp8 Vcat per batch)
    _Float16* att1   = (_Float16*)(ws + 12 * MB);   // 4 MB
    _Float16* att2   = (_Float16*)(ws + 16 * MB);   // 4 MB
    _Float16* x1n    = (_Float16*)(ws + 20 * MB);   // 4 MB
    _Float16* x2n    = (_Float16*)(ws + 24 * MB);   // 4 MB
    _Float16* wsw    = (_Float16*)(ws + 28 * MB);   // ~0.74 MB
    float*    rowsum = (float*)   (ws + 29 * MB);   // 64 KB
    float*    res    = (float*)   (ws + 30 * MB);   // 16 MB
    _Float16* xn     = (_Float16*)(ws + 46 * MB);   // 8 MB
    _Float16* h      = (_Float16*)(ws + 54 * MB);   // 16 MB
    _Float16* xn2    = (_Float16*)(ws + 70 * MB);   // 8 MB
    unsigned char* pmat8 = (unsigned char*)(ws + 78 * MB); // 64 MB (fp8 P per batch)

    prep_kernel<<<dim3(512, 9), 256, 0, stream>>>(Wq, Wv1, Wk, Wv2, Wp1, Wp2, Wf1, Wf2, Wo, wsw);
    ln_kernel<<<dim3(M_ / 4, 2), 256, 0, stream>>>(x1, x2, ln1_g, ln1_b, ln2_g, ln2_b, x1n, x2n);
    proj_kernel<<<dim3(M_ / 64, 4), 256, 0, stream>>>(x1n, x2n, wsw, bq, bv1, bk, bv2,
                                                      q1sw, k2sw, vsw8);
    zero_kernel<<<dim3(16), 256, 0, stream>>>(rowsum);
    score_kernel<<<dim3(32, 32, 4), 256, 0, stream>>>(q1sw, k2sw, pmat8, rowsum);
    pv_kernel<<<dim3(M_ / 64), 256, 0, stream>>>(pmat8, vsw8, rowsum, att1, att2);
    attn_out_kernel<<<dim3(M_ / 64), 256, 0, stream>>>(att1, att2, wsw, bp1, bp2,
                                                       x1, x2, lnf_g, lnf_b, res, xn);
    ffn1_kernel<<<dim3(M_ / 64, 4), 256, 0, stream>>>(xn, wsw, bf1, h);
    ffn2_kernel<<<dim3(M_ / 32), 256, 0, stream>>>(h, wsw, bf2, res, ln3_g, ln3_b, xn2);
    out_kernel<<<dim3(M_ / 32), 256, 0, stream>>>(xn2, wsw, bo, out);
}

// Round 7
// 288.175 us; speedup vs baseline: 2.1069x; 1.1051x over previous
//
#include <hip/hip_runtime.h>
#include <hip/hip_fp16.h>

typedef _Float16 half8 __attribute__((ext_vector_type(8)));
typedef float f32x4 __attribute__((ext_vector_type(4)));
typedef long lng2 __attribute__((ext_vector_type(2)));

#define B_   4
#define L_   4096
#define D_   128
#define M_   (B_*L_)     // 16384
#define D2_  256
#define H_   512
#define OUT_ 55

__device__ __forceinline__ f32x4 mfma16(half8 a, half8 b, f32x4 c) {
    return __builtin_amdgcn_mfma_f32_16x16x32_f16(a, b, c, 0, 0, 0);
}
__device__ __forceinline__ f32x4 mfma8(long a, long b, f32x4 c) {
    return __builtin_amdgcn_mfma_f32_16x16x32_fp8_fp8(a, b, c, 0, 0, 0);
}
// pack 4 floats -> 4 fp8 e4m3 bytes (OCP on gfx950)
__device__ __forceinline__ int pk4(float a, float b, float c, float d) {
    int t = __builtin_amdgcn_cvt_pk_fp8_f32(a, b, 0, false);
    return __builtin_amdgcn_cvt_pk_fp8_f32(c, d, t, true);
}

// fold softmax scale (1/sqrt(128)) * log2(e) into k2 so score uses bare v_exp
#define KSCL (0.08838834764831845f * 1.4426950408889634f)

// ---- weight swizzle offsets (in halfs) within wsw region ----
#define WQ_OFF   0
#define WV1_OFF  16384
#define WK_OFF   32768
#define WV2_OFF  49152
#define WP1_OFF  65536
#define WP2_OFF  81920
#define WF1_OFF  98304     // 256x512 = 131072
#define WF2_OFF  229376    // 512x256 = 131072
#define WO_OFF   360448    // 256x64 (padded) = 16384

// Permuted k-map (within a 32-k chunk): k5 = (h<4 ? q*4+h : 16+q*4+(h-4)).
// Used for: fp8 P & V (16B entries, int t = k>>4 of 64-k block), and fp16
// att & Wp1/Wp2 B-frags. A/B operands agree pairwise -> MFMA result identical.

// Pre-swizzle weights (fp32 row-major [K][N]) into B-fragment layout fp16.
// canonical: q=(k>>3)&3, j=k&7 ; permK (Wp1/Wp2 only): q=(k>>2)&3, j=(k&3)+4*((k>>4)&1)
__global__ void prep_kernel(const float* Wq, const float* Wv1, const float* Wk,
                            const float* Wv2, const float* Wp1, const float* Wp2,
                            const float* Wf1, const float* Wf2, const float* Wo,
                            _Float16* wsw) {
    int id = blockIdx.y;
    int t  = blockIdx.x * 256 + threadIdx.x;
    const float* src = nullptr; int K = 0, N = 0, Npad = 0, off = 0;
    switch (id) {
        case 0: src = Wq;  K = 128; N = 128; Npad = 128; off = WQ_OFF;  break;
        case 1: src = Wv1; K = 128; N = 128; Npad = 128; off = WV1_OFF; break;
        case 2: src = Wk;  K = 128; N = 128; Npad = 128; off = WK_OFF;  break;
        case 3: src = Wv2; K = 128; N = 128; Npad = 128; off = WV2_OFF; break;
        case 4: src = Wp1; K = 128; N = 128; Npad = 128; off = WP1_OFF; break;
        case 5: src = Wp2; K = 128; N = 128; Npad = 128; off = WP2_OFF; break;
        case 6: src = Wf1; K = 256; N = 512; Npad = 512; off = WF1_OFF; break;
        case 7: src = Wf2; K = 512; N = 256; Npad = 256; off = WF2_OFF; break;
        case 8: src = Wo;  K = 256; N = 55;  Npad = 64;  off = WO_OFF;  break;
        default: return;
    }
    int total = K * Npad;
    if (t >= total) return;
    int k = t / Npad, n = t % Npad;
    float v = (n < N) ? src[k * N + n] : 0.f;
    int s = k >> 5, c = n >> 4, ln = n & 15;
    int q, j;
    if (id == 4 || id == 5) { q = (k >> 2) & 3; j = (k & 3) + (((k >> 4) & 1) << 2); }
    else                    { q = (k >> 3) & 3; j = k & 7; }
    int nc = Npad >> 4;
    wsw[off + ((size_t)((s * nc + c) * 64 + q * 16 + ln)) * 8 + j] = (_Float16)v;
}

// FR layout for X[M][C] halfs:
// idx = ((lt*(C/32) + s)*64 + q*16 + ln_r)*8 + j ; lt=row>>4, ln_r=row&15,
// s=col>>5, q=(col>>3)&3, j=col&7.

// LayerNorm over D=128, one wave per token, fp32 in -> fp16 FR-swizzled out
__global__ __launch_bounds__(256) void ln_kernel(const float* x1, const float* x2,
        const float* g1, const float* b1, const float* g2, const float* b2,
        _Float16* x1n, _Float16* x2n) {
    int wave = threadIdx.x >> 6, lane = threadIdx.x & 63;
    int token = blockIdx.x * 4 + wave;
    const float* x = blockIdx.y ? x2 : x1;
    const float* g = blockIdx.y ? g2 : g1;
    const float* bb = blockIdx.y ? b2 : b1;
    _Float16* o = blockIdx.y ? x2n : x1n;
    const float* xr = x + (size_t)token * D_;
    float a0 = xr[lane], a1 = xr[lane + 64];
    float s = a0 + a1, s2 = a0 * a0 + a1 * a1;
    #pragma unroll
    for (int off = 1; off < 64; off <<= 1) {
        s += __shfl_xor(s, off);
        s2 += __shfl_xor(s2, off);
    }
    float mean = s * (1.f / 128.f);
    float var = s2 * (1.f / 128.f) - mean * mean;
    float inv = rsqrtf(var + 1e-5f);
    int lt = token >> 4, ln_r = token & 15;
    #pragma unroll
    for (int h = 0; h < 2; h++) {
        int col = lane + h * 64;
        float v = (h ? a1 : a0);
        float out = (v - mean) * inv * g[col] + bb[col];
        int ss = col >> 5, q = (col >> 3) & 3, j = col & 7;
        o[((size_t)((lt * 4 + ss) * 64 + q * 16 + ln_r)) * 8 + j] = (_Float16)out;
    }
}

// Projections. q1 fp16 FR; k2 fp16 FR pre-scaled by KSCL; v1/v2 -> vsw8 fp8
// permuted-k B-frag layout: int at ((sp*16+cb+c)*64 + q2*16+ln)*16 + t*4,
// where k-row l0: sp=l0>>6, t=(l0>>4)&3, q2=(l0>>2)&3, bytes=r.
__global__ __launch_bounds__(256) void proj_kernel(const _Float16* x1n, const _Float16* x2n,
        const _Float16* wsw, const float* bq, const float* bv1, const float* bk,
        const float* bv2, _Float16* q1, _Float16* k2, unsigned char* vsw8) {
    int g = blockIdx.y;   // 0:Wq 1:Wv1 2:Wk 3:Wv2
    const _Float16* A = (g < 2) ? x1n : x2n;
    const _Float16* Bw = wsw + g * 16384;
    const float* bias = (g == 0) ? bq : (g == 1) ? bv1 : (g == 2) ? bk : bv2;
    int wave = threadIdx.x >> 6, lane = threadIdx.x & 63;
    int quad = lane >> 4, ln = lane & 15;
    int mbase = blockIdx.x * 64 + wave * 16;
    int lt = mbase >> 4;

    half8 a[4];
    #pragma unroll
    for (int s = 0; s < 4; s++)
        a[s] = *(const half8*)(A + ((size_t)((lt * 4 + s) * 64 + lane)) * 8);

    f32x4 acc[8];
    #pragma unroll
    for (int c = 0; c < 8; c++) {
        acc[c] = f32x4{0.f, 0.f, 0.f, 0.f};
        #pragma unroll
        for (int s = 0; s < 4; s++) {
            half8 bf = *(const half8*)(Bw + ((size_t)((s * 8 + c) * 64 + lane)) * 8);
            acc[c] = mfma16(a[s], bf, acc[c]);
        }
    }
    bool isV = (g == 1) || (g == 3);
    if (!isV) {
        float scl = (g == 2) ? KSCL : 1.f;
        _Float16* out = (g == 0) ? q1 : k2;
        #pragma unroll
        for (int c = 0; c < 8; c++) {
            int n = c * 16 + ln;
            float bv = bias[n];
            #pragma unroll
            for (int r = 0; r < 4; r++) {
                int s_o = c >> 1, q_o = ((c & 1) << 1) | (ln >> 3), j = ln & 7;
                out[((size_t)((lt * 4 + s_o) * 64 + q_o * 16 + (quad * 4 + r))) * 8 + j]
                    = (_Float16)((acc[c][r] + bv) * scl);
            }
        }
    } else {
        int cbase = (g == 3) ? 8 : 0;
        int b = mbase >> 12;
        int l0 = (mbase & (L_ - 1)) + quad * 4;
        int sp = l0 >> 6, tt = (l0 >> 4) & 3, q2 = (l0 >> 2) & 3;
        unsigned char* Vb = vsw8 + (size_t)b * (1u << 20);
        #pragma unroll
        for (int c = 0; c < 8; c++) {
            int n = c * 16 + ln;
            float bv = bias[n];
            int pk = pk4(acc[c][0] + bv, acc[c][1] + bv, acc[c][2] + bv, acc[c][3] + bv);
            *(int*)(Vb + (((size_t)(sp * 16 + cbase + c) * 64 + q2 * 16 + ln) * 16 + tt * 4)) = pk;
        }
    }
}

__global__ __launch_bounds__(256) void zero_kernel(float* rowsum) {
    int i = (blockIdx.x * 256 + threadIdx.x) * 4;
    *(f32x4*)(rowsum + i) = f32x4{0.f, 0.f, 0.f, 0.f};
}

// Pass 1: compute S^T tiles (A=q1 rows = softmax k-dim, B=k2^T cols = att rows).
// p = exp2(acc) (k2 pre-scaled); pk4 over r gives k-runs of 4 -> the permuted-k
// fp8 A-entry is just int4{pkv[0..3][j]}. NO LDS, NO shuffles for data.
__global__ __launch_bounds__(256) void score_kernel(
        const _Float16* __restrict__ q1sw, const _Float16* __restrict__ k2sw,
        unsigned char* __restrict__ pmat8, float* __restrict__ rowsum) {
    int w = threadIdx.x >> 6, lane = threadIdx.x & 63;
    int quad = lane >> 4, ln = lane & 15;
    int b = blockIdx.z;
    int kL0 = blockIdx.y * 128 + (w & 1) * 64;     // q1 rows (contraction dim of PV)
    int mL0 = blockIdx.x * 128 + (w >> 1) * 64;    // k2 rows (att rows)
    int ltk = ((b << 12) + kL0) >> 4;
    int ltm = ((b << 12) + mL0) >> 4;

    f32x4 acc[4][4];
    #pragma unroll
    for (int i = 0; i < 4; i++)
        #pragma unroll
        for (int j = 0; j < 4; j++) acc[i][j] = f32x4{0.f, 0.f, 0.f, 0.f};

    #pragma unroll
    for (int s = 0; s < 4; s++) {
        half8 a[4], bq[4];
        #pragma unroll
        for (int i = 0; i < 4; i++)
            a[i] = *(const half8*)(q1sw + ((size_t)(((ltk + i) * 4 + s) * 64 + lane)) * 8);
        #pragma unroll
        for (int j = 0; j < 4; j++)
            bq[j] = *(const half8*)(k2sw + ((size_t)(((ltm + j) * 4 + s) * 64 + lane)) * 8);
        #pragma unroll
        for (int i = 0; i < 4; i++)
            #pragma unroll
            for (int j = 0; j < 4; j++)
                acc[i][j] = mfma16(a[i], bq[j], acc[i][j]);
    }

    // acc[i][j]: k = kL0 + i*16 + quad*4 + r ; att-row m = mL0 + j*16 + ln
    unsigned char* Pb = pmat8 + (size_t)b * (16u << 20);
    int sp = kL0 >> 6;
    #pragma unroll
    for (int j = 0; j < 4; j++) {
        int4 d;
        float csum = 0.f;
        #pragma unroll
        for (int i = 0; i < 4; i++) {
            float p0 = exp2f(acc[i][j][0]);
            float p1 = exp2f(acc[i][j][1]);
            float p2 = exp2f(acc[i][j][2]);
            float p3 = exp2f(acc[i][j][3]);
            csum += (p0 + p1) + (p2 + p3);
            ((int*)&d)[i] = pk4(p0, p1, p2, p3);
        }
        csum += __shfl_xor(csum, 16);
        csum += __shfl_xor(csum, 32);
        if (lane < 16)
            atomicAdd(&rowsum[(b << 12) + mL0 + j * 16 + ln], csum);
        int lt = (mL0 >> 4) + j;
        *(int4*)(Pb + (((size_t)(lt * 64 + sp)) * 64 + lane) * 16) = d;
    }
}

// Pass 2: O^T = V^T . P^T via operand swap: mfma8(A=V-frag, B=P-frag).
// C rows = n (V col 0..255), C cols = m (att row) -> att-row lands on the LANE
// axis = attn_out's A-frag orientation. Permuted-k fp16 att stores, no LDS,
// no barriers. 512 blocks (32 m-rows) x 4 waves (4 n-tiles each), depth-2 prefetch.
__global__ __launch_bounds__(256) void pv_kernel(
        const unsigned char* __restrict__ pmat8, const unsigned char* __restrict__ vsw8,
        const float* __restrict__ rowsum,
        _Float16* __restrict__ att1, _Float16* __restrict__ att2) {
    int w = threadIdx.x >> 6, lane = threadIdx.x & 63;
    int quad = lane >> 4, ln = lane & 15;
    int rowG0 = blockIdx.x * 32;
    int b = rowG0 >> 12;
    int lt0 = (rowG0 & (L_ - 1)) >> 4;   // 2 m-tiles
    const unsigned char* Pb = pmat8 + (size_t)b * (16u << 20);
    const unsigned char* Vb = vsw8 + (size_t)b * (1u << 20);

    f32x4 acc[4][2];
    #pragma unroll
    for (int i = 0; i < 4; i++)
        #pragma unroll
        for (int c = 0; c < 2; c++) acc[i][c] = f32x4{0.f, 0.f, 0.f, 0.f};

    lng2 Vf[2][4], Pf[2][2];
    #pragma unroll
    for (int p = 0; p < 2; p++) {
        #pragma unroll
        for (int i = 0; i < 4; i++)
            Vf[p][i] = *(const lng2*)(Vb + (((size_t)(p * 16 + w * 4 + i)) * 64 + lane) * 16);
        #pragma unroll
        for (int c = 0; c < 2; c++)
            Pf[p][c] = *(const lng2*)(Pb + (((size_t)((lt0 + c) * 64 + p)) * 64 + lane) * 16);
    }

    #define PVSTEP(buf, sp) do {                                                     \
        int spn = ((sp) + 2 < 64) ? (sp) + 2 : 63;                                   \
        lng2 Vn[4], Pn[2];                                                           \
        _Pragma("unroll")                                                            \
        for (int i = 0; i < 4; i++)                                                  \
            Vn[i] = *(const lng2*)(Vb + (((size_t)(spn * 16 + w * 4 + i)) * 64 + lane) * 16); \
        _Pragma("unroll")                                                            \
        for (int c = 0; c < 2; c++)                                                  \
            Pn[c] = *(const lng2*)(Pb + (((size_t)((lt0 + c) * 64 + spn)) * 64 + lane) * 16); \
        _Pragma("unroll")                                                            \
        for (int i = 0; i < 4; i++)                                                  \
            _Pragma("unroll")                                                        \
            for (int c = 0; c < 2; c++) {                                            \
                acc[i][c] = mfma8(Vf[buf][i].x, Pf[buf][c].x, acc[i][c]);             \
                acc[i][c] = mfma8(Vf[buf][i].y, Pf[buf][c].y, acc[i][c]);             \
            }                                                                        \
        _Pragma("unroll")                                                            \
        for (int i = 0; i < 4; i++) Vf[buf][i] = Vn[i];                              \
        _Pragma("unroll")                                                            \
        for (int c = 0; c < 2; c++) Pf[buf][c] = Pn[c];                              \
    } while (0)

    for (int sp = 0; sp < 64; sp += 2) {
        PVSTEP(0, sp);
        PVSTEP(1, sp + 1);
    }
    #undef PVSTEP

    // acc[i][c]: n = (w*4+i)*16 + quad*4 + r ; m = rowG0 + c*16 + ln
    _Float16* att = (w >= 2) ? att2 : att1;
    #pragma unroll
    for (int c = 0; c < 2; c++) {
        float inv = 1.f / rowsum[rowG0 + c * 16 + ln];
        int lt = (rowG0 >> 4) + c;
        #pragma unroll
        for (int sl = 0; sl < 2; sl++) {
            half8 v;
            #pragma unroll
            for (int r = 0; r < 4; r++) {
                v[r]     = (_Float16)(acc[2 * sl][c][r] * inv);
                v[r + 4] = (_Float16)(acc[2 * sl + 1][c][r] * inv);
            }
            int s = (w & 1) * 2 + sl;
            *(half8*)(att + ((size_t)((lt * 4 + s) * 64 + lane)) * 8) = v;
        }
    }
}

// out_s = att_s @ Wp_s + bias + residual ; concat -> res (fp32) ; LNf -> xn (FR fp16)
// (att and Wp are permuted-k consistently; frags are opaque 16B loads here)
__global__ __launch_bounds__(256) void attn_out_kernel(const _Float16* att1, const _Float16* att2,
        const _Float16* wsw, const float* bp1, const float* bp2,
        const float* x1, const float* x2, const float* lnf_g, const float* lnf_b,
        float* res, _Float16* xn) {
    int wave = threadIdx.x >> 6, lane = threadIdx.x & 63;
    int quad = lane >> 4, ln = lane & 15;
    int mbase = blockIdx.x * 64 + wave * 16;
    int lt = mbase >> 4;
    const _Float16* Wp1 = wsw + WP1_OFF;
    const _Float16* Wp2 = wsw + WP2_OFF;

    half8 a1[4], a2[4];
    #pragma unroll
    for (int s = 0; s < 4; s++) {
        a1[s] = *(const half8*)(att1 + ((size_t)((lt * 4 + s) * 64 + lane)) * 8);
        a2[s] = *(const half8*)(att2 + ((size_t)((lt * 4 + s) * 64 + lane)) * 8);
    }
    f32x4 y1[8], y2[8];
    #pragma unroll
    for (int c = 0; c < 8; c++) {
        y1[c] = f32x4{0,0,0,0}; y2[c] = f32x4{0,0,0,0};
        #pragma unroll
        for (int s = 0; s < 4; s++) {
            y1[c] = mfma16(a1[s], *(const half8*)(Wp1 + ((size_t)((s * 8 + c) * 64 + lane)) * 8), y1[c]);
            y2[c] = mfma16(a2[s], *(const half8*)(Wp2 + ((size_t)((s * 8 + c) * 64 + lane)) * 8), y2[c]);
        }
    }
    #pragma unroll
    for (int c = 0; c < 8; c++) {
        int n = c * 16 + ln;
        float b1v = bp1[n], b2v = bp2[n];
        #pragma unroll
        for (int r = 0; r < 4; r++) {
            int m = mbase + quad * 4 + r;
            y1[c][r] += b1v + x1[(size_t)m * D_ + n];
            y2[c][r] += b2v + x2[(size_t)m * D_ + n];
        }
    }
    float sum[4] = {0,0,0,0}, sq[4] = {0,0,0,0};
    #pragma unroll
    for (int c = 0; c < 8; c++)
        #pragma unroll
        for (int r = 0; r < 4; r++) {
            sum[r] += y1[c][r] + y2[c][r];
            sq[r]  += y1[c][r] * y1[c][r] + y2[c][r] * y2[c][r];
        }
    #pragma unroll
    for (int off = 1; off < 16; off <<= 1)
        #pragma unroll
        for (int r = 0; r < 4; r++) { sum[r] += __shfl_xor(sum[r], off); sq[r] += __shfl_xor(sq[r], off); }
    #pragma unroll
    for (int r = 0; r < 4; r++) {
        float mean = sum[r] * (1.f / 256.f);
        float var = sq[r] * (1.f / 256.f) - mean * mean;
        float inv = rsqrtf(var + 1e-5f);
        int m = mbase + quad * 4 + r;
        int lt_m = m >> 4;
        #pragma unroll
        for (int c = 0; c < 8; c++) {
            int n = c * 16 + ln;
            res[(size_t)m * D2_ + n]       = y1[c][r];
            res[(size_t)m * D2_ + 128 + n] = y2[c][r];
            float yn1 = (y1[c][r] - mean) * inv * lnf_g[n] + lnf_b[n];
            float yn2 = (y2[c][r] - mean) * inv * lnf_g[128 + n] + lnf_b[128 + n];
            int s_x = n >> 5, q_x = (n >> 3) & 3, j = n & 7;
            xn[((size_t)((lt_m * 8 + s_x) * 64 + q_x * 16 + (m & 15))) * 8 + j] = (_Float16)yn1;
            int n2 = 128 + n;
            int s_y = n2 >> 5, q_y = (n2 >> 3) & 3, j2 = n2 & 7;
            xn[((size_t)((lt_m * 8 + s_y) * 64 + q_y * 16 + (m & 15))) * 8 + j2] = (_Float16)yn2;
        }
    }
}

// h = gelu(xn @ Wf1 + bf1)  [M x 512], FR-swizzled in/out
__global__ __launch_bounds__(256) void ffn1_kernel(const _Float16* xn, const _Float16* wsw,
        const float* bf1, _Float16* h) {
    int wave = threadIdx.x >> 6, lane = threadIdx.x & 63;
    int quad = lane >> 4, ln = lane & 15;
    int mbase = blockIdx.x * 64 + wave * 16;
    int lt = mbase >> 4;
    int nt = blockIdx.y;   // 0..3
    const _Float16* W = wsw + WF1_OFF;   // K=256, N=512, nc=32

    half8 a[8];
    #pragma unroll
    for (int s = 0; s < 8; s++)
        a[s] = *(const half8*)(xn + ((size_t)((lt * 8 + s) * 64 + lane)) * 8);

    f32x4 acc[8];
    #pragma unroll
    for (int c = 0; c < 8; c++) {
        acc[c] = f32x4{0,0,0,0};
        int cg = nt * 8 + c;
        #pragma unroll
        for (int s = 0; s < 8; s++)
            acc[c] = mfma16(a[s], *(const half8*)(W + ((size_t)((s * 32 + cg) * 64 + lane)) * 8), acc[c]);
    }
    #pragma unroll
    for (int c = 0; c < 8; c++) {
        int n = nt * 128 + c * 16 + ln;
        float bv = bf1[n];
        int s_h = n >> 5, q_h = (n >> 3) & 3, j = n & 7;
        #pragma unroll
        for (int r = 0; r < 4; r++) {
            float v = acc[c][r] + bv;
            float ge = 0.5f * v * (1.f + erff(v * 0.70710678118654752f));
            h[((size_t)((lt * 16 + s_h) * 64 + q_h * 16 + (quad * 4 + r))) * 8 + j] = (_Float16)ge;
        }
    }
}

// x = LN3(h @ Wf2 + bf2 + res) -> xn2 (FR-swizzled fp16). Block: 2 rowtiles x 2 N-halves.
__global__ __launch_bounds__(256) void ffn2_kernel(const _Float16* h, const _Float16* wsw,
        const float* bf2, const float* res, const float* g3, const float* b3, _Float16* xn2) {
    __shared__ float sst[2][16][2][2];
    int w = threadIdx.x >> 6, lane = threadIdx.x & 63;
    int quad = lane >> 4, ln = lane & 15;
    int rt = w & 1, nh = w >> 1;
    int mb = blockIdx.x * 32 + rt * 16;
    int lt = mb >> 4;
    const _Float16* W = wsw + WF2_OFF;   // K=512, N=256, nc=16

    f32x4 acc[8];
    #pragma unroll
    for (int c = 0; c < 8; c++) acc[c] = f32x4{0,0,0,0};
    for (int s = 0; s < 16; s++) {
        half8 a = *(const half8*)(h + ((size_t)((lt * 16 + s) * 64 + lane)) * 8);
        #pragma unroll
        for (int c = 0; c < 8; c++)
            acc[c] = mfma16(a, *(const half8*)(W + ((size_t)((s * 16 + nh * 8 + c) * 64 + lane)) * 8), acc[c]);
    }
    float y[8][4];
    float psum[4] = {0,0,0,0}, psq[4] = {0,0,0,0};
    #pragma unroll
    for (int c = 0; c < 8; c++) {
        int n = nh * 128 + c * 16 + ln;
        float bv = bf2[n];
        #pragma unroll
        for (int r = 0; r < 4; r++) {
            int m = mb + quad * 4 + r;
            float v = acc[c][r] + bv + res[(size_t)m * D2_ + n];
            y[c][r] = v; psum[r] += v; psq[r] += v * v;
        }
    }
    #pragma unroll
    for (int off = 1; off < 16; off <<= 1)
        #pragma unroll
        for (int r = 0; r < 4; r++) { psum[r] += __shfl_xor(psum[r], off); psq[r] += __shfl_xor(psq[r], off); }
    if (ln == 0)
        #pragma unroll
        for (int r = 0; r < 4; r++) { sst[rt][quad * 4 + r][nh][0] = psum[r]; sst[rt][quad * 4 + r][nh][1] = psq[r]; }
    __syncthreads();
    #pragma unroll
    for (int r = 0; r < 4; r++) {
        float su = sst[rt][quad * 4 + r][0][0] + sst[rt][quad * 4 + r][1][0];
        float sq = sst[rt][quad * 4 + r][0][1] + sst[rt][quad * 4 + r][1][1];
        float mean = su * (1.f / 256.f);
        float var = sq * (1.f / 256.f) - mean * mean;
        float invs = rsqrtf(var + 1e-5f);
        #pragma unroll
        for (int c = 0; c < 8; c++) {
            int n = nh * 128 + c * 16 + ln;
            float yn = (y[c][r] - mean) * invs * g3[n] + b3[n];
            int s_x = n >> 5, q_x = (n >> 3) & 3, j = n & 7;
            xn2[((size_t)((lt * 8 + s_x) * 64 + q_x * 16 + (quad * 4 + r))) * 8 + j] = (_Float16)yn;
        }
    }
}

// out = xn2 @ Wo + bo [M x 55] fp32. Block: 2 rowtiles x 2 K-halves, LDS combine.
__global__ __launch_bounds__(256) void out_kernel(const _Float16* xn2, const _Float16* wsw,
        const float* bo, float* out) {
    __shared__ f32x4 pc[2][4][64];
    int w = threadIdx.x >> 6, lane = threadIdx.x & 63;
    int quad = lane >> 4, ln = lane & 15;
    int rt = w & 1, kh = w >> 1;
    int mb = blockIdx.x * 32 + rt * 16;
    int lt = mb >> 4;
    const _Float16* W = wsw + WO_OFF;   // K=256, N=64(padded), nc=4

    f32x4 acc[4];
    #pragma unroll
    for (int c = 0; c < 4; c++) acc[c] = f32x4{0,0,0,0};
    #pragma unroll
    for (int ss = 0; ss < 4; ss++) {
        int s = kh * 4 + ss;
        half8 a = *(const half8*)(xn2 + ((size_t)((lt * 8 + s) * 64 + lane)) * 8);
        #pragma unroll
        for (int c = 0; c < 4; c++)
            acc[c] = mfma16(a, *(const half8*)(W + ((size_t)((s * 4 + c) * 64 + lane)) * 8), acc[c]);
    }
    if (kh == 1)
        #pragma unroll
        for (int c = 0; c < 4; c++) pc[rt][c][lane] = acc[c];
    __syncthreads();
    if (kh == 0) {
        #pragma unroll
        for (int c = 0; c < 4; c++) {
            f32x4 p = pc[rt][c][lane];
            int n = c * 16 + ln;
            if (n < OUT_) {
                float bv = bo[n];
                #pragma unroll
                for (int r = 0; r < 4; r++)
                    out[(size_t)(mb + quad * 4 + r) * OUT_ + n] = acc[c][r] + p[r] + bv;
            }
        }
    }
}

extern "C" void kernel_launch(void* const* d_in, const int* in_sizes, int n_in,
                              void* d_out, int out_size, void* d_ws, size_t ws_size,
                              hipStream_t stream) {
    const float* x1    = (const float*)d_in[0];
    const float* x2    = (const float*)d_in[1];
    const float* ln1_g = (const float*)d_in[2];
    const float* ln1_b = (const float*)d_in[3];
    const float* ln2_g = (const float*)d_in[4];
    const float* ln2_b = (const float*)d_in[5];
    const float* Wq    = (const float*)d_in[6];
    const float* bq    = (const float*)d_in[7];
    const float* Wv1   = (const float*)d_in[8];
    const float* bv1   = (const float*)d_in[9];
    const float* Wk    = (const float*)d_in[10];
    const float* bk    = (const float*)d_in[11];
    const float* Wv2   = (const float*)d_in[12];
    const float* bv2   = (const float*)d_in[13];
    const float* Wp1   = (const float*)d_in[14];
    const float* bp1   = (const float*)d_in[15];
    const float* Wp2   = (const float*)d_in[16];
    const float* bp2   = (const float*)d_in[17];
    const float* lnf_g = (const float*)d_in[18];
    const float* lnf_b = (const float*)d_in[19];
    const float* Wf1   = (const float*)d_in[20];
    const float* bf1   = (const float*)d_in[21];
    const float* Wf2   = (const float*)d_in[22];
    const float* bf2   = (const float*)d_in[23];
    const float* ln3_g = (const float*)d_in[24];
    const float* ln3_b = (const float*)d_in[25];
    const float* Wo    = (const float*)d_in[26];
    const float* bo    = (const float*)d_in[27];
    float* out = (float*)d_out;

    char* ws = (char*)d_ws;
    const size_t MB = 1 << 20;
    _Float16* q1sw   = (_Float16*)(ws + 0 * MB);    // 4 MB
    _Float16* k2sw   = (_Float16*)(ws + 4 * MB);    // 4 MB
    unsigned char* vsw8 = (unsigned char*)(ws + 8 * MB);   // 4 MB (fp8 Vcat per batch)
    _Float16* att1   = (_Float16*)(ws + 12 * MB);   // 4 MB
    _Float16* att2   = (_Float16*)(ws + 16 * MB);   // 4 MB
    _Float16* x1n    = (_Float16*)(ws + 20 * MB);   // 4 MB
    _Float16* x2n    = (_Float16*)(ws + 24 * MB);   // 4 MB
    _Float16* wsw    = (_Float16*)(ws + 28 * MB);   // ~0.74 MB
    float*    rowsum = (float*)   (ws + 29 * MB);   // 64 KB
    float*    res    = (float*)   (ws + 30 * MB);   // 16 MB
    _Float16* xn     = (_Float16*)(ws + 46 * MB);   // 8 MB
    _Float16* h      = (_Float16*)(ws + 54 * MB);   // 16 MB
    _Float16* xn2    = (_Float16*)(ws + 70 * MB);   // 8 MB
    unsigned char* pmat8 = (unsigned char*)(ws + 78 * MB); // 64 MB (fp8 P per batch)

    prep_kernel<<<dim3(512, 9), 256, 0, stream>>>(Wq, Wv1, Wk, Wv2, Wp1, Wp2, Wf1, Wf2, Wo, wsw);
    ln_kernel<<<dim3(M_ / 4, 2), 256, 0, stream>>>(x1, x2, ln1_g, ln1_b, ln2_g, ln2_b, x1n, x2n);
    proj_kernel<<<dim3(M_ / 64, 4), 256, 0, stream>>>(x1n, x2n, wsw, bq, bv1, bk, bv2,
                                                      q1sw, k2sw, vsw8);
    zero_kernel<<<dim3(16), 256, 0, stream>>>(rowsum);
    score_kernel<<<dim3(32, 32, 4), 256, 0, stream>>>(q1sw, k2sw, pmat8, rowsum);
    pv_kernel<<<dim3(M_ / 32), 256, 0, stream>>>(pmat8, vsw8, rowsum, att1, att2);
    attn_out_kernel<<<dim3(M_ / 64), 256, 0, stream>>>(att1, att2, wsw, bp1, bp2,
                                                       x1, x2, lnf_g, lnf_b, res, xn);
    ffn1_kernel<<<dim3(M_ / 64, 4), 256, 0, stream>>>(xn, wsw, bf1, h);
    ffn2_kernel<<<dim3(M_ / 32), 256, 0, stream>>>(h, wsw, bf2, res, ln3_g, ln3_b, xn2);
    out_kernel<<<dim3(M_ / 32), 256, 0, stream>>>(xn2, wsw, bo, out);
}

// Round 8
// 257.648 us; speedup vs baseline: 2.3566x; 1.1185x over previous
//
#include <hip/hip_runtime.h>
#include <hip/hip_fp16.h>

typedef _Float16 half8 __attribute__((ext_vector_type(8)));
typedef float f32x4 __attribute__((ext_vector_type(4)));
typedef long lng2 __attribute__((ext_vector_type(2)));

#define B_   4
#define L_   4096
#define D_   128
#define M_   (B_*L_)     // 16384
#define D2_  256
#define H_   512
#define OUT_ 55

__device__ __forceinline__ f32x4 mfma16(half8 a, half8 b, f32x4 c) {
    return __builtin_amdgcn_mfma_f32_16x16x32_f16(a, b, c, 0, 0, 0);
}
__device__ __forceinline__ f32x4 mfma8(long a, long b, f32x4 c) {
    return __builtin_amdgcn_mfma_f32_16x16x32_fp8_fp8(a, b, c, 0, 0, 0);
}
// pack 4 floats -> 4 fp8 e4m3 bytes (OCP on gfx950)
__device__ __forceinline__ int pk4(float a, float b, float c, float d) {
    int t = __builtin_amdgcn_cvt_pk_fp8_f32(a, b, 0, false);
    return __builtin_amdgcn_cvt_pk_fp8_f32(c, d, t, true);
}

// fold softmax scale (1/sqrt(128)) * log2(e) into k2 so score uses bare v_exp
#define KSCL (0.08838834764831845f * 1.4426950408889634f)

// ---- weight swizzle offsets (in halfs) within wsw region ----
#define WQ_OFF   0
#define WV1_OFF  16384
#define WK_OFF   32768
#define WV2_OFF  49152
#define WP1_OFF  65536
#define WP2_OFF  81920
#define WF1_OFF  98304     // 256x512 = 131072
#define WF2_OFF  229376    // 512x256 = 131072
#define WO_OFF   360448    // 256x64 (padded) = 16384

// Permuted k-map (within a 32-k chunk): k5 = (h<4 ? q*4+h : 16+q*4+(h-4)).
// Used for fp8 P & V and fp16 att & Wp1/Wp2 — A/B agree pairwise.

// Pre-swizzle weights (fp32 row-major [K][N]) into B-fragment layout fp16.
// canonical: q=(k>>3)&3, j=k&7 ; permK (Wp1/Wp2 only): q=(k>>2)&3, j=(k&3)+4*((k>>4)&1)
__global__ void prep_kernel(const float* Wq, const float* Wv1, const float* Wk,
                            const float* Wv2, const float* Wp1, const float* Wp2,
                            const float* Wf1, const float* Wf2, const float* Wo,
                            _Float16* wsw) {
    int id = blockIdx.y;
    int t  = blockIdx.x * 256 + threadIdx.x;
    const float* src = nullptr; int K = 0, N = 0, Npad = 0, off = 0;
    switch (id) {
        case 0: src = Wq;  K = 128; N = 128; Npad = 128; off = WQ_OFF;  break;
        case 1: src = Wv1; K = 128; N = 128; Npad = 128; off = WV1_OFF; break;
        case 2: src = Wk;  K = 128; N = 128; Npad = 128; off = WK_OFF;  break;
        case 3: src = Wv2; K = 128; N = 128; Npad = 128; off = WV2_OFF; break;
        case 4: src = Wp1; K = 128; N = 128; Npad = 128; off = WP1_OFF; break;
        case 5: src = Wp2; K = 128; N = 128; Npad = 128; off = WP2_OFF; break;
        case 6: src = Wf1; K = 256; N = 512; Npad = 512; off = WF1_OFF; break;
        case 7: src = Wf2; K = 512; N = 256; Npad = 256; off = WF2_OFF; break;
        case 8: src = Wo;  K = 256; N = 55;  Npad = 64;  off = WO_OFF;  break;
        default: return;
    }
    int total = K * Npad;
    if (t >= total) return;
    int k = t / Npad, n = t % Npad;
    float v = (n < N) ? src[k * N + n] : 0.f;
    int s = k >> 5, c = n >> 4, ln = n & 15;
    int q, j;
    if (id == 4 || id == 5) { q = (k >> 2) & 3; j = (k & 3) + (((k >> 4) & 1) << 2); }
    else                    { q = (k >> 3) & 3; j = k & 7; }
    int nc = Npad >> 4;
    wsw[off + ((size_t)((s * nc + c) * 64 + q * 16 + ln)) * 8 + j] = (_Float16)v;
}

// FR layout for X[M][C] halfs:
// idx = ((lt*(C/32) + s)*64 + q*16 + ln_r)*8 + j ; lt=row>>4, ln_r=row&15,
// s=col>>5, q=(col>>3)&3, j=col&7.

// LayerNorm over D=128, one wave per token, fp32 in -> fp16 FR-swizzled out
__global__ __launch_bounds__(256) void ln_kernel(const float* x1, const float* x2,
        const float* g1, const float* b1, const float* g2, const float* b2,
        _Float16* x1n, _Float16* x2n) {
    int wave = threadIdx.x >> 6, lane = threadIdx.x & 63;
    int token = blockIdx.x * 4 + wave;
    const float* x = blockIdx.y ? x2 : x1;
    const float* g = blockIdx.y ? g2 : g1;
    const float* bb = blockIdx.y ? b2 : b1;
    _Float16* o = blockIdx.y ? x2n : x1n;
    const float* xr = x + (size_t)token * D_;
    float a0 = xr[lane], a1 = xr[lane + 64];
    float s = a0 + a1, s2 = a0 * a0 + a1 * a1;
    #pragma unroll
    for (int off = 1; off < 64; off <<= 1) {
        s += __shfl_xor(s, off);
        s2 += __shfl_xor(s2, off);
    }
    float mean = s * (1.f / 128.f);
    float var = s2 * (1.f / 128.f) - mean * mean;
    float inv = rsqrtf(var + 1e-5f);
    int lt = token >> 4, ln_r = token & 15;
    #pragma unroll
    for (int h = 0; h < 2; h++) {
        int col = lane + h * 64;
        float v = (h ? a1 : a0);
        float out = (v - mean) * inv * g[col] + bb[col];
        int ss = col >> 5, q = (col >> 3) & 3, j = col & 7;
        o[((size_t)((lt * 4 + ss) * 64 + q * 16 + ln_r)) * 8 + j] = (_Float16)out;
    }
}

// Projections. q1 fp16 FR; k2 fp16 FR pre-scaled by KSCL; v1/v2 -> vsw8 fp8
// permuted-k B-frag layout.
__global__ __launch_bounds__(256) void proj_kernel(const _Float16* x1n, const _Float16* x2n,
        const _Float16* wsw, const float* bq, const float* bv1, const float* bk,
        const float* bv2, _Float16* q1, _Float16* k2, unsigned char* vsw8) {
    int g = blockIdx.y;   // 0:Wq 1:Wv1 2:Wk 3:Wv2
    const _Float16* A = (g < 2) ? x1n : x2n;
    const _Float16* Bw = wsw + g * 16384;
    const float* bias = (g == 0) ? bq : (g == 1) ? bv1 : (g == 2) ? bk : bv2;
    int wave = threadIdx.x >> 6, lane = threadIdx.x & 63;
    int quad = lane >> 4, ln = lane & 15;
    int mbase = blockIdx.x * 64 + wave * 16;
    int lt = mbase >> 4;

    half8 a[4];
    #pragma unroll
    for (int s = 0; s < 4; s++)
        a[s] = *(const half8*)(A + ((size_t)((lt * 4 + s) * 64 + lane)) * 8);

    f32x4 acc[8];
    #pragma unroll
    for (int c = 0; c < 8; c++) {
        acc[c] = f32x4{0.f, 0.f, 0.f, 0.f};
        #pragma unroll
        for (int s = 0; s < 4; s++) {
            half8 bf = *(const half8*)(Bw + ((size_t)((s * 8 + c) * 64 + lane)) * 8);
            acc[c] = mfma16(a[s], bf, acc[c]);
        }
    }
    bool isV = (g == 1) || (g == 3);
    if (!isV) {
        float scl = (g == 2) ? KSCL : 1.f;
        _Float16* out = (g == 0) ? q1 : k2;
        #pragma unroll
        for (int c = 0; c < 8; c++) {
            int n = c * 16 + ln;
            float bv = bias[n];
            #pragma unroll
            for (int r = 0; r < 4; r++) {
                int s_o = c >> 1, q_o = ((c & 1) << 1) | (ln >> 3), j = ln & 7;
                out[((size_t)((lt * 4 + s_o) * 64 + q_o * 16 + (quad * 4 + r))) * 8 + j]
                    = (_Float16)((acc[c][r] + bv) * scl);
            }
        }
    } else {
        int cbase = (g == 3) ? 8 : 0;
        int b = mbase >> 12;
        int l0 = (mbase & (L_ - 1)) + quad * 4;
        int sp = l0 >> 6, tt = (l0 >> 4) & 3, q2 = (l0 >> 2) & 3;
        unsigned char* Vb = vsw8 + (size_t)b * (1u << 20);
        #pragma unroll
        for (int c = 0; c < 8; c++) {
            int n = c * 16 + ln;
            float bv = bias[n];
            int pk = pk4(acc[c][0] + bv, acc[c][1] + bv, acc[c][2] + bv, acc[c][3] + bv);
            *(int*)(Vb + (((size_t)(sp * 16 + cbase + c) * 64 + q2 * 16 + ln) * 16 + tt * 4)) = pk;
        }
    }
}

__global__ __launch_bounds__(256) void zero_kernel(float* rowsum) {
    int i = (blockIdx.x * 256 + threadIdx.x) * 4;
    *(f32x4*)(rowsum + i) = f32x4{0.f, 0.f, 0.f, 0.f};
}

// Pass 1: S^T tiles (A=q1 rows = softmax k-dim, B=k2^T cols = att rows).
// p = exp2(acc); pk4 over r -> permuted-k fp8 A-entries, direct 16B stores.
__global__ __launch_bounds__(256) void score_kernel(
        const _Float16* __restrict__ q1sw, const _Float16* __restrict__ k2sw,
        unsigned char* __restrict__ pmat8, float* __restrict__ rowsum) {
    int w = threadIdx.x >> 6, lane = threadIdx.x & 63;
    int quad = lane >> 4, ln = lane & 15;
    int b = blockIdx.z;
    int kL0 = blockIdx.y * 128 + (w & 1) * 64;     // q1 rows (contraction dim of PV)
    int mL0 = blockIdx.x * 128 + (w >> 1) * 64;    // k2 rows (att rows)
    int ltk = ((b << 12) + kL0) >> 4;
    int ltm = ((b << 12) + mL0) >> 4;

    f32x4 acc[4][4];
    #pragma unroll
    for (int i = 0; i < 4; i++)
        #pragma unroll
        for (int j = 0; j < 4; j++) acc[i][j] = f32x4{0.f, 0.f, 0.f, 0.f};

    #pragma unroll
    for (int s = 0; s < 4; s++) {
        half8 a[4], bq[4];
        #pragma unroll
        for (int i = 0; i < 4; i++)
            a[i] = *(const half8*)(q1sw + ((size_t)(((ltk + i) * 4 + s) * 64 + lane)) * 8);
        #pragma unroll
        for (int j = 0; j < 4; j++)
            bq[j] = *(const half8*)(k2sw + ((size_t)(((ltm + j) * 4 + s) * 64 + lane)) * 8);
        #pragma unroll
        for (int i = 0; i < 4; i++)
            #pragma unroll
            for (int j = 0; j < 4; j++)
                acc[i][j] = mfma16(a[i], bq[j], acc[i][j]);
    }

    unsigned char* Pb = pmat8 + (size_t)b * (16u << 20);
    int sp = kL0 >> 6;
    #pragma unroll
    for (int j = 0; j < 4; j++) {
        int4 d;
        float csum = 0.f;
        #pragma unroll
        for (int i = 0; i < 4; i++) {
            float p0 = exp2f(acc[i][j][0]);
            float p1 = exp2f(acc[i][j][1]);
            float p2 = exp2f(acc[i][j][2]);
            float p3 = exp2f(acc[i][j][3]);
            csum += (p0 + p1) + (p2 + p3);
            ((int*)&d)[i] = pk4(p0, p1, p2, p3);
        }
        csum += __shfl_xor(csum, 16);
        csum += __shfl_xor(csum, 32);
        if (lane < 16)
            atomicAdd(&rowsum[(b << 12) + mL0 + j * 16 + ln], csum);
        int lt = (mL0 >> 4) + j;
        *(int4*)(Pb + (((size_t)(lt * 64 + sp)) * 64 + lane) * 16) = d;
    }
}

// Pass 2: O^T = V^T . P^T (operand swap). att-row lands on lane axis =
// attn_out's A-frag orientation. No LDS, no barriers, depth-2 prefetch.
__global__ __launch_bounds__(256) void pv_kernel(
        const unsigned char* __restrict__ pmat8, const unsigned char* __restrict__ vsw8,
        const float* __restrict__ rowsum,
        _Float16* __restrict__ att1, _Float16* __restrict__ att2) {
    int w = threadIdx.x >> 6, lane = threadIdx.x & 63;
    int quad = lane >> 4, ln = lane & 15;
    int rowG0 = blockIdx.x * 32;
    int b = rowG0 >> 12;
    int lt0 = (rowG0 & (L_ - 1)) >> 4;   // 2 m-tiles
    const unsigned char* Pb = pmat8 + (size_t)b * (16u << 20);
    const unsigned char* Vb = vsw8 + (size_t)b * (1u << 20);

    f32x4 acc[4][2];
    #pragma unroll
    for (int i = 0; i < 4; i++)
        #pragma unroll
        for (int c = 0; c < 2; c++) acc[i][c] = f32x4{0.f, 0.f, 0.f, 0.f};

    lng2 Vf[2][4], Pf[2][2];
    #pragma unroll
    for (int p = 0; p < 2; p++) {
        #pragma unroll
        for (int i = 0; i < 4; i++)
            Vf[p][i] = *(const lng2*)(Vb + (((size_t)(p * 16 + w * 4 + i)) * 64 + lane) * 16);
        #pragma unroll
        for (int c = 0; c < 2; c++)
            Pf[p][c] = *(const lng2*)(Pb + (((size_t)((lt0 + c) * 64 + p)) * 64 + lane) * 16);
    }

    #define PVSTEP(buf, sp) do {                                                     \
        int spn = ((sp) + 2 < 64) ? (sp) + 2 : 63;                                   \
        lng2 Vn[4], Pn[2];                                                           \
        _Pragma("unroll")                                                            \
        for (int i = 0; i < 4; i++)                                                  \
            Vn[i] = *(const lng2*)(Vb + (((size_t)(spn * 16 + w * 4 + i)) * 64 + lane) * 16); \
        _Pragma("unroll")                                                            \
        for (int c = 0; c < 2; c++)                                                  \
            Pn[c] = *(const lng2*)(Pb + (((size_t)((lt0 + c) * 64 + spn)) * 64 + lane) * 16); \
        _Pragma("unroll")                                                            \
        for (int i = 0; i < 4; i++)                                                  \
            _Pragma("unroll")                                                        \
            for (int c = 0; c < 2; c++) {                                            \
                acc[i][c] = mfma8(Vf[buf][i].x, Pf[buf][c].x, acc[i][c]);             \
                acc[i][c] = mfma8(Vf[buf][i].y, Pf[buf][c].y, acc[i][c]);             \
            }                                                                        \
        _Pragma("unroll")                                                            \
        for (int i = 0; i < 4; i++) Vf[buf][i] = Vn[i];                              \
        _Pragma("unroll")                                                            \
        for (int c = 0; c < 2; c++) Pf[buf][c] = Pn[c];                              \
    } while (0)

    for (int sp = 0; sp < 64; sp += 2) {
        PVSTEP(0, sp);
        PVSTEP(1, sp + 1);
    }
    #undef PVSTEP

    _Float16* att = (w >= 2) ? att2 : att1;
    #pragma unroll
    for (int c = 0; c < 2; c++) {
        float inv = 1.f / rowsum[rowG0 + c * 16 + ln];
        int lt = (rowG0 >> 4) + c;
        #pragma unroll
        for (int sl = 0; sl < 2; sl++) {
            half8 v;
            #pragma unroll
            for (int r = 0; r < 4; r++) {
                v[r]     = (_Float16)(acc[2 * sl][c][r] * inv);
                v[r + 4] = (_Float16)(acc[2 * sl + 1][c][r] * inv);
            }
            int s = (w & 1) * 2 + sl;
            *(half8*)(att + ((size_t)((lt * 4 + s) * 64 + lane)) * 8) = v;
        }
    }
}

// out_s = att_s @ Wp_s + bias + residual ; concat -> res (fp16) ; LNf -> xn (FR fp16)
__global__ __launch_bounds__(256) void attn_out_kernel(const _Float16* att1, const _Float16* att2,
        const _Float16* wsw, const float* bp1, const float* bp2,
        const float* x1, const float* x2, const float* lnf_g, const float* lnf_b,
        _Float16* res, _Float16* xn) {
    int wave = threadIdx.x >> 6, lane = threadIdx.x & 63;
    int quad = lane >> 4, ln = lane & 15;
    int mbase = blockIdx.x * 64 + wave * 16;
    int lt = mbase >> 4;
    const _Float16* Wp1 = wsw + WP1_OFF;
    const _Float16* Wp2 = wsw + WP2_OFF;

    half8 a1[4], a2[4];
    #pragma unroll
    for (int s = 0; s < 4; s++) {
        a1[s] = *(const half8*)(att1 + ((size_t)((lt * 4 + s) * 64 + lane)) * 8);
        a2[s] = *(const half8*)(att2 + ((size_t)((lt * 4 + s) * 64 + lane)) * 8);
    }
    f32x4 y1[8], y2[8];
    #pragma unroll
    for (int c = 0; c < 8; c++) {
        y1[c] = f32x4{0,0,0,0}; y2[c] = f32x4{0,0,0,0};
        #pragma unroll
        for (int s = 0; s < 4; s++) {
            y1[c] = mfma16(a1[s], *(const half8*)(Wp1 + ((size_t)((s * 8 + c) * 64 + lane)) * 8), y1[c]);
            y2[c] = mfma16(a2[s], *(const half8*)(Wp2 + ((size_t)((s * 8 + c) * 64 + lane)) * 8), y2[c]);
        }
    }
    #pragma unroll
    for (int c = 0; c < 8; c++) {
        int n = c * 16 + ln;
        float b1v = bp1[n], b2v = bp2[n];
        #pragma unroll
        for (int r = 0; r < 4; r++) {
            int m = mbase + quad * 4 + r;
            y1[c][r] += b1v + x1[(size_t)m * D_ + n];
            y2[c][r] += b2v + x2[(size_t)m * D_ + n];
        }
    }
    float sum[4] = {0,0,0,0}, sq[4] = {0,0,0,0};
    #pragma unroll
    for (int c = 0; c < 8; c++)
        #pragma unroll
        for (int r = 0; r < 4; r++) {
            sum[r] += y1[c][r] + y2[c][r];
            sq[r]  += y1[c][r] * y1[c][r] + y2[c][r] * y2[c][r];
        }
    #pragma unroll
    for (int off = 1; off < 16; off <<= 1)
        #pragma unroll
        for (int r = 0; r < 4; r++) { sum[r] += __shfl_xor(sum[r], off); sq[r] += __shfl_xor(sq[r], off); }
    #pragma unroll
    for (int r = 0; r < 4; r++) {
        float mean = sum[r] * (1.f / 256.f);
        float var = sq[r] * (1.f / 256.f) - mean * mean;
        float inv = rsqrtf(var + 1e-5f);
        int m = mbase + quad * 4 + r;
        int lt_m = m >> 4;
        #pragma unroll
        for (int c = 0; c < 8; c++) {
            int n = c * 16 + ln;
            res[(size_t)m * D2_ + n]       = (_Float16)y1[c][r];
            res[(size_t)m * D2_ + 128 + n] = (_Float16)y2[c][r];
            float yn1 = (y1[c][r] - mean) * inv * lnf_g[n] + lnf_b[n];
            float yn2 = (y2[c][r] - mean) * inv * lnf_g[128 + n] + lnf_b[128 + n];
            int s_x = n >> 5, q_x = (n >> 3) & 3, j = n & 7;
            xn[((size_t)((lt_m * 8 + s_x) * 64 + q_x * 16 + (m & 15))) * 8 + j] = (_Float16)yn1;
            int n2 = 128 + n;
            int s_y = n2 >> 5, q_y = (n2 >> 3) & 3, j2 = n2 & 7;
            xn[((size_t)((lt_m * 8 + s_y) * 64 + q_y * 16 + (m & 15))) * 8 + j2] = (_Float16)yn2;
        }
    }
}

// h = gelu(xn @ Wf1 + bf1)  [M x 512], FR in/out. Explicit W-prefetch pipeline
// over c: next 8 W-frags load during current 8 MFMAs.
__global__ __launch_bounds__(256) void ffn1_kernel(const _Float16* xn, const _Float16* wsw,
        const float* bf1, _Float16* h) {
    int wave = threadIdx.x >> 6, lane = threadIdx.x & 63;
    int quad = lane >> 4, ln = lane & 15;
    int mbase = blockIdx.x * 64 + wave * 16;
    int lt = mbase >> 4;
    int nt = blockIdx.y;   // 0..3
    const _Float16* W = wsw + WF1_OFF;   // K=256, N=512, nc=32

    half8 a[8];
    #pragma unroll
    for (int s = 0; s < 8; s++)
        a[s] = *(const half8*)(xn + ((size_t)((lt * 8 + s) * 64 + lane)) * 8);

    f32x4 acc[8];
    #pragma unroll
    for (int c = 0; c < 8; c++) acc[c] = f32x4{0,0,0,0};

    half8 Wc[8], Wn[8];
    #pragma unroll
    for (int s = 0; s < 8; s++)
        Wc[s] = *(const half8*)(W + ((size_t)((s * 32 + nt * 8) * 64 + lane)) * 8);
    #pragma unroll
    for (int c = 0; c < 8; c++) {
        int cn = (c < 7) ? c + 1 : 7;
        #pragma unroll
        for (int s = 0; s < 8; s++)
            Wn[s] = *(const half8*)(W + ((size_t)((s * 32 + nt * 8 + cn) * 64 + lane)) * 8);
        #pragma unroll
        for (int s = 0; s < 8; s++)
            acc[c] = mfma16(a[s], Wc[s], acc[c]);
        #pragma unroll
        for (int s = 0; s < 8; s++) Wc[s] = Wn[s];
    }
    #pragma unroll
    for (int c = 0; c < 8; c++) {
        int n = nt * 128 + c * 16 + ln;
        float bv = bf1[n];
        int s_h = n >> 5, q_h = (n >> 3) & 3, j = n & 7;
        #pragma unroll
        for (int r = 0; r < 4; r++) {
            float v = acc[c][r] + bv;
            float ge = 0.5f * v * (1.f + erff(v * 0.70710678118654752f));
            h[((size_t)((lt * 16 + s_h) * 64 + q_h * 16 + (quad * 4 + r))) * 8 + j] = (_Float16)ge;
        }
    }
}

// x = LN3(h @ Wf2 + bf2 + res) -> xn2 (FR fp16). Explicit software pipeline:
// prefetch step s+1's A-frag + 8 W-frags during step s's MFMA burst.
// (r7 evidence: un-pipelined k-loop was 46.8us at 3% MfmaUtil — pure latency.)
__global__ __launch_bounds__(256) void ffn2_kernel(const _Float16* h, const _Float16* wsw,
        const float* bf2, const _Float16* res, const float* g3, const float* b3, _Float16* xn2) {
    __shared__ float sst[2][16][2][2];
    int w = threadIdx.x >> 6, lane = threadIdx.x & 63;
    int quad = lane >> 4, ln = lane & 15;
    int rt = w & 1, nh = w >> 1;
    int mb = blockIdx.x * 32 + rt * 16;
    int lt = mb >> 4;
    const _Float16* W = wsw + WF2_OFF;   // K=512, N=256, nc=16

    f32x4 acc[8];
    #pragma unroll
    for (int c = 0; c < 8; c++) acc[c] = f32x4{0,0,0,0};

    half8 aC, aN;
    half8 Wc[8], Wn[8];
    aC = *(const half8*)(h + ((size_t)((lt * 16 + 0) * 64 + lane)) * 8);
    #pragma unroll
    for (int c = 0; c < 8; c++)
        Wc[c] = *(const half8*)(W + ((size_t)((0 * 16 + nh * 8 + c) * 64 + lane)) * 8);

    #pragma unroll
    for (int s = 0; s < 16; s++) {
        int sn = (s < 15) ? s + 1 : 15;
        aN = *(const half8*)(h + ((size_t)((lt * 16 + sn) * 64 + lane)) * 8);
        #pragma unroll
        for (int c = 0; c < 8; c++)
            Wn[c] = *(const half8*)(W + ((size_t)((sn * 16 + nh * 8 + c) * 64 + lane)) * 8);
        #pragma unroll
        for (int c = 0; c < 8; c++)
            acc[c] = mfma16(aC, Wc[c], acc[c]);
        aC = aN;
        #pragma unroll
        for (int c = 0; c < 8; c++) Wc[c] = Wn[c];
    }

    float y[8][4];
    float psum[4] = {0,0,0,0}, psq[4] = {0,0,0,0};
    #pragma unroll
    for (int c = 0; c < 8; c++) {
        int n = nh * 128 + c * 16 + ln;
        float bv = bf2[n];
        #pragma unroll
        for (int r = 0; r < 4; r++) {
            int m = mb + quad * 4 + r;
            float v = acc[c][r] + bv + (float)res[(size_t)m * D2_ + n];
            y[c][r] = v; psum[r] += v; psq[r] += v * v;
        }
    }
    #pragma unroll
    for (int off = 1; off < 16; off <<= 1)
        #pragma unroll
        for (int r = 0; r < 4; r++) { psum[r] += __shfl_xor(psum[r], off); psq[r] += __shfl_xor(psq[r], off); }
    if (ln == 0)
        #pragma unroll
        for (int r = 0; r < 4; r++) { sst[rt][quad * 4 + r][nh][0] = psum[r]; sst[rt][quad * 4 + r][nh][1] = psq[r]; }
    __syncthreads();
    #pragma unroll
    for (int r = 0; r < 4; r++) {
        float su = sst[rt][quad * 4 + r][0][0] + sst[rt][quad * 4 + r][1][0];
        float sq = sst[rt][quad * 4 + r][0][1] + sst[rt][quad * 4 + r][1][1];
        float mean = su * (1.f / 256.f);
        float var = sq * (1.f / 256.f) - mean * mean;
        float invs = rsqrtf(var + 1e-5f);
        #pragma unroll
        for (int c = 0; c < 8; c++) {
            int n = nh * 128 + c * 16 + ln;
            float yn = (y[c][r] - mean) * invs * g3[n] + b3[n];
            int s_x = n >> 5, q_x = (n >> 3) & 3, j = n & 7;
            xn2[((size_t)((lt * 8 + s_x) * 64 + q_x * 16 + (quad * 4 + r))) * 8 + j] = (_Float16)yn;
        }
    }
}

// out = xn2 @ Wo + bo [M x 55] fp32. Block: 2 rowtiles x 2 K-halves, LDS combine.
__global__ __launch_bounds__(256) void out_kernel(const _Float16* xn2, const _Float16* wsw,
        const float* bo, float* out) {
    __shared__ f32x4 pc[2][4][64];
    int w = threadIdx.x >> 6, lane = threadIdx.x & 63;
    int quad = lane >> 4, ln = lane & 15;
    int rt = w & 1, kh = w >> 1;
    int mb = blockIdx.x * 32 + rt * 16;
    int lt = mb >> 4;
    const _Float16* W = wsw + WO_OFF;   // K=256, N=64(padded), nc=4

    f32x4 acc[4];
    #pragma unroll
    for (int c = 0; c < 4; c++) acc[c] = f32x4{0,0,0,0};
    #pragma unroll
    for (int ss = 0; ss < 4; ss++) {
        int s = kh * 4 + ss;
        half8 a = *(const half8*)(xn2 + ((size_t)((lt * 8 + s) * 64 + lane)) * 8);
        #pragma unroll
        for (int c = 0; c < 4; c++)
            acc[c] = mfma16(a, *(const half8*)(W + ((size_t)((s * 4 + c) * 64 + lane)) * 8), acc[c]);
    }
    if (kh == 1)
        #pragma unroll
        for (int c = 0; c < 4; c++) pc[rt][c][lane] = acc[c];
    __syncthreads();
    if (kh == 0) {
        #pragma unroll
        for (int c = 0; c < 4; c++) {
            f32x4 p = pc[rt][c][lane];
            int n = c * 16 + ln;
            if (n < OUT_) {
                float bv = bo[n];
                #pragma unroll
                for (int r = 0; r < 4; r++)
                    out[(size_t)(mb + quad * 4 + r) * OUT_ + n] = acc[c][r] + p[r] + bv;
            }
        }
    }
}

extern "C" void kernel_launch(void* const* d_in, const int* in_sizes, int n_in,
                              void* d_out, int out_size, void* d_ws, size_t ws_size,
                              hipStream_t stream) {
    const float* x1    = (const float*)d_in[0];
    const float* x2    = (const float*)d_in[1];
    const float* ln1_g = (const float*)d_in[2];
    const float* ln1_b = (const float*)d_in[3];
    const float* ln2_g = (const float*)d_in[4];
    const float* ln2_b = (const float*)d_in[5];
    const float* Wq    = (const float*)d_in[6];
    const float* bq    = (const float*)d_in[7];
    const float* Wv1   = (const float*)d_in[8];
    const float* bv1   = (const float*)d_in[9];
    const float* Wk    = (const float*)d_in[10];
    const float* bk    = (const float*)d_in[11];
    const float* Wv2   = (const float*)d_in[12];
    const float* bv2   = (const float*)d_in[13];
    const float* Wp1   = (const float*)d_in[14];
    const float* bp1   = (const float*)d_in[15];
    const float* Wp2   = (const float*)d_in[16];
    const float* bp2   = (const float*)d_in[17];
    const float* lnf_g = (const float*)d_in[18];
    const float* lnf_b = (const float*)d_in[19];
    const float* Wf1   = (const float*)d_in[20];
    const float* bf1   = (const float*)d_in[21];
    const float* Wf2   = (const float*)d_in[22];
    const float* bf2   = (const float*)d_in[23];
    const float* ln3_g = (const float*)d_in[24];
    const float* ln3_b = (const float*)d_in[25];
    const float* Wo    = (const float*)d_in[26];
    const float* bo    = (const float*)d_in[27];
    float* out = (float*)d_out;

    char* ws = (char*)d_ws;
    const size_t MB = 1 << 20;
    _Float16* q1sw   = (_Float16*)(ws + 0 * MB);    // 4 MB
    _Float16* k2sw   = (_Float16*)(ws + 4 * MB);    // 4 MB
    unsigned char* vsw8 = (unsigned char*)(ws + 8 * MB);   // 4 MB (fp8 Vcat per batch)
    _Float16* att1   = (_Float16*)(ws + 12 * MB);   // 4 MB
    _Float16* att2   = (_Float16*)(ws + 16 * MB);   // 4 MB
    _Float16* x1n    = (_Float16*)(ws + 20 * MB);   // 4 MB
    _Float16* x2n    = (_Float16*)(ws + 24 * MB);   // 4 MB
    _Float16* wsw    = (_Float16*)(ws + 28 * MB);   // ~0.74 MB
    float*    rowsum = (float*)   (ws + 29 * MB);   // 64 KB
    _Float16* res    = (_Float16*)(ws + 30 * MB);   // 8 MB (fp16 now)
    _Float16* xn     = (_Float16*)(ws + 46 * MB);   // 8 MB
    _Float16* h      = (_Float16*)(ws + 54 * MB);   // 16 MB
    _Float16* xn2    = (_Float16*)(ws + 70 * MB);   // 8 MB
    unsigned char* pmat8 = (unsigned char*)(ws + 78 * MB); // 64 MB (fp8 P per batch)

    prep_kernel<<<dim3(512, 9), 256, 0, stream>>>(Wq, Wv1, Wk, Wv2, Wp1, Wp2, Wf1, Wf2, Wo, wsw);
    ln_kernel<<<dim3(M_ / 4, 2), 256, 0, stream>>>(x1, x2, ln1_g, ln1_b, ln2_g, ln2_b, x1n, x2n);
    proj_kernel<<<dim3(M_ / 64, 4), 256, 0, stream>>>(x1n, x2n, wsw, bq, bv1, bk, bv2,
                                                      q1sw, k2sw, vsw8);
    zero_kernel<<<dim3(16), 256, 0, stream>>>(rowsum);
    score_kernel<<<dim3(32, 32, 4), 256, 0, stream>>>(q1sw, k2sw, pmat8, rowsum);
    pv_kernel<<<dim3(M_ / 32), 256, 0, stream>>>(pmat8, vsw8, rowsum, att1, att2);
    attn_out_kernel<<<dim3(M_ / 64), 256, 0, stream>>>(att1, att2, wsw, bp1, bp2,
                                                       x1, x2, lnf_g, lnf_b, res, xn);
    ffn1_kernel<<<dim3(M_ / 64, 4), 256, 0, stream>>>(xn, wsw, bf1, h);
    ffn2_kernel<<<dim3(M_ / 32), 256, 0, stream>>>(h, wsw, bf2, res, ln3_g, ln3_b, xn2);
    out_kernel<<<dim3(M_ / 32), 256, 0, stream>>>(xn2, wsw, bo, out);
}

// Round 9
// 249.590 us; speedup vs baseline: 2.4327x; 1.0323x over previous
//
#include <hip/hip_runtime.h>
#include <hip/hip_fp16.h>

typedef _Float16 half8 __attribute__((ext_vector_type(8)));
typedef float f32x4 __attribute__((ext_vector_type(4)));
typedef long lng2 __attribute__((ext_vector_type(2)));

#define B_   4
#define L_   4096
#define D_   128
#define M_   (B_*L_)     // 16384
#define D2_  256
#define H_   512
#define OUT_ 55

__device__ __forceinline__ f32x4 mfma16(half8 a, half8 b, f32x4 c) {
    return __builtin_amdgcn_mfma_f32_16x16x32_f16(a, b, c, 0, 0, 0);
}
__device__ __forceinline__ f32x4 mfma8(long a, long b, f32x4 c) {
    return __builtin_amdgcn_mfma_f32_16x16x32_fp8_fp8(a, b, c, 0, 0, 0);
}
// pack 4 floats -> 4 fp8 e4m3 bytes (OCP on gfx950)
__device__ __forceinline__ int pk4(float a, float b, float c, float d) {
    int t = __builtin_amdgcn_cvt_pk_fp8_f32(a, b, 0, false);
    return __builtin_amdgcn_cvt_pk_fp8_f32(c, d, t, true);
}
// raw v_exp_f32 — exp2f w/o fast-math lowers to OCML denorm-safe seq (~25cyc, r8 VALUBusy=47%)
__device__ __forceinline__ float fexp2(float x) { return __builtin_amdgcn_exp2f(x); }

// fold softmax scale (1/sqrt(128)) * log2(e) into k2 so score uses bare v_exp
#define KSCL (0.08838834764831845f * 1.4426950408889634f)

// ---- weight swizzle offsets (in halfs) within wsw region ----
#define WQ_OFF   0
#define WV1_OFF  16384
#define WK_OFF   32768
#define WV2_OFF  49152
#define WP1_OFF  65536
#define WP2_OFF  81920
#define WF1_OFF  98304     // 256x512 = 131072
#define WF2_OFF  229376    // 512x256 = 131072
#define WO_OFF   360448    // 256x64 (padded) = 16384

// Permuted k-map (within a 32-k chunk): k5 = (h<4 ? q*4+h : 16+q*4+(h-4)).
// Used for fp8 P & V and fp16 att & Wp1/Wp2 — A/B agree pairwise.

// Pre-swizzle weights (fp32 row-major [K][N]) into B-fragment layout fp16.
// canonical: q=(k>>3)&3, j=k&7 ; permK (Wp1/Wp2 only): q=(k>>2)&3, j=(k&3)+4*((k>>4)&1)
__global__ void prep_kernel(const float* Wq, const float* Wv1, const float* Wk,
                            const float* Wv2, const float* Wp1, const float* Wp2,
                            const float* Wf1, const float* Wf2, const float* Wo,
                            _Float16* wsw) {
    int id = blockIdx.y;
    int t  = blockIdx.x * 256 + threadIdx.x;
    const float* src = nullptr; int K = 0, N = 0, Npad = 0, off = 0;
    switch (id) {
        case 0: src = Wq;  K = 128; N = 128; Npad = 128; off = WQ_OFF;  break;
        case 1: src = Wv1; K = 128; N = 128; Npad = 128; off = WV1_OFF; break;
        case 2: src = Wk;  K = 128; N = 128; Npad = 128; off = WK_OFF;  break;
        case 3: src = Wv2; K = 128; N = 128; Npad = 128; off = WV2_OFF; break;
        case 4: src = Wp1; K = 128; N = 128; Npad = 128; off = WP1_OFF; break;
        case 5: src = Wp2; K = 128; N = 128; Npad = 128; off = WP2_OFF; break;
        case 6: src = Wf1; K = 256; N = 512; Npad = 512; off = WF1_OFF; break;
        case 7: src = Wf2; K = 512; N = 256; Npad = 256; off = WF2_OFF; break;
        case 8: src = Wo;  K = 256; N = 55;  Npad = 64;  off = WO_OFF;  break;
        default: return;
    }
    int total = K * Npad;
    if (t >= total) return;
    int k = t / Npad, n = t % Npad;
    float v = (n < N) ? src[k * N + n] : 0.f;
    int s = k >> 5, c = n >> 4, ln = n & 15;
    int q, j;
    if (id == 4 || id == 5) { q = (k >> 2) & 3; j = (k & 3) + (((k >> 4) & 1) << 2); }
    else                    { q = (k >> 3) & 3; j = k & 7; }
    int nc = Npad >> 4;
    wsw[off + ((size_t)((s * nc + c) * 64 + q * 16 + ln)) * 8 + j] = (_Float16)v;
}

// FR layout for X[M][C] halfs:
// idx = ((lt*(C/32) + s)*64 + q*16 + ln_r)*8 + j ; lt=row>>4, ln_r=row&15,
// s=col>>5, q=(col>>3)&3, j=col&7.

// LayerNorm over D=128, one wave per token, fp32 in -> fp16 FR-swizzled out
__global__ __launch_bounds__(256) void ln_kernel(const float* x1, const float* x2,
        const float* g1, const float* b1, const float* g2, const float* b2,
        _Float16* x1n, _Float16* x2n) {
    int wave = threadIdx.x >> 6, lane = threadIdx.x & 63;
    int token = blockIdx.x * 4 + wave;
    const float* x = blockIdx.y ? x2 : x1;
    const float* g = blockIdx.y ? g2 : g1;
    const float* bb = blockIdx.y ? b2 : b1;
    _Float16* o = blockIdx.y ? x2n : x1n;
    const float* xr = x + (size_t)token * D_;
    float a0 = xr[lane], a1 = xr[lane + 64];
    float s = a0 + a1, s2 = a0 * a0 + a1 * a1;
    #pragma unroll
    for (int off = 1; off < 64; off <<= 1) {
        s += __shfl_xor(s, off);
        s2 += __shfl_xor(s2, off);
    }
    float mean = s * (1.f / 128.f);
    float var = s2 * (1.f / 128.f) - mean * mean;
    float inv = rsqrtf(var + 1e-5f);
    int lt = token >> 4, ln_r = token & 15;
    #pragma unroll
    for (int h = 0; h < 2; h++) {
        int col = lane + h * 64;
        float v = (h ? a1 : a0);
        float out = (v - mean) * inv * g[col] + bb[col];
        int ss = col >> 5, q = (col >> 3) & 3, j = col & 7;
        o[((size_t)((lt * 4 + ss) * 64 + q * 16 + ln_r)) * 8 + j] = (_Float16)out;
    }
}

// Projections. q1 fp16 FR; k2 fp16 FR pre-scaled by KSCL; v1/v2 -> vsw8 fp8
// permuted-k B-frag layout. W-frag register prefetch pipeline over c.
__global__ __launch_bounds__(256) void proj_kernel(const _Float16* x1n, const _Float16* x2n,
        const _Float16* wsw, const float* bq, const float* bv1, const float* bk,
        const float* bv2, _Float16* q1, _Float16* k2, unsigned char* vsw8) {
    int g = blockIdx.y;   // 0:Wq 1:Wv1 2:Wk 3:Wv2
    const _Float16* A = (g < 2) ? x1n : x2n;
    const _Float16* Bw = wsw + g * 16384;
    const float* bias = (g == 0) ? bq : (g == 1) ? bv1 : (g == 2) ? bk : bv2;
    int wave = threadIdx.x >> 6, lane = threadIdx.x & 63;
    int quad = lane >> 4, ln = lane & 15;
    int mbase = blockIdx.x * 64 + wave * 16;
    int lt = mbase >> 4;

    half8 a[4];
    #pragma unroll
    for (int s = 0; s < 4; s++)
        a[s] = *(const half8*)(A + ((size_t)((lt * 4 + s) * 64 + lane)) * 8);

    f32x4 acc[8];
    #pragma unroll
    for (int c = 0; c < 8; c++) acc[c] = f32x4{0.f, 0.f, 0.f, 0.f};

    half8 Wc[4], Wn[4];
    #pragma unroll
    for (int s = 0; s < 4; s++)
        Wc[s] = *(const half8*)(Bw + ((size_t)((s * 8 + 0) * 64 + lane)) * 8);
    #pragma unroll
    for (int c = 0; c < 8; c++) {
        int cn = (c < 7) ? c + 1 : 7;
        #pragma unroll
        for (int s = 0; s < 4; s++)
            Wn[s] = *(const half8*)(Bw + ((size_t)((s * 8 + cn) * 64 + lane)) * 8);
        #pragma unroll
        for (int s = 0; s < 4; s++)
            acc[c] = mfma16(a[s], Wc[s], acc[c]);
        #pragma unroll
        for (int s = 0; s < 4; s++) Wc[s] = Wn[s];
    }

    bool isV = (g == 1) || (g == 3);
    if (!isV) {
        float scl = (g == 2) ? KSCL : 1.f;
        _Float16* out = (g == 0) ? q1 : k2;
        #pragma unroll
        for (int c = 0; c < 8; c++) {
            int n = c * 16 + ln;
            float bv = bias[n];
            #pragma unroll
            for (int r = 0; r < 4; r++) {
                int s_o = c >> 1, q_o = ((c & 1) << 1) | (ln >> 3), j = ln & 7;
                out[((size_t)((lt * 4 + s_o) * 64 + q_o * 16 + (quad * 4 + r))) * 8 + j]
                    = (_Float16)((acc[c][r] + bv) * scl);
            }
        }
    } else {
        int cbase = (g == 3) ? 8 : 0;
        int b = mbase >> 12;
        int l0 = (mbase & (L_ - 1)) + quad * 4;
        int sp = l0 >> 6, tt = (l0 >> 4) & 3, q2 = (l0 >> 2) & 3;
        unsigned char* Vb = vsw8 + (size_t)b * (1u << 20);
        #pragma unroll
        for (int c = 0; c < 8; c++) {
            int n = c * 16 + ln;
            float bv = bias[n];
            int pk = pk4(acc[c][0] + bv, acc[c][1] + bv, acc[c][2] + bv, acc[c][3] + bv);
            *(int*)(Vb + (((size_t)(sp * 16 + cbase + c) * 64 + q2 * 16 + ln) * 16 + tt * 4)) = pk;
        }
    }
}

__global__ __launch_bounds__(256) void zero_kernel(float* rowsum) {
    int i = (blockIdx.x * 256 + threadIdx.x) * 4;
    *(f32x4*)(rowsum + i) = f32x4{0.f, 0.f, 0.f, 0.f};
}

// Pass 1: S^T tiles (A=q1 rows = softmax k-dim, B=k2^T cols = att rows).
// p = exp2(acc) via raw v_exp_f32; pk4 over r -> permuted-k fp8 A-entries.
__global__ __launch_bounds__(256) void score_kernel(
        const _Float16* __restrict__ q1sw, const _Float16* __restrict__ k2sw,
        unsigned char* __restrict__ pmat8, float* __restrict__ rowsum) {
    int w = threadIdx.x >> 6, lane = threadIdx.x & 63;
    int quad = lane >> 4, ln = lane & 15;
    int b = blockIdx.z;
    int kL0 = blockIdx.y * 128 + (w & 1) * 64;     // q1 rows (contraction dim of PV)
    int mL0 = blockIdx.x * 128 + (w >> 1) * 64;    // k2 rows (att rows)
    int ltk = ((b << 12) + kL0) >> 4;
    int ltm = ((b << 12) + mL0) >> 4;

    f32x4 acc[4][4];
    #pragma unroll
    for (int i = 0; i < 4; i++)
        #pragma unroll
        for (int j = 0; j < 4; j++) acc[i][j] = f32x4{0.f, 0.f, 0.f, 0.f};

    #pragma unroll
    for (int s = 0; s < 4; s++) {
        half8 a[4], bq[4];
        #pragma unroll
        for (int i = 0; i < 4; i++)
            a[i] = *(const half8*)(q1sw + ((size_t)(((ltk + i) * 4 + s) * 64 + lane)) * 8);
        #pragma unroll
        for (int j = 0; j < 4; j++)
            bq[j] = *(const half8*)(k2sw + ((size_t)(((ltm + j) * 4 + s) * 64 + lane)) * 8);
        #pragma unroll
        for (int i = 0; i < 4; i++)
            #pragma unroll
            for (int j = 0; j < 4; j++)
                acc[i][j] = mfma16(a[i], bq[j], acc[i][j]);
    }

    unsigned char* Pb = pmat8 + (size_t)b * (16u << 20);
    int sp = kL0 >> 6;
    #pragma unroll
    for (int j = 0; j < 4; j++) {
        int4 d;
        float csum = 0.f;
        #pragma unroll
        for (int i = 0; i < 4; i++) {
            float p0 = fexp2(acc[i][j][0]);
            float p1 = fexp2(acc[i][j][1]);
            float p2 = fexp2(acc[i][j][2]);
            float p3 = fexp2(acc[i][j][3]);
            csum += (p0 + p1) + (p2 + p3);
            ((int*)&d)[i] = pk4(p0, p1, p2, p3);
        }
        csum += __shfl_xor(csum, 16);
        csum += __shfl_xor(csum, 32);
        if (lane < 16)
            atomicAdd(&rowsum[(b << 12) + mL0 + j * 16 + ln], csum);
        int lt = (mL0 >> 4) + j;
        *(int4*)(Pb + (((size_t)(lt * 64 + sp)) * 64 + lane) * 16) = d;
    }
}

// Pass 2: O^T = V^T . P^T (operand swap). att-row lands on lane axis =
// attn_out's A-frag orientation. No LDS, no barriers, depth-2 prefetch.
__global__ __launch_bounds__(256) void pv_kernel(
        const unsigned char* __restrict__ pmat8, const unsigned char* __restrict__ vsw8,
        const float* __restrict__ rowsum,
        _Float16* __restrict__ att1, _Float16* __restrict__ att2) {
    int w = threadIdx.x >> 6, lane = threadIdx.x & 63;
    int quad = lane >> 4, ln = lane & 15;
    int rowG0 = blockIdx.x * 32;
    int b = rowG0 >> 12;
    int lt0 = (rowG0 & (L_ - 1)) >> 4;   // 2 m-tiles
    const unsigned char* Pb = pmat8 + (size_t)b * (16u << 20);
    const unsigned char* Vb = vsw8 + (size_t)b * (1u << 20);

    f32x4 acc[4][2];
    #pragma unroll
    for (int i = 0; i < 4; i++)
        #pragma unroll
        for (int c = 0; c < 2; c++) acc[i][c] = f32x4{0.f, 0.f, 0.f, 0.f};

    lng2 Vf[2][4], Pf[2][2];
    #pragma unroll
    for (int p = 0; p < 2; p++) {
        #pragma unroll
        for (int i = 0; i < 4; i++)
            Vf[p][i] = *(const lng2*)(Vb + (((size_t)(p * 16 + w * 4 + i)) * 64 + lane) * 16);
        #pragma unroll
        for (int c = 0; c < 2; c++)
            Pf[p][c] = *(const lng2*)(Pb + (((size_t)((lt0 + c) * 64 + p)) * 64 + lane) * 16);
    }

    #define PVSTEP(buf, sp) do {                                                     \
        int spn = ((sp) + 2 < 64) ? (sp) + 2 : 63;                                   \
        lng2 Vn[4], Pn[2];                                                           \
        _Pragma("unroll")                                                            \
        for (int i = 0; i < 4; i++)                                                  \
            Vn[i] = *(const lng2*)(Vb + (((size_t)(spn * 16 + w * 4 + i)) * 64 + lane) * 16); \
        _Pragma("unroll")                                                            \
        for (int c = 0; c < 2; c++)                                                  \
            Pn[c] = *(const lng2*)(Pb + (((size_t)((lt0 + c) * 64 + spn)) * 64 + lane) * 16); \
        _Pragma("unroll")                                                            \
        for (int i = 0; i < 4; i++)                                                  \
            _Pragma("unroll")                                                        \
            for (int c = 0; c < 2; c++) {                                            \
                acc[i][c] = mfma8(Vf[buf][i].x, Pf[buf][c].x, acc[i][c]);             \
                acc[i][c] = mfma8(Vf[buf][i].y, Pf[buf][c].y, acc[i][c]);             \
            }                                                                        \
        _Pragma("unroll")                                                            \
        for (int i = 0; i < 4; i++) Vf[buf][i] = Vn[i];                              \
        _Pragma("unroll")                                                            \
        for (int c = 0; c < 2; c++) Pf[buf][c] = Pn[c];                              \
    } while (0)

    for (int sp = 0; sp < 64; sp += 2) {
        PVSTEP(0, sp);
        PVSTEP(1, sp + 1);
    }
    #undef PVSTEP

    _Float16* att = (w >= 2) ? att2 : att1;
    #pragma unroll
    for (int c = 0; c < 2; c++) {
        float inv = 1.f / rowsum[rowG0 + c * 16 + ln];
        int lt = (rowG0 >> 4) + c;
        #pragma unroll
        for (int sl = 0; sl < 2; sl++) {
            half8 v;
            #pragma unroll
            for (int r = 0; r < 4; r++) {
                v[r]     = (_Float16)(acc[2 * sl][c][r] * inv);
                v[r + 4] = (_Float16)(acc[2 * sl + 1][c][r] * inv);
            }
            int s = (w & 1) * 2 + sl;
            *(half8*)(att + ((size_t)((lt * 4 + s) * 64 + lane)) * 8) = v;
        }
    }
}

// out_s = att_s @ Wp_s + bias + residual ; concat -> res (fp16) ; LNf -> xn (FR fp16)
// W-frag register prefetch pipeline over c.
__global__ __launch_bounds__(256) void attn_out_kernel(const _Float16* att1, const _Float16* att2,
        const _Float16* wsw, const float* bp1, const float* bp2,
        const float* x1, const float* x2, const float* lnf_g, const float* lnf_b,
        _Float16* res, _Float16* xn) {
    int wave = threadIdx.x >> 6, lane = threadIdx.x & 63;
    int quad = lane >> 4, ln = lane & 15;
    int mbase = blockIdx.x * 64 + wave * 16;
    int lt = mbase >> 4;
    const _Float16* Wp1 = wsw + WP1_OFF;
    const _Float16* Wp2 = wsw + WP2_OFF;

    half8 a1[4], a2[4];
    #pragma unroll
    for (int s = 0; s < 4; s++) {
        a1[s] = *(const half8*)(att1 + ((size_t)((lt * 4 + s) * 64 + lane)) * 8);
        a2[s] = *(const half8*)(att2 + ((size_t)((lt * 4 + s) * 64 + lane)) * 8);
    }
    f32x4 y1[8], y2[8];
    #pragma unroll
    for (int c = 0; c < 8; c++) { y1[c] = f32x4{0,0,0,0}; y2[c] = f32x4{0,0,0,0}; }

    half8 W1c[4], W2c[4], W1n[4], W2n[4];
    #pragma unroll
    for (int s = 0; s < 4; s++) {
        W1c[s] = *(const half8*)(Wp1 + ((size_t)((s * 8 + 0) * 64 + lane)) * 8);
        W2c[s] = *(const half8*)(Wp2 + ((size_t)((s * 8 + 0) * 64 + lane)) * 8);
    }
    #pragma unroll
    for (int c = 0; c < 8; c++) {
        int cn = (c < 7) ? c + 1 : 7;
        #pragma unroll
        for (int s = 0; s < 4; s++) {
            W1n[s] = *(const half8*)(Wp1 + ((size_t)((s * 8 + cn) * 64 + lane)) * 8);
            W2n[s] = *(const half8*)(Wp2 + ((size_t)((s * 8 + cn) * 64 + lane)) * 8);
        }
        #pragma unroll
        for (int s = 0; s < 4; s++) {
            y1[c] = mfma16(a1[s], W1c[s], y1[c]);
            y2[c] = mfma16(a2[s], W2c[s], y2[c]);
        }
        #pragma unroll
        for (int s = 0; s < 4; s++) { W1c[s] = W1n[s]; W2c[s] = W2n[s]; }
    }

    #pragma unroll
    for (int c = 0; c < 8; c++) {
        int n = c * 16 + ln;
        float b1v = bp1[n], b2v = bp2[n];
        #pragma unroll
        for (int r = 0; r < 4; r++) {
            int m = mbase + quad * 4 + r;
            y1[c][r] += b1v + x1[(size_t)m * D_ + n];
            y2[c][r] += b2v + x2[(size_t)m * D_ + n];
        }
    }
    float sum[4] = {0,0,0,0}, sq[4] = {0,0,0,0};
    #pragma unroll
    for (int c = 0; c < 8; c++)
        #pragma unroll
        for (int r = 0; r < 4; r++) {
            sum[r] += y1[c][r] + y2[c][r];
            sq[r]  += y1[c][r] * y1[c][r] + y2[c][r] * y2[c][r];
        }
    #pragma unroll
    for (int off = 1; off < 16; off <<= 1)
        #pragma unroll
        for (int r = 0; r < 4; r++) { sum[r] += __shfl_xor(sum[r], off); sq[r] += __shfl_xor(sq[r], off); }
    #pragma unroll
    for (int r = 0; r < 4; r++) {
        float mean = sum[r] * (1.f / 256.f);
        float var = sq[r] * (1.f / 256.f) - mean * mean;
        float inv = rsqrtf(var + 1e-5f);
        int m = mbase + quad * 4 + r;
        int lt_m = m >> 4;
        #pragma unroll
        for (int c = 0; c < 8; c++) {
            int n = c * 16 + ln;
            res[(size_t)m * D2_ + n]       = (_Float16)y1[c][r];
            res[(size_t)m * D2_ + 128 + n] = (_Float16)y2[c][r];
            float yn1 = (y1[c][r] - mean) * inv * lnf_g[n] + lnf_b[n];
            float yn2 = (y2[c][r] - mean) * inv * lnf_g[128 + n] + lnf_b[128 + n];
            int s_x = n >> 5, q_x = (n >> 3) & 3, j = n & 7;
            xn[((size_t)((lt_m * 8 + s_x) * 64 + q_x * 16 + (m & 15))) * 8 + j] = (_Float16)yn1;
            int n2 = 128 + n;
            int s_y = n2 >> 5, q_y = (n2 >> 3) & 3, j2 = n2 & 7;
            xn[((size_t)((lt_m * 8 + s_y) * 64 + q_y * 16 + (m & 15))) * 8 + j2] = (_Float16)yn2;
        }
    }
}

// h = gelu(xn @ Wf1 + bf1)  [M x 512], FR in/out. W-prefetch pipeline; fast
// tanh-form GELU (x*sigmoid(2u)) via raw v_exp — erff was ~20-instr polynomial.
__global__ __launch_bounds__(256) void ffn1_kernel(const _Float16* xn, const _Float16* wsw,
        const float* bf1, _Float16* h) {
    int wave = threadIdx.x >> 6, lane = threadIdx.x & 63;
    int quad = lane >> 4, ln = lane & 15;
    int mbase = blockIdx.x * 64 + wave * 16;
    int lt = mbase >> 4;
    int nt = blockIdx.y;   // 0..3
    const _Float16* W = wsw + WF1_OFF;   // K=256, N=512, nc=32

    half8 a[8];
    #pragma unroll
    for (int s = 0; s < 8; s++)
        a[s] = *(const half8*)(xn + ((size_t)((lt * 8 + s) * 64 + lane)) * 8);

    f32x4 acc[8];
    #pragma unroll
    for (int c = 0; c < 8; c++) acc[c] = f32x4{0,0,0,0};

    half8 Wc[8], Wn[8];
    #pragma unroll
    for (int s = 0; s < 8; s++)
        Wc[s] = *(const half8*)(W + ((size_t)((s * 32 + nt * 8) * 64 + lane)) * 8);
    #pragma unroll
    for (int c = 0; c < 8; c++) {
        int cn = (c < 7) ? c + 1 : 7;
        #pragma unroll
        for (int s = 0; s < 8; s++)
            Wn[s] = *(const half8*)(W + ((size_t)((s * 32 + nt * 8 + cn) * 64 + lane)) * 8);
        #pragma unroll
        for (int s = 0; s < 8; s++)
            acc[c] = mfma16(a[s], Wc[s], acc[c]);
        #pragma unroll
        for (int s = 0; s < 8; s++) Wc[s] = Wn[s];
    }
    #pragma unroll
    for (int c = 0; c < 8; c++) {
        int n = nt * 128 + c * 16 + ln;
        float bv = bf1[n];
        int s_h = n >> 5, q_h = (n >> 3) & 3, j = n & 7;
        #pragma unroll
        for (int r = 0; r < 4; r++) {
            float v = acc[c][r] + bv;
            // gelu_tanh(v) = v * sigmoid(2*0.79788456*(v + 0.044715 v^3))
            float u = 0.7978845608f * (v + 0.044715f * v * v * v);
            float e = fexp2(-2.8853900818f * u);     // 2*log2(e)*u
            float ge = v * __builtin_amdgcn_rcpf(1.f + e);
            h[((size_t)((lt * 16 + s_h) * 64 + q_h * 16 + (quad * 4 + r))) * 8 + j] = (_Float16)ge;
        }
    }
}

// x = LN3(h @ Wf2 + bf2 + res) -> xn2 (FR fp16). Software-pipelined K-loop.
__global__ __launch_bounds__(256) void ffn2_kernel(const _Float16* h, const _Float16* wsw,
        const float* bf2, const _Float16* res, const float* g3, const float* b3, _Float16* xn2) {
    __shared__ float sst[2][16][2][2];
    int w = threadIdx.x >> 6, lane = threadIdx.x & 63;
    int quad = lane >> 4, ln = lane & 15;
    int rt = w & 1, nh = w >> 1;
    int mb = blockIdx.x * 32 + rt * 16;
    int lt = mb >> 4;
    const _Float16* W = wsw + WF2_OFF;   // K=512, N=256, nc=16

    f32x4 acc[8];
    #pragma unroll
    for (int c = 0; c < 8; c++) acc[c] = f32x4{0,0,0,0};

    half8 aC, aN;
    half8 Wc[8], Wn[8];
    aC = *(const half8*)(h + ((size_t)((lt * 16 + 0) * 64 + lane)) * 8);
    #pragma unroll
    for (int c = 0; c < 8; c++)
        Wc[c] = *(const half8*)(W + ((size_t)((0 * 16 + nh * 8 + c) * 64 + lane)) * 8);

    #pragma unroll
    for (int s = 0; s < 16; s++) {
        int sn = (s < 15) ? s + 1 : 15;
        aN = *(const half8*)(h + ((size_t)((lt * 16 + sn) * 64 + lane)) * 8);
        #pragma unroll
        for (int c = 0; c < 8; c++)
            Wn[c] = *(const half8*)(W + ((size_t)((sn * 16 + nh * 8 + c) * 64 + lane)) * 8);
        #pragma unroll
        for (int c = 0; c < 8; c++)
            acc[c] = mfma16(aC, Wc[c], acc[c]);
        aC = aN;
        #pragma unroll
        for (int c = 0; c < 8; c++) Wc[c] = Wn[c];
    }

    float y[8][4];
    float psum[4] = {0,0,0,0}, psq[4] = {0,0,0,0};
    #pragma unroll
    for (int c = 0; c < 8; c++) {
        int n = nh * 128 + c * 16 + ln;
        float bv = bf2[n];
        #pragma unroll
        for (int r = 0; r < 4; r++) {
            int m = mb + quad * 4 + r;
            float v = acc[c][r] + bv + (float)res[(size_t)m * D2_ + n];
            y[c][r] = v; psum[r] += v; psq[r] += v * v;
        }
    }
    #pragma unroll
    for (int off = 1; off < 16; off <<= 1)
        #pragma unroll
        for (int r = 0; r < 4; r++) { psum[r] += __shfl_xor(psum[r], off); psq[r] += __shfl_xor(psq[r], off); }
    if (ln == 0)
        #pragma unroll
        for (int r = 0; r < 4; r++) { sst[rt][quad * 4 + r][nh][0] = psum[r]; sst[rt][quad * 4 + r][nh][1] = psq[r]; }
    __syncthreads();
    #pragma unroll
    for (int r = 0; r < 4; r++) {
        float su = sst[rt][quad * 4 + r][0][0] + sst[rt][quad * 4 + r][1][0];
        float sq = sst[rt][quad * 4 + r][0][1] + sst[rt][quad * 4 + r][1][1];
        float mean = su * (1.f / 256.f);
        float var = sq * (1.f / 256.f) - mean * mean;
        float invs = rsqrtf(var + 1e-5f);
        #pragma unroll
        for (int c = 0; c < 8; c++) {
            int n = nh * 128 + c * 16 + ln;
            float yn = (y[c][r] - mean) * invs * g3[n] + b3[n];
            int s_x = n >> 5, q_x = (n >> 3) & 3, j = n & 7;
            xn2[((size_t)((lt * 8 + s_x) * 64 + q_x * 16 + (quad * 4 + r))) * 8 + j] = (_Float16)yn;
        }
    }
}

// out = xn2 @ Wo + bo [M x 55] fp32. Block: 2 rowtiles x 2 K-halves, LDS combine.
__global__ __launch_bounds__(256) void out_kernel(const _Float16* xn2, const _Float16* wsw,
        const float* bo, float* out) {
    __shared__ f32x4 pc[2][4][64];
    int w = threadIdx.x >> 6, lane = threadIdx.x & 63;
    int quad = lane >> 4, ln = lane & 15;
    int rt = w & 1, kh = w >> 1;
    int mb = blockIdx.x * 32 + rt * 16;
    int lt = mb >> 4;
    const _Float16* W = wsw + WO_OFF;   // K=256, N=64(padded), nc=4

    f32x4 acc[4];
    #pragma unroll
    for (int c = 0; c < 4; c++) acc[c] = f32x4{0,0,0,0};
    #pragma unroll
    for (int ss = 0; ss < 4; ss++) {
        int s = kh * 4 + ss;
        half8 a = *(const half8*)(xn2 + ((size_t)((lt * 8 + s) * 64 + lane)) * 8);
        #pragma unroll
        for (int c = 0; c < 4; c++)
            acc[c] = mfma16(a, *(const half8*)(W + ((size_t)((s * 4 + c) * 64 + lane)) * 8), acc[c]);
    }
    if (kh == 1)
        #pragma unroll
        for (int c = 0; c < 4; c++) pc[rt][c][lane] = acc[c];
    __syncthreads();
    if (kh == 0) {
        #pragma unroll
        for (int c = 0; c < 4; c++) {
            f32x4 p = pc[rt][c][lane];
            int n = c * 16 + ln;
            if (n < OUT_) {
                float bv = bo[n];
                #pragma unroll
                for (int r = 0; r < 4; r++)
                    out[(size_t)(mb + quad * 4 + r) * OUT_ + n] = acc[c][r] + p[r] + bv;
            }
        }
    }
}

extern "C" void kernel_launch(void* const* d_in, const int* in_sizes, int n_in,
                              void* d_out, int out_size, void* d_ws, size_t ws_size,
                              hipStream_t stream) {
    const float* x1    = (const float*)d_in[0];
    const float* x2    = (const float*)d_in[1];
    const float* ln1_g = (const float*)d_in[2];
    const float* ln1_b = (const float*)d_in[3];
    const float* ln2_g = (const float*)d_in[4];
    const float* ln2_b = (const float*)d_in[5];
    const float* Wq    = (const float*)d_in[6];
    const float* bq    = (const float*)d_in[7];
    const float* Wv1   = (const float*)d_in[8];
    const float* bv1   = (const float*)d_in[9];
    const float* Wk    = (const float*)d_in[10];
    const float* bk    = (const float*)d_in[11];
    const float* Wv2   = (const float*)d_in[12];
    const float* bv2   = (const float*)d_in[13];
    const float* Wp1   = (const float*)d_in[14];
    const float* bp1   = (const float*)d_in[15];
    const float* Wp2   = (const float*)d_in[16];
    const float* bp2   = (const float*)d_in[17];
    const float* lnf_g = (const float*)d_in[18];
    const float* lnf_b = (const float*)d_in[19];
    const float* Wf1   = (const float*)d_in[20];
    const float* bf1   = (const float*)d_in[21];
    const float* Wf2   = (const float*)d_in[22];
    const float* bf2   = (const float*)d_in[23];
    const float* ln3_g = (const float*)d_in[24];
    const float* ln3_b = (const float*)d_in[25];
    const float* Wo    = (const float*)d_in[26];
    const float* bo    = (const float*)d_in[27];
    float* out = (float*)d_out;

    char* ws = (char*)d_ws;
    const size_t MB = 1 << 20;
    _Float16* q1sw   = (_Float16*)(ws + 0 * MB);    // 4 MB
    _Float16* k2sw   = (_Float16*)(ws + 4 * MB);    // 4 MB
    unsigned char* vsw8 = (unsigned char*)(ws + 8 * MB);   // 4 MB (fp8 Vcat per batch)
    _Float16* att1   = (_Float16*)(ws + 12 * MB);   // 4 MB
    _Float16* att2   = (_Float16*)(ws + 16 * MB);   // 4 MB
    _Float16* x1n    = (_Float16*)(ws + 20 * MB);   // 4 MB
    _Float16* x2n    = (_Float16*)(ws + 24 * MB);   // 4 MB
    _Float16* wsw    = (_Float16*)(ws + 28 * MB);   // ~0.74 MB
    float*    rowsum = (float*)   (ws + 29 * MB);   // 64 KB
    _Float16* res    = (_Float16*)(ws + 30 * MB);   // 8 MB
    _Float16* xn     = (_Float16*)(ws + 46 * MB);   // 8 MB
    _Float16* h      = (_Float16*)(ws + 54 * MB);   // 16 MB
    _Float16* xn2    = (_Float16*)(ws + 70 * MB);   // 8 MB
    unsigned char* pmat8 = (unsigned char*)(ws + 78 * MB); // 64 MB (fp8 P per batch)

    prep_kernel<<<dim3(512, 9), 256, 0, stream>>>(Wq, Wv1, Wk, Wv2, Wp1, Wp2, Wf1, Wf2, Wo, wsw);
    ln_kernel<<<dim3(M_ / 4, 2), 256, 0, stream>>>(x1, x2, ln1_g, ln1_b, ln2_g, ln2_b, x1n, x2n);
    proj_kernel<<<dim3(M_ / 64, 4), 256, 0, stream>>>(x1n, x2n, wsw, bq, bv1, bk, bv2,
                                                      q1sw, k2sw, vsw8);
    zero_kernel<<<dim3(16), 256, 0, stream>>>(rowsum);
    score_kernel<<<dim3(32, 32, 4), 256, 0, stream>>>(q1sw, k2sw, pmat8, rowsum);
    pv_kernel<<<dim3(M_ / 32), 256, 0, stream>>>(pmat8, vsw8, rowsum, att1, att2);
    attn_out_kernel<<<dim3(M_ / 64), 256, 0, stream>>>(att1, att2, wsw, bp1, bp2,
                                                       x1, x2, lnf_g, lnf_b, res, xn);
    ffn1_kernel<<<dim3(M_ / 64, 4), 256, 0, stream>>>(xn, wsw, bf1, h);
    ffn2_kernel<<<dim3(M_ / 32), 256, 0, stream>>>(h, wsw, bf2, res, ln3_g, ln3_b, xn2);
    out_kernel<<<dim3(M_ / 32), 256, 0, stream>>>(xn2, wsw, bo, out);
}

// Round 10
// 240.752 us; speedup vs baseline: 2.5220x; 1.0367x over previous
//
#include <hip/hip_runtime.h>
#include <hip/hip_fp16.h>

typedef _Float16 half8 __attribute__((ext_vector_type(8)));
typedef float f32x4 __attribute__((ext_vector_type(4)));
typedef long lng2 __attribute__((ext_vector_type(2)));

#define B_   4
#define L_   4096
#define D_   128
#define M_   (B_*L_)     // 16384
#define D2_  256
#define H_   512
#define OUT_ 55

__device__ __forceinline__ f32x4 mfma16(half8 a, half8 b, f32x4 c) {
    return __builtin_amdgcn_mfma_f32_16x16x32_f16(a, b, c, 0, 0, 0);
}
__device__ __forceinline__ f32x4 mfma8(long a, long b, f32x4 c) {
    return __builtin_amdgcn_mfma_f32_16x16x32_fp8_fp8(a, b, c, 0, 0, 0);
}
// pack 4 floats -> 4 fp8 e4m3 bytes (OCP on gfx950)
__device__ __forceinline__ int pk4(float a, float b, float c, float d) {
    int t = __builtin_amdgcn_cvt_pk_fp8_f32(a, b, 0, false);
    return __builtin_amdgcn_cvt_pk_fp8_f32(c, d, t, true);
}
// raw v_exp_f32 — exp2f w/o fast-math lowers to OCML denorm-safe seq (~25cyc, r8 VALUBusy=47%)
__device__ __forceinline__ float fexp2(float x) { return __builtin_amdgcn_exp2f(x); }

// fold softmax scale (1/sqrt(128)) * log2(e) into k2 so score uses bare v_exp
#define KSCL (0.08838834764831845f * 1.4426950408889634f)

// ---- weight swizzle offsets (in halfs) within wsw region ----
#define WQ_OFF   0
#define WV1_OFF  16384
#define WK_OFF   32768
#define WV2_OFF  49152
#define WP1_OFF  65536
#define WP2_OFF  81920
#define WF1_OFF  98304     // 256x512 = 131072
#define WF2_OFF  229376    // 512x256 = 131072
#define WO_OFF   360448    // 256x64 (padded) = 16384

// Permuted k-map (within a 32-k chunk): k5 = (h<4 ? q*4+h : 16+q*4+(h-4)).
// Used for fp8 P & V and fp16 att & Wp1/Wp2 — A/B agree pairwise.

// Pre-swizzle weights (fp32 row-major [K][N]) into B-fragment layout fp16.
// canonical: q=(k>>3)&3, j=k&7 ; permK (Wp1/Wp2 only): q=(k>>2)&3, j=(k&3)+4*((k>>4)&1)
__global__ void prep_kernel(const float* Wq, const float* Wv1, const float* Wk,
                            const float* Wv2, const float* Wp1, const float* Wp2,
                            const float* Wf1, const float* Wf2, const float* Wo,
                            _Float16* wsw) {
    int id = blockIdx.y;
    int t  = blockIdx.x * 256 + threadIdx.x;
    const float* src = nullptr; int K = 0, N = 0, Npad = 0, off = 0;
    switch (id) {
        case 0: src = Wq;  K = 128; N = 128; Npad = 128; off = WQ_OFF;  break;
        case 1: src = Wv1; K = 128; N = 128; Npad = 128; off = WV1_OFF; break;
        case 2: src = Wk;  K = 128; N = 128; Npad = 128; off = WK_OFF;  break;
        case 3: src = Wv2; K = 128; N = 128; Npad = 128; off = WV2_OFF; break;
        case 4: src = Wp1; K = 128; N = 128; Npad = 128; off = WP1_OFF; break;
        case 5: src = Wp2; K = 128; N = 128; Npad = 128; off = WP2_OFF; break;
        case 6: src = Wf1; K = 256; N = 512; Npad = 512; off = WF1_OFF; break;
        case 7: src = Wf2; K = 512; N = 256; Npad = 256; off = WF2_OFF; break;
        case 8: src = Wo;  K = 256; N = 55;  Npad = 64;  off = WO_OFF;  break;
        default: return;
    }
    int total = K * Npad;
    if (t >= total) return;
    int k = t / Npad, n = t % Npad;
    float v = (n < N) ? src[k * N + n] : 0.f;
    int s = k >> 5, c = n >> 4, ln = n & 15;
    int q, j;
    if (id == 4 || id == 5) { q = (k >> 2) & 3; j = (k & 3) + (((k >> 4) & 1) << 2); }
    else                    { q = (k >> 3) & 3; j = k & 7; }
    int nc = Npad >> 4;
    wsw[off + ((size_t)((s * nc + c) * 64 + q * 16 + ln)) * 8 + j] = (_Float16)v;
}

// FR layout for X[M][C] halfs:
// idx = ((lt*(C/32) + s)*64 + q*16 + ln_r)*8 + j ; lt=row>>4, ln_r=row&15,
// s=col>>5, q=(col>>3)&3, j=col&7.

// LayerNorm over D=128, one wave per token, fp32 in -> fp16 FR-swizzled out
__global__ __launch_bounds__(256) void ln_kernel(const float* x1, const float* x2,
        const float* g1, const float* b1, const float* g2, const float* b2,
        _Float16* x1n, _Float16* x2n) {
    int wave = threadIdx.x >> 6, lane = threadIdx.x & 63;
    int token = blockIdx.x * 4 + wave;
    const float* x = blockIdx.y ? x2 : x1;
    const float* g = blockIdx.y ? g2 : g1;
    const float* bb = blockIdx.y ? b2 : b1;
    _Float16* o = blockIdx.y ? x2n : x1n;
    const float* xr = x + (size_t)token * D_;
    float a0 = xr[lane], a1 = xr[lane + 64];
    float s = a0 + a1, s2 = a0 * a0 + a1 * a1;
    #pragma unroll
    for (int off = 1; off < 64; off <<= 1) {
        s += __shfl_xor(s, off);
        s2 += __shfl_xor(s2, off);
    }
    float mean = s * (1.f / 128.f);
    float var = s2 * (1.f / 128.f) - mean * mean;
    float inv = rsqrtf(var + 1e-5f);
    int lt = token >> 4, ln_r = token & 15;
    #pragma unroll
    for (int h = 0; h < 2; h++) {
        int col = lane + h * 64;
        float v = (h ? a1 : a0);
        float out = (v - mean) * inv * g[col] + bb[col];
        int ss = col >> 5, q = (col >> 3) & 3, j = col & 7;
        o[((size_t)((lt * 4 + ss) * 64 + q * 16 + ln_r)) * 8 + j] = (_Float16)out;
    }
}

// Projections. q1 fp16 FR; k2 fp16 FR pre-scaled by KSCL; v1/v2 -> vsw8 fp8
// permuted-k B-frag layout. W-frag register prefetch pipeline over c.
__global__ __launch_bounds__(256) void proj_kernel(const _Float16* x1n, const _Float16* x2n,
        const _Float16* wsw, const float* bq, const float* bv1, const float* bk,
        const float* bv2, _Float16* q1, _Float16* k2, unsigned char* vsw8) {
    int g = blockIdx.y;   // 0:Wq 1:Wv1 2:Wk 3:Wv2
    const _Float16* A = (g < 2) ? x1n : x2n;
    const _Float16* Bw = wsw + g * 16384;
    const float* bias = (g == 0) ? bq : (g == 1) ? bv1 : (g == 2) ? bk : bv2;
    int wave = threadIdx.x >> 6, lane = threadIdx.x & 63;
    int quad = lane >> 4, ln = lane & 15;
    int mbase = blockIdx.x * 64 + wave * 16;
    int lt = mbase >> 4;

    half8 a[4];
    #pragma unroll
    for (int s = 0; s < 4; s++)
        a[s] = *(const half8*)(A + ((size_t)((lt * 4 + s) * 64 + lane)) * 8);

    f32x4 acc[8];
    #pragma unroll
    for (int c = 0; c < 8; c++) acc[c] = f32x4{0.f, 0.f, 0.f, 0.f};

    half8 Wc[4], Wn[4];
    #pragma unroll
    for (int s = 0; s < 4; s++)
        Wc[s] = *(const half8*)(Bw + ((size_t)((s * 8 + 0) * 64 + lane)) * 8);
    #pragma unroll
    for (int c = 0; c < 8; c++) {
        int cn = (c < 7) ? c + 1 : 7;
        #pragma unroll
        for (int s = 0; s < 4; s++)
            Wn[s] = *(const half8*)(Bw + ((size_t)((s * 8 + cn) * 64 + lane)) * 8);
        #pragma unroll
        for (int s = 0; s < 4; s++)
            acc[c] = mfma16(a[s], Wc[s], acc[c]);
        #pragma unroll
        for (int s = 0; s < 4; s++) Wc[s] = Wn[s];
    }

    bool isV = (g == 1) || (g == 3);
    if (!isV) {
        float scl = (g == 2) ? KSCL : 1.f;
        _Float16* out = (g == 0) ? q1 : k2;
        #pragma unroll
        for (int c = 0; c < 8; c++) {
            int n = c * 16 + ln;
            float bv = bias[n];
            #pragma unroll
            for (int r = 0; r < 4; r++) {
                int s_o = c >> 1, q_o = ((c & 1) << 1) | (ln >> 3), j = ln & 7;
                out[((size_t)((lt * 4 + s_o) * 64 + q_o * 16 + (quad * 4 + r))) * 8 + j]
                    = (_Float16)((acc[c][r] + bv) * scl);
            }
        }
    } else {
        int cbase = (g == 3) ? 8 : 0;
        int b = mbase >> 12;
        int l0 = (mbase & (L_ - 1)) + quad * 4;
        int sp = l0 >> 6, tt = (l0 >> 4) & 3, q2 = (l0 >> 2) & 3;
        unsigned char* Vb = vsw8 + (size_t)b * (1u << 20);
        #pragma unroll
        for (int c = 0; c < 8; c++) {
            int n = c * 16 + ln;
            float bv = bias[n];
            int pk = pk4(acc[c][0] + bv, acc[c][1] + bv, acc[c][2] + bv, acc[c][3] + bv);
            *(int*)(Vb + (((size_t)(sp * 16 + cbase + c) * 64 + q2 * 16 + ln) * 16 + tt * 4)) = pk;
        }
    }
}

__global__ __launch_bounds__(256) void zero_kernel(float* rowsum) {
    int i = (blockIdx.x * 256 + threadIdx.x) * 4;
    *(f32x4*)(rowsum + i) = f32x4{0.f, 0.f, 0.f, 0.f};
}

// Pass 1: S^T tiles (A=q1 rows = softmax k-dim, B=k2^T cols = att rows).
// p = exp2(acc) via raw v_exp_f32; pk4 over r -> permuted-k fp8 A-entries.
__global__ __launch_bounds__(256) void score_kernel(
        const _Float16* __restrict__ q1sw, const _Float16* __restrict__ k2sw,
        unsigned char* __restrict__ pmat8, float* __restrict__ rowsum) {
    int w = threadIdx.x >> 6, lane = threadIdx.x & 63;
    int quad = lane >> 4, ln = lane & 15;
    int b = blockIdx.z;
    int kL0 = blockIdx.y * 128 + (w & 1) * 64;     // q1 rows (contraction dim of PV)
    int mL0 = blockIdx.x * 128 + (w >> 1) * 64;    // k2 rows (att rows)
    int ltk = ((b << 12) + kL0) >> 4;
    int ltm = ((b << 12) + mL0) >> 4;

    f32x4 acc[4][4];
    #pragma unroll
    for (int i = 0; i < 4; i++)
        #pragma unroll
        for (int j = 0; j < 4; j++) acc[i][j] = f32x4{0.f, 0.f, 0.f, 0.f};

    #pragma unroll
    for (int s = 0; s < 4; s++) {
        half8 a[4], bq[4];
        #pragma unroll
        for (int i = 0; i < 4; i++)
            a[i] = *(const half8*)(q1sw + ((size_t)(((ltk + i) * 4 + s) * 64 + lane)) * 8);
        #pragma unroll
        for (int j = 0; j < 4; j++)
            bq[j] = *(const half8*)(k2sw + ((size_t)(((ltm + j) * 4 + s) * 64 + lane)) * 8);
        #pragma unroll
        for (int i = 0; i < 4; i++)
            #pragma unroll
            for (int j = 0; j < 4; j++)
                acc[i][j] = mfma16(a[i], bq[j], acc[i][j]);
    }

    unsigned char* Pb = pmat8 + (size_t)b * (16u << 20);
    int sp = kL0 >> 6;
    #pragma unroll
    for (int j = 0; j < 4; j++) {
        int4 d;
        float csum = 0.f;
        #pragma unroll
        for (int i = 0; i < 4; i++) {
            float p0 = fexp2(acc[i][j][0]);
            float p1 = fexp2(acc[i][j][1]);
            float p2 = fexp2(acc[i][j][2]);
            float p3 = fexp2(acc[i][j][3]);
            csum += (p0 + p1) + (p2 + p3);
            ((int*)&d)[i] = pk4(p0, p1, p2, p3);
        }
        csum += __shfl_xor(csum, 16);
        csum += __shfl_xor(csum, 32);
        if (lane < 16)
            atomicAdd(&rowsum[(b << 12) + mL0 + j * 16 + ln], csum);
        int lt = (mL0 >> 4) + j;
        *(int4*)(Pb + (((size_t)(lt * 64 + sp)) * 64 + lane) * 16) = d;
    }
}

// Pass 2: O^T = V^T . P^T (operand swap). 512-thread blocks, 8 waves:
// wave (wc, kh) = (n-quarter, k-half). In-block k-split doubles wave supply
// to 4/SIMD (r9: grid-limited at 2/SIMD, MfmaUtil 30%). fp32 partials merged
// in LDS. att-row lands on lane axis = attn_out's A-frag orientation.
__global__ __launch_bounds__(512) void pv_kernel(
        const unsigned char* __restrict__ pmat8, const unsigned char* __restrict__ vsw8,
        const float* __restrict__ rowsum,
        _Float16* __restrict__ att1, _Float16* __restrict__ att2) {
    __shared__ f32x4 part[4][2][4][64];   // 32 KB: [wc][m c][n i][lane]
    int w = threadIdx.x >> 6, lane = threadIdx.x & 63;
    int quad = lane >> 4, ln = lane & 15;
    int wc = w & 3, kh = w >> 2;
    int rowG0 = blockIdx.x * 32;
    int b = rowG0 >> 12;
    int lt0 = (rowG0 & (L_ - 1)) >> 4;   // 2 m-tiles
    const unsigned char* Pb = pmat8 + (size_t)b * (16u << 20);
    const unsigned char* Vb = vsw8 + (size_t)b * (1u << 20);
    int c0 = wc * 4;
    int sp0 = kh * 32;

    f32x4 acc[4][2];
    #pragma unroll
    for (int i = 0; i < 4; i++)
        #pragma unroll
        for (int c = 0; c < 2; c++) acc[i][c] = f32x4{0.f, 0.f, 0.f, 0.f};

    lng2 Vf[2][4], Pf[2][2];
    #pragma unroll
    for (int p = 0; p < 2; p++) {
        #pragma unroll
        for (int i = 0; i < 4; i++)
            Vf[p][i] = *(const lng2*)(Vb + (((size_t)((sp0 + p) * 16 + c0 + i)) * 64 + lane) * 16);
        #pragma unroll
        for (int c = 0; c < 2; c++)
            Pf[p][c] = *(const lng2*)(Pb + (((size_t)((lt0 + c) * 64 + sp0 + p)) * 64 + lane) * 16);
    }

    #define PVSTEP(buf, ii) do {                                                     \
        int spn = sp0 + ((((ii) + 2) < 32) ? (ii) + 2 : 31);                         \
        lng2 Vn[4], Pn[2];                                                           \
        _Pragma("unroll")                                                            \
        for (int i = 0; i < 4; i++)                                                  \
            Vn[i] = *(const lng2*)(Vb + (((size_t)(spn * 16 + c0 + i)) * 64 + lane) * 16); \
        _Pragma("unroll")                                                            \
        for (int c = 0; c < 2; c++)                                                  \
            Pn[c] = *(const lng2*)(Pb + (((size_t)((lt0 + c) * 64 + spn)) * 64 + lane) * 16); \
        _Pragma("unroll")                                                            \
        for (int i = 0; i < 4; i++)                                                  \
            _Pragma("unroll")                                                        \
            for (int c = 0; c < 2; c++) {                                            \
                acc[i][c] = mfma8(Vf[buf][i].x, Pf[buf][c].x, acc[i][c]);             \
                acc[i][c] = mfma8(Vf[buf][i].y, Pf[buf][c].y, acc[i][c]);             \
            }                                                                        \
        _Pragma("unroll")                                                            \
        for (int i = 0; i < 4; i++) Vf[buf][i] = Vn[i];                              \
        _Pragma("unroll")                                                            \
        for (int c = 0; c < 2; c++) Pf[buf][c] = Pn[c];                              \
    } while (0)

    for (int ii = 0; ii < 32; ii += 2) {
        PVSTEP(0, ii);
        PVSTEP(1, ii + 1);
    }
    #undef PVSTEP

    if (kh == 1) {
        #pragma unroll
        for (int i = 0; i < 4; i++)
            #pragma unroll
            for (int c = 0; c < 2; c++)
                part[wc][c][i][lane] = acc[i][c];
    }
    __syncthreads();
    if (kh == 0) {
        #pragma unroll
        for (int i = 0; i < 4; i++)
            #pragma unroll
            for (int c = 0; c < 2; c++)
                acc[i][c] += part[wc][c][i][lane];

        _Float16* att = (wc >= 2) ? att2 : att1;
        #pragma unroll
        for (int c = 0; c < 2; c++) {
            float inv = 1.f / rowsum[rowG0 + c * 16 + ln];
            int lt = (rowG0 >> 4) + c;
            #pragma unroll
            for (int sl = 0; sl < 2; sl++) {
                half8 v;
                #pragma unroll
                for (int r = 0; r < 4; r++) {
                    v[r]     = (_Float16)(acc[2 * sl][c][r] * inv);
                    v[r + 4] = (_Float16)(acc[2 * sl + 1][c][r] * inv);
                }
                int s = (wc & 1) * 2 + sl;
                *(half8*)(att + ((size_t)((lt * 4 + s) * 64 + lane)) * 8) = v;
            }
        }
    }
}

// out_s = att_s @ Wp_s + bias + residual ; concat -> res (fp16) ; LNf -> xn (FR fp16)
// 512 blocks x (2 rowtiles x 2 streams): 2 waves/SIMD (was 256 blocks = 1/SIMD).
__global__ __launch_bounds__(256) void attn_out_kernel(const _Float16* att1, const _Float16* att2,
        const _Float16* wsw, const float* bp1, const float* bp2,
        const float* x1, const float* x2, const float* lnf_g, const float* lnf_b,
        _Float16* res, _Float16* xn) {
    __shared__ float sst[2][16][2][2];
    int w = threadIdx.x >> 6, lane = threadIdx.x & 63;
    int quad = lane >> 4, ln = lane & 15;
    int rt = w & 1, st = w >> 1;
    int mbase = blockIdx.x * 32 + rt * 16;
    int lt = mbase >> 4;
    const _Float16* att = st ? att2 : att1;
    const _Float16* Wp = wsw + (st ? WP2_OFF : WP1_OFF);
    const float* bp = st ? bp2 : bp1;
    const float* xres = st ? x2 : x1;

    half8 a[4];
    #pragma unroll
    for (int s = 0; s < 4; s++)
        a[s] = *(const half8*)(att + ((size_t)((lt * 4 + s) * 64 + lane)) * 8);

    f32x4 y[8];
    #pragma unroll
    for (int c = 0; c < 8; c++) y[c] = f32x4{0,0,0,0};

    half8 Wc[4], Wn[4];
    #pragma unroll
    for (int s = 0; s < 4; s++)
        Wc[s] = *(const half8*)(Wp + ((size_t)((s * 8 + 0) * 64 + lane)) * 8);
    #pragma unroll
    for (int c = 0; c < 8; c++) {
        int cn = (c < 7) ? c + 1 : 7;
        #pragma unroll
        for (int s = 0; s < 4; s++)
            Wn[s] = *(const half8*)(Wp + ((size_t)((s * 8 + cn) * 64 + lane)) * 8);
        #pragma unroll
        for (int s = 0; s < 4; s++)
            y[c] = mfma16(a[s], Wc[s], y[c]);
        #pragma unroll
        for (int s = 0; s < 4; s++) Wc[s] = Wn[s];
    }

    float psum[4] = {0,0,0,0}, psq[4] = {0,0,0,0};
    #pragma unroll
    for (int c = 0; c < 8; c++) {
        int n = c * 16 + ln;
        float bv = bp[n];
        #pragma unroll
        for (int r = 0; r < 4; r++) {
            int m = mbase + quad * 4 + r;
            float v = y[c][r] + bv + xres[(size_t)m * D_ + n];
            y[c][r] = v; psum[r] += v; psq[r] += v * v;
        }
    }
    #pragma unroll
    for (int off = 1; off < 16; off <<= 1)
        #pragma unroll
        for (int r = 0; r < 4; r++) { psum[r] += __shfl_xor(psum[r], off); psq[r] += __shfl_xor(psq[r], off); }
    if (ln == 0)
        #pragma unroll
        for (int r = 0; r < 4; r++) {
            sst[rt][quad * 4 + r][st][0] = psum[r];
            sst[rt][quad * 4 + r][st][1] = psq[r];
        }
    __syncthreads();
    #pragma unroll
    for (int r = 0; r < 4; r++) {
        float su = sst[rt][quad * 4 + r][0][0] + sst[rt][quad * 4 + r][1][0];
        float sq = sst[rt][quad * 4 + r][0][1] + sst[rt][quad * 4 + r][1][1];
        float mean = su * (1.f / 256.f);
        float var = sq * (1.f / 256.f) - mean * mean;
        float inv = rsqrtf(var + 1e-5f);
        int m = mbase + quad * 4 + r;
        int lt_m = m >> 4;
        #pragma unroll
        for (int c = 0; c < 8; c++) {
            int colg = st * 128 + c * 16 + ln;
            res[(size_t)m * D2_ + colg] = (_Float16)y[c][r];
            float yn = (y[c][r] - mean) * inv * lnf_g[colg] + lnf_b[colg];
            int s_x = colg >> 5, q_x = (colg >> 3) & 3, j = colg & 7;
            xn[((size_t)((lt_m * 8 + s_x) * 64 + q_x * 16 + (m & 15))) * 8 + j] = (_Float16)yn;
        }
    }
}

// h = gelu(xn @ Wf1 + bf1)  [M x 512], FR in/out. W-prefetch pipeline; fast
// tanh-form GELU (x*sigmoid(2u)) via raw v_exp.
__global__ __launch_bounds__(256) void ffn1_kernel(const _Float16* xn, const _Float16* wsw,
        const float* bf1, _Float16* h) {
    int wave = threadIdx.x >> 6, lane = threadIdx.x & 63;
    int quad = lane >> 4, ln = lane & 15;
    int mbase = blockIdx.x * 64 + wave * 16;
    int lt = mbase >> 4;
    int nt = blockIdx.y;   // 0..3
    const _Float16* W = wsw + WF1_OFF;   // K=256, N=512, nc=32

    half8 a[8];
    #pragma unroll
    for (int s = 0; s < 8; s++)
        a[s] = *(const half8*)(xn + ((size_t)((lt * 8 + s) * 64 + lane)) * 8);

    f32x4 acc[8];
    #pragma unroll
    for (int c = 0; c < 8; c++) acc[c] = f32x4{0,0,0,0};

    half8 Wc[8], Wn[8];
    #pragma unroll
    for (int s = 0; s < 8; s++)
        Wc[s] = *(const half8*)(W + ((size_t)((s * 32 + nt * 8) * 64 + lane)) * 8);
    #pragma unroll
    for (int c = 0; c < 8; c++) {
        int cn = (c < 7) ? c + 1 : 7;
        #pragma unroll
        for (int s = 0; s < 8; s++)
            Wn[s] = *(const half8*)(W + ((size_t)((s * 32 + nt * 8 + cn) * 64 + lane)) * 8);
        #pragma unroll
        for (int s = 0; s < 8; s++)
            acc[c] = mfma16(a[s], Wc[s], acc[c]);
        #pragma unroll
        for (int s = 0; s < 8; s++) Wc[s] = Wn[s];
    }
    #pragma unroll
    for (int c = 0; c < 8; c++) {
        int n = nt * 128 + c * 16 + ln;
        float bv = bf1[n];
        int s_h = n >> 5, q_h = (n >> 3) & 3, j = n & 7;
        #pragma unroll
        for (int r = 0; r < 4; r++) {
            float v = acc[c][r] + bv;
            float u = 0.7978845608f * (v + 0.044715f * v * v * v);
            float e = fexp2(-2.8853900818f * u);     // 2*log2(e)*u
            float ge = v * __builtin_amdgcn_rcpf(1.f + e);
            h[((size_t)((lt * 16 + s_h) * 64 + q_h * 16 + (quad * 4 + r))) * 8 + j] = (_Float16)ge;
        }
    }
}

// x = LN3(h @ Wf2 + bf2 + res) -> xn2 (FR fp16). Software-pipelined K-loop.
__global__ __launch_bounds__(256) void ffn2_kernel(const _Float16* h, const _Float16* wsw,
        const float* bf2, const _Float16* res, const float* g3, const float* b3, _Float16* xn2) {
    __shared__ float sst[2][16][2][2];
    int w = threadIdx.x >> 6, lane = threadIdx.x & 63;
    int quad = lane >> 4, ln = lane & 15;
    int rt = w & 1, nh = w >> 1;
    int mb = blockIdx.x * 32 + rt * 16;
    int lt = mb >> 4;
    const _Float16* W = wsw + WF2_OFF;   // K=512, N=256, nc=16

    f32x4 acc[8];
    #pragma unroll
    for (int c = 0; c < 8; c++) acc[c] = f32x4{0,0,0,0};

    half8 aC, aN;
    half8 Wc[8], Wn[8];
    aC = *(const half8*)(h + ((size_t)((lt * 16 + 0) * 64 + lane)) * 8);
    #pragma unroll
    for (int c = 0; c < 8; c++)
        Wc[c] = *(const half8*)(W + ((size_t)((0 * 16 + nh * 8 + c) * 64 + lane)) * 8);

    #pragma unroll
    for (int s = 0; s < 16; s++) {
        int sn = (s < 15) ? s + 1 : 15;
        aN = *(const half8*)(h + ((size_t)((lt * 16 + sn) * 64 + lane)) * 8);
        #pragma unroll
        for (int c = 0; c < 8; c++)
            Wn[c] = *(const half8*)(W + ((size_t)((sn * 16 + nh * 8 + c) * 64 + lane)) * 8);
        #pragma unroll
        for (int c = 0; c < 8; c++)
            acc[c] = mfma16(aC, Wc[c], acc[c]);
        aC = aN;
        #pragma unroll
        for (int c = 0; c < 8; c++) Wc[c] = Wn[c];
    }

    float y[8][4];
    float psum[4] = {0,0,0,0}, psq[4] = {0,0,0,0};
    #pragma unroll
    for (int c = 0; c < 8; c++) {
        int n = nh * 128 + c * 16 + ln;
        float bv = bf2[n];
        #pragma unroll
        for (int r = 0; r < 4; r++) {
            int m = mb + quad * 4 + r;
            float v = acc[c][r] + bv + (float)res[(size_t)m * D2_ + n];
            y[c][r] = v; psum[r] += v; psq[r] += v * v;
        }
    }
    #pragma unroll
    for (int off = 1; off < 16; off <<= 1)
        #pragma unroll
        for (int r = 0; r < 4; r++) { psum[r] += __shfl_xor(psum[r], off); psq[r] += __shfl_xor(psq[r], off); }
    if (ln == 0)
        #pragma unroll
        for (int r = 0; r < 4; r++) { sst[rt][quad * 4 + r][nh][0] = psum[r]; sst[rt][quad * 4 + r][nh][1] = psq[r]; }
    __syncthreads();
    #pragma unroll
    for (int r = 0; r < 4; r++) {
        float su = sst[rt][quad * 4 + r][0][0] + sst[rt][quad * 4 + r][1][0];
        float sq = sst[rt][quad * 4 + r][0][1] + sst[rt][quad * 4 + r][1][1];
        float mean = su * (1.f / 256.f);
        float var = sq * (1.f / 256.f) - mean * mean;
        float invs = rsqrtf(var + 1e-5f);
        #pragma unroll
        for (int c = 0; c < 8; c++) {
            int n = nh * 128 + c * 16 + ln;
            float yn = (y[c][r] - mean) * invs * g3[n] + b3[n];
            int s_x = n >> 5, q_x = (n >> 3) & 3, j = n & 7;
            xn2[((size_t)((lt * 8 + s_x) * 64 + q_x * 16 + (quad * 4 + r))) * 8 + j] = (_Float16)yn;
        }
    }
}

// out = xn2 @ Wo + bo [M x 55] fp32. Block: 2 rowtiles x 2 K-halves, LDS combine.
__global__ __launch_bounds__(256) void out_kernel(const _Float16* xn2, const _Float16* wsw,
        const float* bo, float* out) {
    __shared__ f32x4 pc[2][4][64];
    int w = threadIdx.x >> 6, lane = threadIdx.x & 63;
    int quad = lane >> 4, ln = lane & 15;
    int rt = w & 1, kh = w >> 1;
    int mb = blockIdx.x * 32 + rt * 16;
    int lt = mb >> 4;
    const _Float16* W = wsw + WO_OFF;   // K=256, N=64(padded), nc=4

    f32x4 acc[4];
    #pragma unroll
    for (int c = 0; c < 4; c++) acc[c] = f32x4{0,0,0,0};
    #pragma unroll
    for (int ss = 0; ss < 4; ss++) {
        int s = kh * 4 + ss;
        half8 a = *(const half8*)(xn2 + ((size_t)((lt * 8 + s) * 64 + lane)) * 8);
        #pragma unroll
        for (int c = 0; c < 4; c++)
            acc[c] = mfma16(a, *(const half8*)(W + ((size_t)((s * 4 + c) * 64 + lane)) * 8), acc[c]);
    }
    if (kh == 1)
        #pragma unroll
        for (int c = 0; c < 4; c++) pc[rt][c][lane] = acc[c];
    __syncthreads();
    if (kh == 0) {
        #pragma unroll
        for (int c = 0; c < 4; c++) {
            f32x4 p = pc[rt][c][lane];
            int n = c * 16 + ln;
            if (n < OUT_) {
                float bv = bo[n];
                #pragma unroll
                for (int r = 0; r < 4; r++)
                    out[(size_t)(mb + quad * 4 + r) * OUT_ + n] = acc[c][r] + p[r] + bv;
            }
        }
    }
}

extern "C" void kernel_launch(void* const* d_in, const int* in_sizes, int n_in,
                              void* d_out, int out_size, void* d_ws, size_t ws_size,
                              hipStream_t stream) {
    const float* x1    = (const float*)d_in[0];
    const float* x2    = (const float*)d_in[1];
    const float* ln1_g = (const float*)d_in[2];
    const float* ln1_b = (const float*)d_in[3];
    const float* ln2_g = (const float*)d_in[4];
    const float* ln2_b = (const float*)d_in[5];
    const float* Wq    = (const float*)d_in[6];
    const float* bq    = (const float*)d_in[7];
    const float* Wv1   = (const float*)d_in[8];
    const float* bv1   = (const float*)d_in[9];
    const float* Wk    = (const float*)d_in[10];
    const float* bk    = (const float*)d_in[11];
    const float* Wv2   = (const float*)d_in[12];
    const float* bv2   = (const float*)d_in[13];
    const float* Wp1   = (const float*)d_in[14];
    const float* bp1   = (const float*)d_in[15];
    const float* Wp2   = (const float*)d_in[16];
    const float* bp2   = (const float*)d_in[17];
    const float* lnf_g = (const float*)d_in[18];
    const float* lnf_b = (const float*)d_in[19];
    const float* Wf1   = (const float*)d_in[20];
    const float* bf1   = (const float*)d_in[21];
    const float* Wf2   = (const float*)d_in[22];
    const float* bf2   = (const float*)d_in[23];
    const float* ln3_g = (const float*)d_in[24];
    const float* ln3_b = (const float*)d_in[25];
    const float* Wo    = (const float*)d_in[26];
    const float* bo    = (const float*)d_in[27];
    float* out = (float*)d_out;

    char* ws = (char*)d_ws;
    const size_t MB = 1 << 20;
    _Float16* q1sw   = (_Float16*)(ws + 0 * MB);    // 4 MB
    _Float16* k2sw   = (_Float16*)(ws + 4 * MB);    // 4 MB
    unsigned char* vsw8 = (unsigned char*)(ws + 8 * MB);   // 4 MB (fp8 Vcat per batch)
    _Float16* att1   = (_Float16*)(ws + 12 * MB);   // 4 MB
    _Float16* att2   = (_Float16*)(ws + 16 * MB);   // 4 MB
    _Float16* x1n    = (_Float16*)(ws + 20 * MB);   // 4 MB
    _Float16* x2n    = (_Float16*)(ws + 24 * MB);   // 4 MB
    _Float16* wsw    = (_Float16*)(ws + 28 * MB);   // ~0.74 MB
    float*    rowsum = (float*)   (ws + 29 * MB);   // 64 KB
    _Float16* res    = (_Float16*)(ws + 30 * MB);   // 8 MB
    _Float16* xn     = (_Float16*)(ws + 46 * MB);   // 8 MB
    _Float16* h      = (_Float16*)(ws + 54 * MB);   // 16 MB
    _Float16* xn2    = (_Float16*)(ws + 70 * MB);   // 8 MB
    unsigned char* pmat8 = (unsigned char*)(ws + 78 * MB); // 64 MB (fp8 P per batch)

    prep_kernel<<<dim3(512, 9), 256, 0, stream>>>(Wq, Wv1, Wk, Wv2, Wp1, Wp2, Wf1, Wf2, Wo, wsw);
    ln_kernel<<<dim3(M_ / 4, 2), 256, 0, stream>>>(x1, x2, ln1_g, ln1_b, ln2_g, ln2_b, x1n, x2n);
    proj_kernel<<<dim3(M_ / 64, 4), 256, 0, stream>>>(x1n, x2n, wsw, bq, bv1, bk, bv2,
                                                      q1sw, k2sw, vsw8);
    zero_kernel<<<dim3(16), 256, 0, stream>>>(rowsum);
    score_kernel<<<dim3(32, 32, 4), 256, 0, stream>>>(q1sw, k2sw, pmat8, rowsum);
    pv_kernel<<<dim3(M_ / 32), 512, 0, stream>>>(pmat8, vsw8, rowsum, att1, att2);
    attn_out_kernel<<<dim3(M_ / 32), 256, 0, stream>>>(att1, att2, wsw, bp1, bp2,
                                                       x1, x2, lnf_g, lnf_b, res, xn);
    ffn1_kernel<<<dim3(M_ / 64, 4), 256, 0, stream>>>(xn, wsw, bf1, h);
    ffn2_kernel<<<dim3(M_ / 32), 256, 0, stream>>>(h, wsw, bf2, res, ln3_g, ln3_b, xn2);
    out_kernel<<<dim3(M_ / 32), 256, 0, stream>>>(xn2, wsw, bo, out);
}

// Round 12
// 239.119 us; speedup vs baseline: 2.5392x; 1.0068x over previous
//
#include <hip/hip_runtime.h>
#include <hip/hip_fp16.h>

typedef _Float16 half8 __attribute__((ext_vector_type(8)));
typedef float f32x4 __attribute__((ext_vector_type(4)));
typedef long lng2 __attribute__((ext_vector_type(2)));

#define B_   4
#define L_   4096
#define D_   128
#define M_   (B_*L_)     // 16384
#define D2_  256
#define H_   512
#define OUT_ 55

__device__ __forceinline__ f32x4 mfma16(half8 a, half8 b, f32x4 c) {
    return __builtin_amdgcn_mfma_f32_16x16x32_f16(a, b, c, 0, 0, 0);
}
__device__ __forceinline__ f32x4 mfma8(long a, long b, f32x4 c) {
    return __builtin_amdgcn_mfma_f32_16x16x32_fp8_fp8(a, b, c, 0, 0, 0);
}
// pack 4 floats -> 4 fp8 e4m3 bytes (OCP on gfx950)
__device__ __forceinline__ int pk4(float a, float b, float c, float d) {
    int t = __builtin_amdgcn_cvt_pk_fp8_f32(a, b, 0, false);
    return __builtin_amdgcn_cvt_pk_fp8_f32(c, d, t, true);
}
// raw v_exp_f32 — exp2f w/o fast-math lowers to OCML denorm-safe seq (~25cyc, r8 VALUBusy=47%)
__device__ __forceinline__ float fexp2(float x) { return __builtin_amdgcn_exp2f(x); }

// fold softmax scale (1/sqrt(128)) * log2(e) into k2 so score uses bare v_exp
#define KSCL (0.08838834764831845f * 1.4426950408889634f)

// ---- weight swizzle offsets (in halfs) within wsw region ----
#define WQ_OFF   0
#define WV1_OFF  16384
#define WK_OFF   32768
#define WV2_OFF  49152
#define WP1_OFF  65536
#define WP2_OFF  81920
#define WF1_OFF  98304     // 256x512 = 131072
#define WF2_OFF  229376    // 512x256 = 131072
#define WO_OFF   360448    // 256x64 (padded) = 16384

// Permuted k-map (within a 32-k chunk): k5 = (h<4 ? q*4+h : 16+q*4+(h-4)).
// Used for fp8 P & V and fp16 att & Wp1/Wp2 — A/B agree pairwise.

// Pre-swizzle weights (fp32 row-major [K][N]) into B-fragment layout fp16.
// canonical: q=(k>>3)&3, j=k&7 ; permK (Wp1/Wp2 only): q=(k>>2)&3, j=(k&3)+4*((k>>4)&1)
// id==9: zero the rowsum buffer (absorbed zero_kernel — one less launch).
__global__ void prep_kernel(const float* Wq, const float* Wv1, const float* Wk,
                            const float* Wv2, const float* Wp1, const float* Wp2,
                            const float* Wf1, const float* Wf2, const float* Wo,
                            _Float16* wsw, float* rowsum) {
    int id = blockIdx.y;
    int t  = blockIdx.x * 256 + threadIdx.x;
    if (id == 9) {
        if (t < 4096) ((f32x4*)rowsum)[t] = f32x4{0.f, 0.f, 0.f, 0.f};
        return;
    }
    const float* src = nullptr; int K = 0, N = 0, Npad = 0, off = 0;
    switch (id) {
        case 0: src = Wq;  K = 128; N = 128; Npad = 128; off = WQ_OFF;  break;
        case 1: src = Wv1; K = 128; N = 128; Npad = 128; off = WV1_OFF; break;
        case 2: src = Wk;  K = 128; N = 128; Npad = 128; off = WK_OFF;  break;
        case 3: src = Wv2; K = 128; N = 128; Npad = 128; off = WV2_OFF; break;
        case 4: src = Wp1; K = 128; N = 128; Npad = 128; off = WP1_OFF; break;
        case 5: src = Wp2; K = 128; N = 128; Npad = 128; off = WP2_OFF; break;
        case 6: src = Wf1; K = 256; N = 512; Npad = 512; off = WF1_OFF; break;
        case 7: src = Wf2; K = 512; N = 256; Npad = 256; off = WF2_OFF; break;
        case 8: src = Wo;  K = 256; N = 55;  Npad = 64;  off = WO_OFF;  break;
        default: return;
    }
    int total = K * Npad;
    if (t >= total) return;
    int k = t / Npad, n = t % Npad;
    float v = (n < N) ? src[k * N + n] : 0.f;
    int s = k >> 5, c = n >> 4, ln = n & 15;
    int q, j;
    if (id == 4 || id == 5) { q = (k >> 2) & 3; j = (k & 3) + (((k >> 4) & 1) << 2); }
    else                    { q = (k >> 3) & 3; j = k & 7; }
    int nc = Npad >> 4;
    wsw[off + ((size_t)((s * nc + c) * 64 + q * 16 + ln)) * 8 + j] = (_Float16)v;
}

// FR layout for X[M][C] halfs:
// idx = ((lt*(C/32) + s)*64 + q*16 + ln_r)*8 + j ; lt=row>>4, ln_r=row&15,
// s=col>>5, q=(col>>3)&3, j=col&7.

// LayerNorm over D=128, one wave per token, fp32 in -> fp16 FR-swizzled out
__global__ __launch_bounds__(256) void ln_kernel(const float* x1, const float* x2,
        const float* g1, const float* b1, const float* g2, const float* b2,
        _Float16* x1n, _Float16* x2n) {
    int wave = threadIdx.x >> 6, lane = threadIdx.x & 63;
    int token = blockIdx.x * 4 + wave;
    const float* x = blockIdx.y ? x2 : x1;
    const float* g = blockIdx.y ? g2 : g1;
    const float* bb = blockIdx.y ? b2 : b1;
    _Float16* o = blockIdx.y ? x2n : x1n;
    const float* xr = x + (size_t)token * D_;
    float a0 = xr[lane], a1 = xr[lane + 64];
    float s = a0 + a1, s2 = a0 * a0 + a1 * a1;
    #pragma unroll
    for (int off = 1; off < 64; off <<= 1) {
        s += __shfl_xor(s, off);
        s2 += __shfl_xor(s2, off);
    }
    float mean = s * (1.f / 128.f);
    float var = s2 * (1.f / 128.f) - mean * mean;
    float inv = rsqrtf(var + 1e-5f);
    int lt = token >> 4, ln_r = token & 15;
    #pragma unroll
    for (int h = 0; h < 2; h++) {
        int col = lane + h * 64;
        float v = (h ? a1 : a0);
        float out = (v - mean) * inv * g[col] + bb[col];
        int ss = col >> 5, q = (col >> 3) & 3, j = col & 7;
        o[((size_t)((lt * 4 + ss) * 64 + q * 16 + ln_r)) * 8 + j] = (_Float16)out;
    }
}

// Projections. q1 fp16 FR; k2 fp16 FR pre-scaled by KSCL; v1/v2 -> vsw8 fp8
// permuted-k B-frag layout. W-frag register prefetch pipeline over c.
__global__ __launch_bounds__(256) void proj_kernel(const _Float16* x1n, const _Float16* x2n,
        const _Float16* wsw, const float* bq, const float* bv1, const float* bk,
        const float* bv2, _Float16* q1, _Float16* k2, unsigned char* vsw8) {
    int g = blockIdx.y;   // 0:Wq 1:Wv1 2:Wk 3:Wv2
    const _Float16* A = (g < 2) ? x1n : x2n;
    const _Float16* Bw = wsw + g * 16384;
    const float* bias = (g == 0) ? bq : (g == 1) ? bv1 : (g == 2) ? bk : bv2;
    int wave = threadIdx.x >> 6, lane = threadIdx.x & 63;
    int quad = lane >> 4, ln = lane & 15;
    int mbase = blockIdx.x * 64 + wave * 16;
    int lt = mbase >> 4;

    half8 a[4];
    #pragma unroll
    for (int s = 0; s < 4; s++)
        a[s] = *(const half8*)(A + ((size_t)((lt * 4 + s) * 64 + lane)) * 8);

    f32x4 acc[8];
    #pragma unroll
    for (int c = 0; c < 8; c++) acc[c] = f32x4{0.f, 0.f, 0.f, 0.f};

    half8 Wc[4], Wn[4];
    #pragma unroll
    for (int s = 0; s < 4; s++)
        Wc[s] = *(const half8*)(Bw + ((size_t)((s * 8 + 0) * 64 + lane)) * 8);
    #pragma unroll
    for (int c = 0; c < 8; c++) {
        int cn = (c < 7) ? c + 1 : 7;
        #pragma unroll
        for (int s = 0; s < 4; s++)
            Wn[s] = *(const half8*)(Bw + ((size_t)((s * 8 + cn) * 64 + lane)) * 8);
        #pragma unroll
        for (int s = 0; s < 4; s++)
            acc[c] = mfma16(a[s], Wc[s], acc[c]);
        #pragma unroll
        for (int s = 0; s < 4; s++) Wc[s] = Wn[s];
    }

    bool isV = (g == 1) || (g == 3);
    if (!isV) {
        float scl = (g == 2) ? KSCL : 1.f;
        _Float16* out = (g == 0) ? q1 : k2;
        #pragma unroll
        for (int c = 0; c < 8; c++) {
            int n = c * 16 + ln;
            float bv = bias[n];
            #pragma unroll
            for (int r = 0; r < 4; r++) {
                int s_o = c >> 1, q_o = ((c & 1) << 1) | (ln >> 3), j = ln & 7;
                out[((size_t)((lt * 4 + s_o) * 64 + q_o * 16 + (quad * 4 + r))) * 8 + j]
                    = (_Float16)((acc[c][r] + bv) * scl);
            }
        }
    } else {
        int cbase = (g == 3) ? 8 : 0;
        int b = mbase >> 12;
        int l0 = (mbase & (L_ - 1)) + quad * 4;
        int sp = l0 >> 6, tt = (l0 >> 4) & 3, q2 = (l0 >> 2) & 3;
        unsigned char* Vb = vsw8 + (size_t)b * (1u << 20);
        #pragma unroll
        for (int c = 0; c < 8; c++) {
            int n = c * 16 + ln;
            float bv = bias[n];
            int pk = pk4(acc[c][0] + bv, acc[c][1] + bv, acc[c][2] + bv, acc[c][3] + bv);
            *(int*)(Vb + (((size_t)(sp * 16 + cbase + c) * 64 + q2 * 16 + ln) * 16 + tt * 4)) = pk;
        }
    }
}

// Pass 1: S^T tiles (A=q1 rows = softmax k-dim, B=k2^T cols = att rows).
// p = exp2(acc) via raw v_exp_f32; pk4 over r -> permuted-k fp8 A-entries.
__global__ __launch_bounds__(256) void score_kernel(
        const _Float16* __restrict__ q1sw, const _Float16* __restrict__ k2sw,
        unsigned char* __restrict__ pmat8, float* __restrict__ rowsum) {
    int w = threadIdx.x >> 6, lane = threadIdx.x & 63;
    int quad = lane >> 4, ln = lane & 15;
    int b = blockIdx.z;
    int kL0 = blockIdx.y * 128 + (w & 1) * 64;     // q1 rows (contraction dim of PV)
    int mL0 = blockIdx.x * 128 + (w >> 1) * 64;    // k2 rows (att rows)
    int ltk = ((b << 12) + kL0) >> 4;
    int ltm = ((b << 12) + mL0) >> 4;

    f32x4 acc[4][4];
    #pragma unroll
    for (int i = 0; i < 4; i++)
        #pragma unroll
        for (int j = 0; j < 4; j++) acc[i][j] = f32x4{0.f, 0.f, 0.f, 0.f};

    #pragma unroll
    for (int s = 0; s < 4; s++) {
        half8 a[4], bq[4];
        #pragma unroll
        for (int i = 0; i < 4; i++)
            a[i] = *(const half8*)(q1sw + ((size_t)(((ltk + i) * 4 + s) * 64 + lane)) * 8);
        #pragma unroll
        for (int j = 0; j < 4; j++)
            bq[j] = *(const half8*)(k2sw + ((size_t)(((ltm + j) * 4 + s) * 64 + lane)) * 8);
        #pragma unroll
        for (int i = 0; i < 4; i++)
            #pragma unroll
            for (int j = 0; j < 4; j++)
                acc[i][j] = mfma16(a[i], bq[j], acc[i][j]);
    }

    unsigned char* Pb = pmat8 + (size_t)b * (16u << 20);
    int sp = kL0 >> 6;
    #pragma unroll
    for (int j = 0; j < 4; j++) {
        int4 d;
        float csum = 0.f;
        #pragma unroll
        for (int i = 0; i < 4; i++) {
            float p0 = fexp2(acc[i][j][0]);
            float p1 = fexp2(acc[i][j][1]);
            float p2 = fexp2(acc[i][j][2]);
            float p3 = fexp2(acc[i][j][3]);
            csum += (p0 + p1) + (p2 + p3);
            ((int*)&d)[i] = pk4(p0, p1, p2, p3);
        }
        csum += __shfl_xor(csum, 16);
        csum += __shfl_xor(csum, 32);
        if (lane < 16)
            atomicAdd(&rowsum[(b << 12) + mL0 + j * 16 + ln], csum);
        int lt = (mL0 >> 4) + j;
        *(int4*)(Pb + (((size_t)(lt * 64 + sp)) * 64 + lane) * 16) = d;
    }
}

// Pass 2: O^T = V^T . P^T (operand swap). 512-thread blocks, 8 waves:
// wave (wc, kh) = (n-quarter, k-half). In-block k-split -> 4 waves/SIMD.
// fp32 partials merged in LDS. att-row lands on lane axis.
__global__ __launch_bounds__(512) void pv_kernel(
        const unsigned char* __restrict__ pmat8, const unsigned char* __restrict__ vsw8,
        const float* __restrict__ rowsum,
        _Float16* __restrict__ att1, _Float16* __restrict__ att2) {
    __shared__ f32x4 part[4][2][4][64];   // 32 KB: [wc][m c][n i][lane]
    int w = threadIdx.x >> 6, lane = threadIdx.x & 63;
    int quad = lane >> 4, ln = lane & 15;
    int wc = w & 3, kh = w >> 2;
    int rowG0 = blockIdx.x * 32;
    int b = rowG0 >> 12;
    int lt0 = (rowG0 & (L_ - 1)) >> 4;   // 2 m-tiles
    const unsigned char* Pb = pmat8 + (size_t)b * (16u << 20);
    const unsigned char* Vb = vsw8 + (size_t)b * (1u << 20);
    int c0 = wc * 4;
    int sp0 = kh * 32;

    f32x4 acc[4][2];
    #pragma unroll
    for (int i = 0; i < 4; i++)
        #pragma unroll
        for (int c = 0; c < 2; c++) acc[i][c] = f32x4{0.f, 0.f, 0.f, 0.f};

    lng2 Vf[2][4], Pf[2][2];
    #pragma unroll
    for (int p = 0; p < 2; p++) {
        #pragma unroll
        for (int i = 0; i < 4; i++)
            Vf[p][i] = *(const lng2*)(Vb + (((size_t)((sp0 + p) * 16 + c0 + i)) * 64 + lane) * 16);
        #pragma unroll
        for (int c = 0; c < 2; c++)
            Pf[p][c] = *(const lng2*)(Pb + (((size_t)((lt0 + c) * 64 + sp0 + p)) * 64 + lane) * 16);
    }

    #define PVSTEP(buf, ii) do {                                                     \
        int spn = sp0 + ((((ii) + 2) < 32) ? (ii) + 2 : 31);                         \
        lng2 Vn[4], Pn[2];                                                           \
        _Pragma("unroll")                                                            \
        for (int i = 0; i < 4; i++)                                                  \
            Vn[i] = *(const lng2*)(Vb + (((size_t)(spn * 16 + c0 + i)) * 64 + lane) * 16); \
        _Pragma("unroll")                                                            \
        for (int c = 0; c < 2; c++)                                                  \
            Pn[c] = *(const lng2*)(Pb + (((size_t)((lt0 + c) * 64 + spn)) * 64 + lane) * 16); \
        _Pragma("unroll")                                                            \
        for (int i = 0; i < 4; i++)                                                  \
            _Pragma("unroll")                                                        \
            for (int c = 0; c < 2; c++) {                                            \
                acc[i][c] = mfma8(Vf[buf][i].x, Pf[buf][c].x, acc[i][c]);             \
                acc[i][c] = mfma8(Vf[buf][i].y, Pf[buf][c].y, acc[i][c]);             \
            }                                                                        \
        _Pragma("unroll")                                                            \
        for (int i = 0; i < 4; i++) Vf[buf][i] = Vn[i];                              \
        _Pragma("unroll")                                                            \
        for (int c = 0; c < 2; c++) Pf[buf][c] = Pn[c];                              \
    } while (0)

    for (int ii = 0; ii < 32; ii += 2) {
        PVSTEP(0, ii);
        PVSTEP(1, ii + 1);
    }
    #undef PVSTEP

    if (kh == 1) {
        #pragma unroll
        for (int i = 0; i < 4; i++)
            #pragma unroll
            for (int c = 0; c < 2; c++)
                part[wc][c][i][lane] = acc[i][c];
    }
    __syncthreads();
    if (kh == 0) {
        #pragma unroll
        for (int i = 0; i < 4; i++)
            #pragma unroll
            for (int c = 0; c < 2; c++)
                acc[i][c] += part[wc][c][i][lane];

        _Float16* att = (wc >= 2) ? att2 : att1;
        #pragma unroll
        for (int c = 0; c < 2; c++) {
            float inv = 1.f / rowsum[rowG0 + c * 16 + ln];
            int lt = (rowG0 >> 4) + c;
            #pragma unroll
            for (int sl = 0; sl < 2; sl++) {
                half8 v;
                #pragma unroll
                for (int r = 0; r < 4; r++) {
                    v[r]     = (_Float16)(acc[2 * sl][c][r] * inv);
                    v[r + 4] = (_Float16)(acc[2 * sl + 1][c][r] * inv);
                }
                int s = (wc & 1) * 2 + sl;
                *(half8*)(att + ((size_t)((lt * 4 + s) * 64 + lane)) * 8) = v;
            }
        }
    }
}

// out_s = att_s @ Wp_s + bias + residual ; concat -> res (fp16) ; LNf -> xn (FR fp16)
// 512 blocks x (2 rowtiles x 2 streams).
__global__ __launch_bounds__(256) void attn_out_kernel(const _Float16* att1, const _Float16* att2,
        const _Float16* wsw, const float* bp1, const float* bp2,
        const float* x1, const float* x2, const float* lnf_g, const float* lnf_b,
        _Float16* res, _Float16* xn) {
    __shared__ float sst[2][16][2][2];
    int w = threadIdx.x >> 6, lane = threadIdx.x & 63;
    int quad = lane >> 4, ln = lane & 15;
    int rt = w & 1, st = w >> 1;
    int mbase = blockIdx.x * 32 + rt * 16;
    int lt = mbase >> 4;
    const _Float16* att = st ? att2 : att1;
    const _Float16* Wp = wsw + (st ? WP2_OFF : WP1_OFF);
    const float* bp = st ? bp2 : bp1;
    const float* xres = st ? x2 : x1;

    half8 a[4];
    #pragma unroll
    for (int s = 0; s < 4; s++)
        a[s] = *(const half8*)(att + ((size_t)((lt * 4 + s) * 64 + lane)) * 8);

    f32x4 y[8];
    #pragma unroll
    for (int c = 0; c < 8; c++) y[c] = f32x4{0,0,0,0};

    half8 Wc[4], Wn[4];
    #pragma unroll
    for (int s = 0; s < 4; s++)
        Wc[s] = *(const half8*)(Wp + ((size_t)((s * 8 + 0) * 64 + lane)) * 8);
    #pragma unroll
    for (int c = 0; c < 8; c++) {
        int cn = (c < 7) ? c + 1 : 7;
        #pragma unroll
        for (int s = 0; s < 4; s++)
            Wn[s] = *(const half8*)(Wp + ((size_t)((s * 8 + cn) * 64 + lane)) * 8);
        #pragma unroll
        for (int s = 0; s < 4; s++)
            y[c] = mfma16(a[s], Wc[s], y[c]);
        #pragma unroll
        for (int s = 0; s < 4; s++) Wc[s] = Wn[s];
    }

    float psum[4] = {0,0,0,0}, psq[4] = {0,0,0,0};
    #pragma unroll
    for (int c = 0; c < 8; c++) {
        int n = c * 16 + ln;
        float bv = bp[n];
        #pragma unroll
        for (int r = 0; r < 4; r++) {
            int m = mbase + quad * 4 + r;
            float v = y[c][r] + bv + xres[(size_t)m * D_ + n];
            y[c][r] = v; psum[r] += v; psq[r] += v * v;
        }
    }
    #pragma unroll
    for (int off = 1; off < 16; off <<= 1)
        #pragma unroll
        for (int r = 0; r < 4; r++) { psum[r] += __shfl_xor(psum[r], off); psq[r] += __shfl_xor(psq[r], off); }
    if (ln == 0)
        #pragma unroll
        for (int r = 0; r < 4; r++) {
            sst[rt][quad * 4 + r][st][0] = psum[r];
            sst[rt][quad * 4 + r][st][1] = psq[r];
        }
    __syncthreads();
    #pragma unroll
    for (int r = 0; r < 4; r++) {
        float su = sst[rt][quad * 4 + r][0][0] + sst[rt][quad * 4 + r][1][0];
        float sq = sst[rt][quad * 4 + r][0][1] + sst[rt][quad * 4 + r][1][1];
        float mean = su * (1.f / 256.f);
        float var = sq * (1.f / 256.f) - mean * mean;
        float inv = rsqrtf(var + 1e-5f);
        int m = mbase + quad * 4 + r;
        int lt_m = m >> 4;
        #pragma unroll
        for (int c = 0; c < 8; c++) {
            int colg = st * 128 + c * 16 + ln;
            res[(size_t)m * D2_ + colg] = (_Float16)y[c][r];
            float yn = (y[c][r] - mean) * inv * lnf_g[colg] + lnf_b[colg];
            int s_x = colg >> 5, q_x = (colg >> 3) & 3, j = colg & 7;
            xn[((size_t)((lt_m * 8 + s_x) * 64 + q_x * 16 + (m & 15))) * 8 + j] = (_Float16)yn;
        }
    }
}

// h = gelu(xn @ Wf1 + bf1)  [M x 512], FR in/out. W-prefetch pipeline; fast
// tanh-form GELU (x*sigmoid(2u)) via raw v_exp.
__global__ __launch_bounds__(256) void ffn1_kernel(const _Float16* xn, const _Float16* wsw,
        const float* bf1, _Float16* h) {
    int wave = threadIdx.x >> 6, lane = threadIdx.x & 63;
    int quad = lane >> 4, ln = lane & 15;
    int mbase = blockIdx.x * 64 + wave * 16;
    int lt = mbase >> 4;
    int nt = blockIdx.y;   // 0..3
    const _Float16* W = wsw + WF1_OFF;   // K=256, N=512, nc=32

    half8 a[8];
    #pragma unroll
    for (int s = 0; s < 8; s++)
        a[s] = *(const half8*)(xn + ((size_t)((lt * 8 + s) * 64 + lane)) * 8);

    f32x4 acc[8];
    #pragma unroll
    for (int c = 0; c < 8; c++) acc[c] = f32x4{0,0,0,0};

    half8 Wc[8], Wn[8];
    #pragma unroll
    for (int s = 0; s < 8; s++)
        Wc[s] = *(const half8*)(W + ((size_t)((s * 32 + nt * 8) * 64 + lane)) * 8);
    #pragma unroll
    for (int c = 0; c < 8; c++) {
        int cn = (c < 7) ? c + 1 : 7;
        #pragma unroll
        for (int s = 0; s < 8; s++)
            Wn[s] = *(const half8*)(W + ((size_t)((s * 32 + nt * 8 + cn) * 64 + lane)) * 8);
        #pragma unroll
        for (int s = 0; s < 8; s++)
            acc[c] = mfma16(a[s], Wc[s], acc[c]);
        #pragma unroll
        for (int s = 0; s < 8; s++) Wc[s] = Wn[s];
    }
    #pragma unroll
    for (int c = 0; c < 8; c++) {
        int n = nt * 128 + c * 16 + ln;
        float bv = bf1[n];
        int s_h = n >> 5, q_h = (n >> 3) & 3, j = n & 7;
        #pragma unroll
        for (int r = 0; r < 4; r++) {
            float v = acc[c][r] + bv;
            float u = 0.7978845608f * (v + 0.044715f * v * v * v);
            float e = fexp2(-2.8853900818f * u);     // 2*log2(e)*u
            float ge = v * __builtin_amdgcn_rcpf(1.f + e);
            h[((size_t)((lt * 16 + s_h) * 64 + q_h * 16 + (quad * 4 + r))) * 8 + j] = (_Float16)ge;
        }
    }
}

// FUSED: xn2 = LN3(h @ Wf2 + bf2 + res) -> LDS tile ; out = xn2 @ Wo + bo.
// Same grid/block shape as old ffn2 (M/32 blocks x 4 waves). Kills the xn2
// global round-trip + out_kernel launch.
__global__ __launch_bounds__(256) void ffn2_out_kernel(const _Float16* h, const _Float16* wsw,
        const float* bf2, const _Float16* res, const float* g3, const float* b3,
        const float* bo, float* out) {
    __shared__ float sst[2][16][2][2];
    __shared__ _Float16 xt[8192];        // 16 KB: 32 rows x 256 cols, FR layout
    __shared__ f32x4 pc[2][4][64];       // 8 KB: out k-half partials
    int w = threadIdx.x >> 6, lane = threadIdx.x & 63;
    int quad = lane >> 4, ln = lane & 15;
    int rt = w & 1, nh = w >> 1;
    int mb = blockIdx.x * 32 + rt * 16;
    int lt = mb >> 4;
    const _Float16* W = wsw + WF2_OFF;   // K=512, N=256, nc=16

    f32x4 acc[8];
    #pragma unroll
    for (int c = 0; c < 8; c++) acc[c] = f32x4{0,0,0,0};

    half8 aC, aN;
    half8 Wc[8], Wn[8];
    aC = *(const half8*)(h + ((size_t)((lt * 16 + 0) * 64 + lane)) * 8);
    #pragma unroll
    for (int c = 0; c < 8; c++)
        Wc[c] = *(const half8*)(W + ((size_t)((0 * 16 + nh * 8 + c) * 64 + lane)) * 8);

    #pragma unroll
    for (int s = 0; s < 16; s++) {
        int sn = (s < 15) ? s + 1 : 15;
        aN = *(const half8*)(h + ((size_t)((lt * 16 + sn) * 64 + lane)) * 8);
        #pragma unroll
        for (int c = 0; c < 8; c++)
            Wn[c] = *(const half8*)(W + ((size_t)((sn * 16 + nh * 8 + c) * 64 + lane)) * 8);
        #pragma unroll
        for (int c = 0; c < 8; c++)
            acc[c] = mfma16(aC, Wc[c], acc[c]);
        aC = aN;
        #pragma unroll
        for (int c = 0; c < 8; c++) Wc[c] = Wn[c];
    }

    float y[8][4];
    float psum[4] = {0,0,0,0}, psq[4] = {0,0,0,0};
    #pragma unroll
    for (int c = 0; c < 8; c++) {
        int n = nh * 128 + c * 16 + ln;
        float bv = bf2[n];
        #pragma unroll
        for (int r = 0; r < 4; r++) {
            int m = mb + quad * 4 + r;
            float v = acc[c][r] + bv + (float)res[(size_t)m * D2_ + n];
            y[c][r] = v; psum[r] += v; psq[r] += v * v;
        }
    }
    #pragma unroll
    for (int off = 1; off < 16; off <<= 1)
        #pragma unroll
        for (int r = 0; r < 4; r++) { psum[r] += __shfl_xor(psum[r], off); psq[r] += __shfl_xor(psq[r], off); }
    if (ln == 0)
        #pragma unroll
        for (int r = 0; r < 4; r++) { sst[rt][quad * 4 + r][nh][0] = psum[r]; sst[rt][quad * 4 + r][nh][1] = psq[r]; }
    __syncthreads();
    #pragma unroll
    for (int r = 0; r < 4; r++) {
        float su = sst[rt][quad * 4 + r][0][0] + sst[rt][quad * 4 + r][1][0];
        float sq = sst[rt][quad * 4 + r][0][1] + sst[rt][quad * 4 + r][1][1];
        float mean = su * (1.f / 256.f);
        float var = sq * (1.f / 256.f) - mean * mean;
        float invs = rsqrtf(var + 1e-5f);
        #pragma unroll
        for (int c = 0; c < 8; c++) {
            int n = nh * 128 + c * 16 + ln;
            float yn = (y[c][r] - mean) * invs * g3[n] + b3[n];
            int s_x = n >> 5, q_x = (n >> 3) & 3, j = n & 7;
            xt[((rt * 8 + s_x) * 64 + q_x * 16 + (quad * 4 + r)) * 8 + j] = (_Float16)yn;
        }
    }
    __syncthreads();

    // ---- out phase: waves (rt2, kh) ----
    int rt2 = w & 1, kh = w >> 1;
    const _Float16* Wo = wsw + WO_OFF;   // K=256, N=64(padded), nc=4
    f32x4 oacc[4];
    #pragma unroll
    for (int c = 0; c < 4; c++) oacc[c] = f32x4{0,0,0,0};
    #pragma unroll
    for (int ss = 0; ss < 4; ss++) {
        int s = kh * 4 + ss;
        half8 a = *(const half8*)(xt + ((size_t)((rt2 * 8 + s) * 64 + lane)) * 8);
        #pragma unroll
        for (int c = 0; c < 4; c++)
            oacc[c] = mfma16(a, *(const half8*)(Wo + ((size_t)((s * 4 + c) * 64 + lane)) * 8), oacc[c]);
    }
    if (kh == 1)
        #pragma unroll
        for (int c = 0; c < 4; c++) pc[rt2][c][lane] = oacc[c];
    __syncthreads();
    if (kh == 0) {
        int mb2 = blockIdx.x * 32 + rt2 * 16;
        #pragma unroll
        for (int c = 0; c < 4; c++) {
            f32x4 p = pc[rt2][c][lane];
            int n = c * 16 + ln;
            if (n < OUT_) {
                float bv = bo[n];
                #pragma unroll
                for (int r = 0; r < 4; r++)
                    out[(size_t)(mb2 + quad * 4 + r) * OUT_ + n] = oacc[c][r] + p[r] + bv;
            }
        }
    }
}

extern "C" void kernel_launch(void* const* d_in, const int* in_sizes, int n_in,
                              void* d_out, int out_size, void* d_ws, size_t ws_size,
                              hipStream_t stream) {
    const float* x1    = (const float*)d_in[0];
    const float* x2    = (const float*)d_in[1];
    const float* ln1_g = (const float*)d_in[2];
    const float* ln1_b = (const float*)d_in[3];
    const float* ln2_g = (const float*)d_in[4];
    const float* ln2_b = (const float*)d_in[5];
    const float* Wq    = (const float*)d_in[6];
    const float* bq    = (const float*)d_in[7];
    const float* Wv1   = (const float*)d_in[8];
    const float* bv1   = (const float*)d_in[9];
    const float* Wk    = (const float*)d_in[10];
    const float* bk    = (const float*)d_in[11];
    const float* Wv2   = (const float*)d_in[12];
    const float* bv2   = (const float*)d_in[13];
    const float* Wp1   = (const float*)d_in[14];
    const float* bp1   = (const float*)d_in[15];
    const float* Wp2   = (const float*)d_in[16];
    const float* bp2   = (const float*)d_in[17];
    const float* lnf_g = (const float*)d_in[18];
    const float* lnf_b = (const float*)d_in[19];
    const float* Wf1   = (const float*)d_in[20];
    const float* bf1   = (const float*)d_in[21];
    const float* Wf2   = (const float*)d_in[22];
    const float* bf2   = (const float*)d_in[23];
    const float* ln3_g = (const float*)d_in[24];
    const float* ln3_b = (const float*)d_in[25];
    const float* Wo    = (const float*)d_in[26];
    const float* bo    = (const float*)d_in[27];
    float* out = (float*)d_out;

    char* ws = (char*)d_ws;
    const size_t MB = 1 << 20;
    _Float16* q1sw   = (_Float16*)(ws + 0 * MB);    // 4 MB
    _Float16* k2sw   = (_Float16*)(ws + 4 * MB);    // 4 MB
    unsigned char* vsw8 = (unsigned char*)(ws + 8 * MB);   // 4 MB (fp8 Vcat per batch)
    _Float16* att1   = (_Float16*)(ws + 12 * MB);   // 4 MB
    _Float16* att2   = (_Float16*)(ws + 16 * MB);   // 4 MB
    _Float16* x1n    = (_Float16*)(ws + 20 * MB);   // 4 MB
    _Float16* x2n    = (_Float16*)(ws + 24 * MB);   // 4 MB
    _Float16* wsw    = (_Float16*)(ws + 28 * MB);   // ~0.74 MB
    float*    rowsum = (float*)   (ws + 29 * MB);   // 64 KB
    _Float16* res    = (_Float16*)(ws + 30 * MB);   // 8 MB
    _Float16* xn     = (_Float16*)(ws + 46 * MB);   // 8 MB
    _Float16* h      = (_Float16*)(ws + 54 * MB);   // 16 MB
    unsigned char* pmat8 = (unsigned char*)(ws + 78 * MB); // 64 MB (fp8 P per batch)

    prep_kernel<<<dim3(512, 10), 256, 0, stream>>>(Wq, Wv1, Wk, Wv2, Wp1, Wp2, Wf1, Wf2, Wo,
                                                   wsw, rowsum);
    ln_kernel<<<dim3(M_ / 4, 2), 256, 0, stream>>>(x1, x2, ln1_g, ln1_b, ln2_g, ln2_b, x1n, x2n);
    proj_kernel<<<dim3(M_ / 64, 4), 256, 0, stream>>>(x1n, x2n, wsw, bq, bv1, bk, bv2,
                                                      q1sw, k2sw, vsw8);
    score_kernel<<<dim3(32, 32, 4), 256, 0, stream>>>(q1sw, k2sw, pmat8, rowsum);
    pv_kernel<<<dim3(M_ / 32), 512, 0, stream>>>(pmat8, vsw8, rowsum, att1, att2);
    attn_out_kernel<<<dim3(M_ / 32), 256, 0, stream>>>(att1, att2, wsw, bp1, bp2,
                                                       x1, x2, lnf_g, lnf_b, res, xn);
    ffn1_kernel<<<dim3(M_ / 64, 4), 256, 0, stream>>>(xn, wsw, bf1, h);
    ffn2_out_kernel<<<dim3(M_ / 32), 256, 0, stream>>>(h, wsw, bf2, res, ln3_g, ln3_b, bo, out);
}